// Round 1
// baseline (1051.883 us; speedup 1.0000x reference)
//
#include <hip/hip_runtime.h>
#include <cstddef>
#include <cstdint>

// ---------------- problem constants ----------------
constexpr int L_IN   = 16384;
constexpr int L_SEQ  = 2047;          // (16384-16)/8 + 1
constexpr int BATCH  = 8;
constexpr int M_TOK  = BATCH * L_SEQ; // 16376
constexpr int D_INNER = 512;
constexpr int NHEADS  = 8;
constexpr int HEADDIM = 64;
constexpr int D_STATE = 128;
constexpr int CONV_DIM = 768;
constexpr int D_IN_PROJ = 1288;

// ---------------- workspace layout (floats) ----------------
constexpr size_t OFF_U    = 0;                       // 16376*256   = 4,192,256
constexpr size_t OFF_ZX   = OFF_U   + 4192256;       // 16376*1288  = 21,092,288
constexpr size_t OFF_DT   = OFF_ZX  + 21092288;      // 16376*8     = 131,008
constexpr size_t OFF_DA   = OFF_DT  + 131008;
constexpr size_t OFF_XC   = OFF_DA  + 131008;        // 16376*768   = 12,576,768
constexpr size_t OFF_Y    = OFF_XC  + 12576768;      // 16376*512   = 8,384,512
constexpr size_t OFF_YC1A = OFF_Y   + 8384512;       // 8*8*2047    = 131,008
constexpr size_t OFF_YC1B = OFF_YC1A + 131008;
// total ≈ 46.77M floats ≈ 187 MB

// ============================================================
// K1: front conv (4->256, K=16, stride 8, VALID) + ReLU, emit u[(b*L+t)*256 + c]
// ============================================================
__global__ __launch_bounds__(256) void k_front(const float* __restrict__ x,
    const float* __restrict__ w, const float* __restrict__ cb,
    float* __restrict__ u) {
  const int tb = blockIdx.x;   // 128 tiles of 16 t
  const int b  = blockIdx.y;   // 8
  const int t0 = tb * 16;
  __shared__ float xs[4][136];
  for (int i = threadIdx.x; i < 4 * 136; i += 256) {
    int ic = i / 136, off = i % 136;
    int gi = t0 * 8 + off;
    xs[ic][off] = (gi < L_IN) ? x[((size_t)b * 4 + ic) * L_IN + gi] : 0.f;
  }
  __syncthreads();
  const int c = threadIdx.x;
  float wreg[64];
#pragma unroll
  for (int q = 0; q < 16; q++)
    *(float4*)&wreg[q * 4] = *(const float4*)(w + (size_t)c * 64 + q * 4);
  const float base = cb[c];
  float acc[16];
#pragma unroll
  for (int ts = 0; ts < 16; ts++) acc[ts] = base;
#pragma unroll
  for (int ic = 0; ic < 4; ic++) {
#pragma unroll
    for (int ts = 0; ts < 16; ts++) {
#pragma unroll
      for (int k = 0; k < 16; k++)
        acc[ts] = fmaf(xs[ic][ts * 8 + k], wreg[ic * 16 + k], acc[ts]);
    }
  }
#pragma unroll
  for (int ts = 0; ts < 16; ts++) {
    int t = t0 + ts;
    if (t < L_SEQ)
      u[((size_t)b * L_SEQ + t) * 256 + c] = fmaxf(acc[ts], 0.f);
  }
}

// ============================================================
// K2/K7: fp32 GEMM  C[m][n] = sum_k A[m*K+k]*B[n*K+k]   (NT, both K-contig)
// 128x128 tile, 256 threads, 8x8 per thread, K%16==0
// ============================================================
__global__ __launch_bounds__(256) void gemm_nt(const float* __restrict__ A,
    const float* __restrict__ B, float* __restrict__ C,
    int M, int N, int K) {
  __shared__ float As[16][132];
  __shared__ float Bs[16][132];
  const int tid = threadIdx.x;
  const int tx = tid & 15, ty = tid >> 4;
  const int m0 = blockIdx.y * 128, n0 = blockIdx.x * 128;
  const int arow = tid >> 1;        // 0..127
  const int akq  = (tid & 1) * 8;   // 0 or 8
  float acc[8][8] = {};
  for (int k0 = 0; k0 < K; k0 += 16) {
    float4 av0 = {0,0,0,0}, av1 = {0,0,0,0}, bv0 = {0,0,0,0}, bv1 = {0,0,0,0};
    int gm = m0 + arow;
    if (gm < M) {
      const float* p = A + (size_t)gm * K + k0 + akq;
      av0 = *(const float4*)p; av1 = *(const float4*)(p + 4);
    }
    int gn = n0 + arow;
    if (gn < N) {
      const float* p = B + (size_t)gn * K + k0 + akq;
      bv0 = *(const float4*)p; bv1 = *(const float4*)(p + 4);
    }
    __syncthreads();
    As[akq+0][arow]=av0.x; As[akq+1][arow]=av0.y; As[akq+2][arow]=av0.z; As[akq+3][arow]=av0.w;
    As[akq+4][arow]=av1.x; As[akq+5][arow]=av1.y; As[akq+6][arow]=av1.z; As[akq+7][arow]=av1.w;
    Bs[akq+0][arow]=bv0.x; Bs[akq+1][arow]=bv0.y; Bs[akq+2][arow]=bv0.z; Bs[akq+3][arow]=bv0.w;
    Bs[akq+4][arow]=bv1.x; Bs[akq+5][arow]=bv1.y; Bs[akq+6][arow]=bv1.z; Bs[akq+7][arow]=bv1.w;
    __syncthreads();
#pragma unroll
    for (int k = 0; k < 16; k++) {
      float a[8], bb[8];
      *(float4*)&a[0]  = *(const float4*)&As[k][ty * 8];
      *(float4*)&a[4]  = *(const float4*)&As[k][ty * 8 + 4];
      *(float4*)&bb[0] = *(const float4*)&Bs[k][tx * 8];
      *(float4*)&bb[4] = *(const float4*)&Bs[k][tx * 8 + 4];
#pragma unroll
      for (int i = 0; i < 8; i++)
#pragma unroll
        for (int j = 0; j < 8; j++)
          acc[i][j] = fmaf(a[i], bb[j], acc[i][j]);
    }
  }
#pragma unroll
  for (int i = 0; i < 8; i++) {
    int gm = m0 + ty * 8 + i;
    if (gm >= M) break;
    float* crow = C + (size_t)gm * N;
#pragma unroll
    for (int j = 0; j < 8; j++) {
      int gn = n0 + tx * 8 + j;
      if (gn < N) crow[gn] = acc[i][j];
    }
  }
}

// ============================================================
// K3: dt = softplus(zx[:,1280+h] + dt_bias[h]); dA = exp(-exp(A_log[h])*dt)
// ============================================================
__global__ void k_dt(const float* __restrict__ zx, const float* __restrict__ dt_bias,
                     const float* __restrict__ A_log, float* __restrict__ dt,
                     float* __restrict__ dA) {
  int i = blockIdx.x * 256 + threadIdx.x;
  if (i >= M_TOK * NHEADS) return;
  int hd = i & 7;
  int row = i >> 3;
  float v = zx[(size_t)row * D_IN_PROJ + (D_INNER + CONV_DIM) + hd] + dt_bias[hd];
  float sp = (v > 20.f) ? v : log1pf(expf(v));
  dt[i] = sp;
  dA[i] = expf(-expf(A_log[hd]) * sp);
}

// ============================================================
// K4: depthwise causal conv (D_CONV=4, left pad 3) + bias + silu
//     in: zx cols [512,1280) viewed (b,t,c); out: xc[(b*L+t)*768 + c]
// ============================================================
__global__ void k_dw(const float* __restrict__ zx, const float* __restrict__ w,
                     const float* __restrict__ bias, float* __restrict__ xc) {
  size_t idx = (size_t)blockIdx.x * 256 + threadIdx.x;
  if (idx >= (size_t)M_TOK * CONV_DIM) return;
  int c = (int)(idx % CONV_DIM);
  int row = (int)(idx / CONV_DIM);
  int t = row % L_SEQ, b = row / L_SEQ;
  float acc = bias[c];
#pragma unroll
  for (int k = 0; k < 4; k++) {
    int tt = t - 3 + k;
    if (tt >= 0)
      acc = fmaf(zx[((size_t)b * L_SEQ + tt) * D_IN_PROJ + D_INNER + c], w[c * 4 + k], acc);
  }
  xc[(size_t)row * CONV_DIM + c] = acc / (1.f + expf(-acc));
}

// ============================================================
// K5: sequential SSM scan.
//   grid (64 bh, 16 wg), 64 threads. lane = ps*16+ns: p = wg*4+ps, n = ns*8..+8
//   h[p,n] = h*dA + dt*x[p]*B[n];  y[p] = sum_n h*C[n]  (DPP 16-lane reduce)
// ============================================================
template<int CTRL>
__device__ __forceinline__ float dppadd(float x) {
  int v = __builtin_amdgcn_update_dpp(0, __float_as_int(x), CTRL, 0xf, 0xf, true);
  return x + __int_as_float(v);
}

struct Pref { float4 B0, B1, C0, C1; float xv, dAv, dtv; };

#define LDP(S, T) { const float* r = xc + (rowbase + (size_t)(T)) * CONV_DIM;          \
  S.B0 = *(const float4*)(r + 512 + nb); S.B1 = *(const float4*)(r + 516 + nb);        \
  S.C0 = *(const float4*)(r + 640 + nb); S.C1 = *(const float4*)(r + 644 + nb);        \
  S.xv = r[hp];                                                                        \
  S.dAv = dA[(rowbase + (size_t)(T)) * 8 + h];                                         \
  S.dtv = dt[(rowbase + (size_t)(T)) * 8 + h]; }

#define STEP(S, T) { float coef = S.dtv * S.xv;                                        \
  hs[0] = fmaf(hs[0], S.dAv, coef * S.B0.x); hs[1] = fmaf(hs[1], S.dAv, coef * S.B0.y);\
  hs[2] = fmaf(hs[2], S.dAv, coef * S.B0.z); hs[3] = fmaf(hs[3], S.dAv, coef * S.B0.w);\
  hs[4] = fmaf(hs[4], S.dAv, coef * S.B1.x); hs[5] = fmaf(hs[5], S.dAv, coef * S.B1.y);\
  hs[6] = fmaf(hs[6], S.dAv, coef * S.B1.z); hs[7] = fmaf(hs[7], S.dAv, coef * S.B1.w);\
  float acc = hs[0]*S.C0.x + hs[1]*S.C0.y + hs[2]*S.C0.z + hs[3]*S.C0.w                \
            + hs[4]*S.C1.x + hs[5]*S.C1.y + hs[6]*S.C1.z + hs[7]*S.C1.w;               \
  acc = dppadd<0x128>(acc); acc = dppadd<0x124>(acc);                                  \
  acc = dppadd<0x122>(acc); acc = dppadd<0x121>(acc);                                  \
  if (ns == 0) y[(rowbase + (size_t)(T)) * D_INNER + hp] = acc + Dsk * S.xv; }

__global__ __launch_bounds__(64) void k_scan(const float* __restrict__ xc,
    const float* __restrict__ dt, const float* __restrict__ dA,
    const float* __restrict__ Dskip, float* __restrict__ y) {
  const int bh = blockIdx.x;  // 64
  const int wg = blockIdx.y;  // 16
  const int b = bh >> 3, h = bh & 7;
  const int lane = threadIdx.x;
  const int ps = lane >> 4;   // 0..3
  const int ns = lane & 15;   // 0..15
  const int p  = wg * 4 + ps;
  const int nb = ns * 8;
  const int hp = h * 64 + p;
  const float Dsk = Dskip[h];
  const size_t rowbase = (size_t)b * L_SEQ;
  float hs[8] = {0, 0, 0, 0, 0, 0, 0, 0};
  Pref s0, s1, s2;
  LDP(s0, 0); LDP(s1, 1); LDP(s2, 2);
  int t = 0;
  for (; t + 3 <= L_SEQ; t += 3) {
    STEP(s0, t);     if (t + 3 < L_SEQ) LDP(s0, t + 3);
    STEP(s1, t + 1); if (t + 4 < L_SEQ) LDP(s1, t + 4);
    STEP(s2, t + 2); if (t + 5 < L_SEQ) LDP(s2, t + 5);
  }
  if (t < L_SEQ) { STEP(s0, t); }   // L_SEQ % 3 == 1
}

// ============================================================
// K6: y = y*silu(z); y *= rsqrt(mean(y^2)+1e-5)*norm_w   (in-place, row=512)
// ============================================================
__global__ __launch_bounds__(512) void k_norm(float* __restrict__ y,
    const float* __restrict__ zx, const float* __restrict__ norm_w) {
  const int row = blockIdx.x;
  const int c = threadIdx.x;
  float z = zx[(size_t)row * D_IN_PROJ + c];
  float g = z / (1.f + expf(-z));
  float v = y[(size_t)row * D_INNER + c] * g;
  float ss = v * v;
#pragma unroll
  for (int m = 32; m >= 1; m >>= 1) ss += __shfl_xor(ss, m, 64);
  __shared__ float red[8];
  if ((threadIdx.x & 63) == 0) red[threadIdx.x >> 6] = ss;
  __syncthreads();
  float tot = 0.f;
#pragma unroll
  for (int i = 0; i < 8; i++) tot += red[i];
  float scale = rsqrtf(tot * (1.f / 512.f) + 1e-5f);
  y[(size_t)row * D_INNER + c] = v * scale * norm_w[c];
}

// ============================================================
// K8: conv1 (256->8ch, K=16, pad(7,8)) — partial over ic halves, no bias
//     grid (16 t-tiles, 8 b, 2 ic-half); out yc1[z][(b*8+oc)*L + t]
// ============================================================
__global__ __launch_bounds__(256) void k_conv1(const float* __restrict__ om,
    const float* __restrict__ w, float* __restrict__ yc1a, float* __restrict__ yc1b) {
  const int tt = blockIdx.x, b = blockIdx.y, zc = blockIdx.z;
  const int t0 = tt * 128;
  const int tsub = threadIdx.x >> 1;     // 0..127
  const int ochalf = threadIdx.x & 1;    // 0..1 -> oc base
  __shared__ float inl[143][65];
  __shared__ float wl[64][16][8];
  float acc[4] = {0, 0, 0, 0};
  for (int cc2 = 0; cc2 < 2; cc2++) {
    const int icc = zc * 2 + cc2;        // ic chunk of 64
    __syncthreads();
    for (int i = threadIdx.x; i < 143 * 64; i += 256) {
      int r = i >> 6, cc = i & 63;
      int tin = t0 - 7 + r;
      float v = 0.f;
      if (tin >= 0 && tin < L_SEQ)
        v = om[((size_t)b * L_SEQ + tin) * 256 + icc * 64 + cc];
      inl[r][cc] = v;
    }
    for (int i = threadIdx.x; i < 64 * 16 * 8; i += 256) {
      int oc = i & 7, k = (i >> 3) & 15, ic = i >> 7;
      wl[ic][k][oc] = w[((size_t)oc * 256 + icc * 64 + ic) * 16 + k];
    }
    __syncthreads();
    for (int ic = 0; ic < 64; ic++) {
#pragma unroll
      for (int k = 0; k < 16; k++) {
        float iv = inl[tsub + k][ic];
        float4 wv = *(const float4*)&wl[ic][k][ochalf * 4];
        acc[0] = fmaf(iv, wv.x, acc[0]);
        acc[1] = fmaf(iv, wv.y, acc[1]);
        acc[2] = fmaf(iv, wv.z, acc[2]);
        acc[3] = fmaf(iv, wv.w, acc[3]);
      }
    }
  }
  int t = t0 + tsub;
  if (t < L_SEQ) {
    float* dst = (zc == 0) ? yc1a : yc1b;
#pragma unroll
    for (int j = 0; j < 4; j++)
      dst[((size_t)b * 8 + ochalf * 4 + j) * L_SEQ + t] = acc[j];
  }
}

// ============================================================
// K9: transposed conv (8->4ch, K=16, lhs_dilation=8, pad 15/15) + both conv1
//     partials + conv1 bias folded in + convT bias
// ============================================================
__global__ void k_convT(const float* __restrict__ yc1a, const float* __restrict__ yc1b,
                        const float* __restrict__ b1, const float* __restrict__ wT,
                        const float* __restrict__ bT, float* __restrict__ out) {
  const int s = blockIdx.x * 256 + threadIdx.x;  // 16384
  const int c = blockIdx.y, b = blockIdx.z;
  float acc = bT[c];
  const int k0 = (15 - (s & 7)) & 7;
#pragma unroll
  for (int dk = 0; dk < 2; dk++) {
    int k = k0 + 8 * dk;
    int num = s - 15 + k;          // divisible by 8 by construction
    int m = num >> 3;
    if (num >= 0 && m < L_SEQ) {
#pragma unroll
      for (int j = 0; j < 8; j++) {
        float v = yc1a[((size_t)b * 8 + j) * L_SEQ + m]
                + yc1b[((size_t)b * 8 + j) * L_SEQ + m] + b1[j];
        acc = fmaf(v, wT[((size_t)j * 4 + c) * 16 + (15 - k)], acc);
      }
    }
  }
  out[((size_t)b * 4 + c) * L_IN + s] = acc;
}

// ============================================================
extern "C" void kernel_launch(void* const* d_in, const int* in_sizes, int n_in,
                              void* d_out, int out_size, void* d_ws, size_t ws_size,
                              hipStream_t stream) {
  const float* x         = (const float*)d_in[0];
  const float* conv_w    = (const float*)d_in[1];
  const float* conv_b    = (const float*)d_in[2];
  const float* in_proj_w = (const float*)d_in[3];
  const float* conv1d_w  = (const float*)d_in[4];
  const float* conv1d_b  = (const float*)d_in[5];
  const float* dt_bias   = (const float*)d_in[6];
  const float* A_log     = (const float*)d_in[7];
  const float* D_skip    = (const float*)d_in[8];
  const float* norm_w    = (const float*)d_in[9];
  const float* out_proj_w= (const float*)d_in[10];
  const float* conv1_w   = (const float*)d_in[11];
  const float* conv1_b   = (const float*)d_in[12];
  const float* convT_w   = (const float*)d_in[13];
  const float* convT_b   = (const float*)d_in[14];
  float* out = (float*)d_out;
  float* ws  = (float*)d_ws;

  float* u    = ws + OFF_U;
  float* zx   = ws + OFF_ZX;
  float* dtb  = ws + OFF_DT;
  float* dAb  = ws + OFF_DA;
  float* xc   = ws + OFF_XC;
  float* yb   = ws + OFF_Y;
  float* yc1a = ws + OFF_YC1A;
  float* yc1b = ws + OFF_YC1B;
  float* om   = u;  // u dead after in_proj GEMM

  // 1. front conv + relu -> u (b,t,256)
  k_front<<<dim3(128, 8), 256, 0, stream>>>(x, conv_w, conv_b, u);
  // 2. in_proj: zx = u @ W^T  (16376 x 1288, K=256)
  gemm_nt<<<dim3(11, 128), 256, 0, stream>>>(u, in_proj_w, zx, M_TOK, D_IN_PROJ, 256);
  // 3. dt / dA
  k_dt<<<dim3((M_TOK * NHEADS + 255) / 256), 256, 0, stream>>>(zx, dt_bias, A_log, dtb, dAb);
  // 4. depthwise causal conv + silu -> xc (b,t,768)
  k_dw<<<dim3((int)(((size_t)M_TOK * CONV_DIM + 255) / 256)), 256, 0, stream>>>(
      zx, conv1d_w, conv1d_b, xc);
  // 5. SSM scan -> yb (b,t,512)  (includes D_skip term)
  k_scan<<<dim3(64, 16), 64, 0, stream>>>(xc, dtb, dAb, D_skip, yb);
  // 6. gate + RMSNorm (in place)
  k_norm<<<dim3(M_TOK), 512, 0, stream>>>(yb, zx, norm_w);
  // 7. out_proj: om = yb @ Wout^T  (16376 x 256, K=512)
  gemm_nt<<<dim3(2, 128), 256, 0, stream>>>(yb, out_proj_w, om, M_TOK, 256, D_INNER);
  // 8. conv1 partials (ic split across z)
  k_conv1<<<dim3(16, 8, 2), 256, 0, stream>>>(om, conv1_w, yc1a, yc1b);
  // 9. transposed conv -> out
  k_convT<<<dim3(64, 4, 8), 256, 0, stream>>>(yc1a, yc1b, conv1_b, convT_w, convT_b, out);
}

// Round 2
// 919.179 us; speedup vs baseline: 1.1444x; 1.1444x over previous
//
#include <hip/hip_runtime.h>
#include <cstddef>
#include <cstdint>

// ---------------- problem constants ----------------
constexpr int L_IN   = 16384;
constexpr int L_SEQ  = 2047;          // (16384-16)/8 + 1
constexpr int BATCH  = 8;
constexpr int M_TOK  = BATCH * L_SEQ; // 16376
constexpr int D_INNER = 512;
constexpr int NHEADS  = 8;
constexpr int HEADDIM = 64;
constexpr int D_STATE = 128;
constexpr int CONV_DIM = 768;
constexpr int D_IN_PROJ = 1288;

// chunked scan params
constexpr int LC  = 256;              // chunk length
constexpr int NCH = 8;                // ceil(2047/256)

// ---------------- workspace layout (floats) ----------------
constexpr size_t OFF_U    = 0;                       // 16376*256   = 4,192,256
constexpr size_t OFF_ZX   = OFF_U   + 4192256;       // 16376*1288  = 21,092,288
constexpr size_t OFF_DT   = OFF_ZX  + 21092288;      // 16376*8     = 131,008
constexpr size_t OFF_DA   = OFF_DT  + 131008;
constexpr size_t OFF_XC   = OFF_DA  + 131008;        // 16376*768   = 12,576,768
constexpr size_t OFF_Y    = OFF_XC  + 12576768;      // 16376*512   = 8,384,512
constexpr size_t OFF_YC1A = OFF_Y   + 8384512;       // 8*8*2047    = 131,008
constexpr size_t OFF_YC1B = OFF_YC1A + 131008;
// total ≈ 46.77M floats ≈ 187 MB
// Scan summaries HS (64 bh × 7 slots × 8192 = 3,670,016 floats) alias the u
// region (dead between in_proj GEMM and out_proj GEMM). P (512 floats)
// aliases yc1a (dead until k_conv1).

// ============================================================
// K1: front conv (4->256, K=16, stride 8, VALID) + ReLU, emit u[(b*L+t)*256 + c]
// ============================================================
__global__ __launch_bounds__(256) void k_front(const float* __restrict__ x,
    const float* __restrict__ w, const float* __restrict__ cb,
    float* __restrict__ u) {
  const int tb = blockIdx.x;   // 128 tiles of 16 t
  const int b  = blockIdx.y;   // 8
  const int t0 = tb * 16;
  __shared__ float xs[4][136];
  for (int i = threadIdx.x; i < 4 * 136; i += 256) {
    int ic = i / 136, off = i % 136;
    int gi = t0 * 8 + off;
    xs[ic][off] = (gi < L_IN) ? x[((size_t)b * 4 + ic) * L_IN + gi] : 0.f;
  }
  __syncthreads();
  const int c = threadIdx.x;
  float wreg[64];
#pragma unroll
  for (int q = 0; q < 16; q++)
    *(float4*)&wreg[q * 4] = *(const float4*)(w + (size_t)c * 64 + q * 4);
  const float base = cb[c];
  float acc[16];
#pragma unroll
  for (int ts = 0; ts < 16; ts++) acc[ts] = base;
#pragma unroll
  for (int ic = 0; ic < 4; ic++) {
#pragma unroll
    for (int ts = 0; ts < 16; ts++) {
#pragma unroll
      for (int k = 0; k < 16; k++)
        acc[ts] = fmaf(xs[ic][ts * 8 + k], wreg[ic * 16 + k], acc[ts]);
    }
  }
#pragma unroll
  for (int ts = 0; ts < 16; ts++) {
    int t = t0 + ts;
    if (t < L_SEQ)
      u[((size_t)b * L_SEQ + t) * 256 + c] = fmaxf(acc[ts], 0.f);
  }
}

// ============================================================
// K2/K7: fp32 GEMM  C[m][n] = sum_k A[m*K+k]*B[n*K+k]   (NT, both K-contig)
// ============================================================
__global__ __launch_bounds__(256) void gemm_nt(const float* __restrict__ A,
    const float* __restrict__ B, float* __restrict__ C,
    int M, int N, int K) {
  __shared__ float As[16][132];
  __shared__ float Bs[16][132];
  const int tid = threadIdx.x;
  const int tx = tid & 15, ty = tid >> 4;
  const int m0 = blockIdx.y * 128, n0 = blockIdx.x * 128;
  const int arow = tid >> 1;        // 0..127
  const int akq  = (tid & 1) * 8;   // 0 or 8
  float acc[8][8] = {};
  for (int k0 = 0; k0 < K; k0 += 16) {
    float4 av0 = {0,0,0,0}, av1 = {0,0,0,0}, bv0 = {0,0,0,0}, bv1 = {0,0,0,0};
    int gm = m0 + arow;
    if (gm < M) {
      const float* p = A + (size_t)gm * K + k0 + akq;
      av0 = *(const float4*)p; av1 = *(const float4*)(p + 4);
    }
    int gn = n0 + arow;
    if (gn < N) {
      const float* p = B + (size_t)gn * K + k0 + akq;
      bv0 = *(const float4*)p; bv1 = *(const float4*)(p + 4);
    }
    __syncthreads();
    As[akq+0][arow]=av0.x; As[akq+1][arow]=av0.y; As[akq+2][arow]=av0.z; As[akq+3][arow]=av0.w;
    As[akq+4][arow]=av1.x; As[akq+5][arow]=av1.y; As[akq+6][arow]=av1.z; As[akq+7][arow]=av1.w;
    Bs[akq+0][arow]=bv0.x; Bs[akq+1][arow]=bv0.y; Bs[akq+2][arow]=bv0.z; Bs[akq+3][arow]=bv0.w;
    Bs[akq+4][arow]=bv1.x; Bs[akq+5][arow]=bv1.y; Bs[akq+6][arow]=bv1.z; Bs[akq+7][arow]=bv1.w;
    __syncthreads();
#pragma unroll
    for (int k = 0; k < 16; k++) {
      float a[8], bb[8];
      *(float4*)&a[0]  = *(const float4*)&As[k][ty * 8];
      *(float4*)&a[4]  = *(const float4*)&As[k][ty * 8 + 4];
      *(float4*)&bb[0] = *(const float4*)&Bs[k][tx * 8];
      *(float4*)&bb[4] = *(const float4*)&Bs[k][tx * 8 + 4];
#pragma unroll
      for (int i = 0; i < 8; i++)
#pragma unroll
        for (int j = 0; j < 8; j++)
          acc[i][j] = fmaf(a[i], bb[j], acc[i][j]);
    }
  }
#pragma unroll
  for (int i = 0; i < 8; i++) {
    int gm = m0 + ty * 8 + i;
    if (gm >= M) break;
    float* crow = C + (size_t)gm * N;
#pragma unroll
    for (int j = 0; j < 8; j++) {
      int gn = n0 + tx * 8 + j;
      if (gn < N) crow[gn] = acc[i][j];
    }
  }
}

// ============================================================
// K3: dt = softplus(zx[:,1280+h] + dt_bias[h]); dA = exp(-exp(A_log[h])*dt)
// ============================================================
__global__ void k_dt(const float* __restrict__ zx, const float* __restrict__ dt_bias,
                     const float* __restrict__ A_log, float* __restrict__ dt,
                     float* __restrict__ dA) {
  int i = blockIdx.x * 256 + threadIdx.x;
  if (i >= M_TOK * NHEADS) return;
  int hd = i & 7;
  int row = i >> 3;
  float v = zx[(size_t)row * D_IN_PROJ + (D_INNER + CONV_DIM) + hd] + dt_bias[hd];
  float sp = (v > 20.f) ? v : log1pf(expf(v));
  dt[i] = sp;
  dA[i] = expf(-expf(A_log[hd]) * sp);
}

// ============================================================
// K4: depthwise causal conv (D_CONV=4, left pad 3) + bias + silu
// ============================================================
__global__ void k_dw(const float* __restrict__ zx, const float* __restrict__ w,
                     const float* __restrict__ bias, float* __restrict__ xc) {
  size_t idx = (size_t)blockIdx.x * 256 + threadIdx.x;
  if (idx >= (size_t)M_TOK * CONV_DIM) return;
  int c = (int)(idx % CONV_DIM);
  int row = (int)(idx / CONV_DIM);
  int t = row % L_SEQ, b = row / L_SEQ;
  float acc = bias[c];
#pragma unroll
  for (int k = 0; k < 4; k++) {
    int tt = t - 3 + k;
    if (tt >= 0)
      acc = fmaf(zx[((size_t)b * L_SEQ + tt) * D_IN_PROJ + D_INNER + c], w[c * 4 + k], acc);
  }
  xc[(size_t)row * CONV_DIM + c] = acc / (1.f + expf(-acc));
}

// ============================================================
// K5: chunked SSM scan (3 passes).
//   lane = ps*16+ns: p = pw*4+ps, n = ns*8..+8 ; 4 waves/block (pw = by*4+wave)
// ============================================================
template<int CTRL>
__device__ __forceinline__ float dppadd(float x) {
  int v = __builtin_amdgcn_update_dpp(0, __float_as_int(x), CTRL, 0xf, 0xf, true);
  return x + __int_as_float(v);
}

struct Pref  { float4 B0, B1, C0, C1; float xv, dAv, dtv; };
struct PrefA { float4 B0, B1; float xv, dAv, dtv; };

#define LDP(S, T) { const float* r = xc + (rowbase + (size_t)(T)) * CONV_DIM;          \
  S.B0 = *(const float4*)(r + 512 + nb); S.B1 = *(const float4*)(r + 516 + nb);        \
  S.C0 = *(const float4*)(r + 640 + nb); S.C1 = *(const float4*)(r + 644 + nb);        \
  S.xv = r[hp];                                                                        \
  S.dAv = dA[(rowbase + (size_t)(T)) * 8 + h];                                         \
  S.dtv = dt[(rowbase + (size_t)(T)) * 8 + h]; }

#define LDPA(S, T) { const float* r = xc + (rowbase + (size_t)(T)) * CONV_DIM;         \
  S.B0 = *(const float4*)(r + 512 + nb); S.B1 = *(const float4*)(r + 516 + nb);        \
  S.xv = r[hp];                                                                        \
  S.dAv = dA[(rowbase + (size_t)(T)) * 8 + h];                                         \
  S.dtv = dt[(rowbase + (size_t)(T)) * 8 + h]; }

#define STEP(S, T) { float coef = S.dtv * S.xv;                                        \
  hs[0] = fmaf(hs[0], S.dAv, coef * S.B0.x); hs[1] = fmaf(hs[1], S.dAv, coef * S.B0.y);\
  hs[2] = fmaf(hs[2], S.dAv, coef * S.B0.z); hs[3] = fmaf(hs[3], S.dAv, coef * S.B0.w);\
  hs[4] = fmaf(hs[4], S.dAv, coef * S.B1.x); hs[5] = fmaf(hs[5], S.dAv, coef * S.B1.y);\
  hs[6] = fmaf(hs[6], S.dAv, coef * S.B1.z); hs[7] = fmaf(hs[7], S.dAv, coef * S.B1.w);\
  float acc = hs[0]*S.C0.x + hs[1]*S.C0.y + hs[2]*S.C0.z + hs[3]*S.C0.w                \
            + hs[4]*S.C1.x + hs[5]*S.C1.y + hs[6]*S.C1.z + hs[7]*S.C1.w;               \
  acc = dppadd<0x128>(acc); acc = dppadd<0x124>(acc);                                  \
  acc = dppadd<0x122>(acc); acc = dppadd<0x121>(acc);                                  \
  if (ns == 0) y[(rowbase + (size_t)(T)) * D_INNER + hp] = acc + Dsk * S.xv; }

#define STEPA(S) { float coef = S.dtv * S.xv;                                          \
  hs[0] = fmaf(hs[0], S.dAv, coef * S.B0.x); hs[1] = fmaf(hs[1], S.dAv, coef * S.B0.y);\
  hs[2] = fmaf(hs[2], S.dAv, coef * S.B0.z); hs[3] = fmaf(hs[3], S.dAv, coef * S.B0.w);\
  hs[4] = fmaf(hs[4], S.dAv, coef * S.B1.x); hs[5] = fmaf(hs[5], S.dAv, coef * S.B1.y);\
  hs[6] = fmaf(hs[6], S.dAv, coef * S.B1.z); hs[7] = fmaf(hs[7], S.dAv, coef * S.B1.w);\
  pr *= S.dAv; }

// Pass A: local scans for chunks 0..6 -> summaries S (into HS) and P
__global__ __launch_bounds__(256) void k_scanA(const float* __restrict__ xc,
    const float* __restrict__ dt, const float* __restrict__ dA,
    float* __restrict__ HS, float* __restrict__ Pbuf) {
  const int bh = blockIdx.x;                 // 64
  const int pw = blockIdx.y * 4 + (threadIdx.x >> 6);  // 0..15
  const int ch = blockIdx.z;                 // 0..6
  const int b = bh >> 3, h = bh & 7;
  const int lane = threadIdx.x & 63;
  const int ps = lane >> 4, ns = lane & 15;
  const int p  = pw * 4 + ps;
  const int nb = ns * 8;
  const int hp = h * 64 + p;
  const size_t rowbase = (size_t)b * L_SEQ;
  const int t0 = ch * LC, t1 = t0 + LC;      // all pass-A chunks full (<=1792)
  float hs[8] = {0, 0, 0, 0, 0, 0, 0, 0};
  float pr = 1.f;
  PrefA s0, s1, s2;
  LDPA(s0, t0); LDPA(s1, t0 + 1); LDPA(s2, t0 + 2);
  int t = t0;
  for (; t + 3 <= t1; t += 3) {
    STEPA(s0); if (t + 3 < t1) LDPA(s0, t + 3);
    STEPA(s1); if (t + 4 < t1) LDPA(s1, t + 4);
    STEPA(s2); if (t + 5 < t1) LDPA(s2, t + 5);
  }
  if (t     < t1) { STEPA(s0); }
  if (t + 1 < t1) { STEPA(s1); }
  float* Sp = HS + (((size_t)bh * 7 + ch) * 8192) + (size_t)p * 128 + nb;
  *(float4*)Sp       = *(float4*)&hs[0];
  *(float4*)(Sp + 4) = *(float4*)&hs[4];
  if (threadIdx.x == 0 && blockIdx.y == 0) Pbuf[bh * 8 + ch] = pr;
}

// Pass B: in-place sequential combine: slot[c] becomes Hin for chunk c+1
__global__ __launch_bounds__(256) void k_scanB(float* __restrict__ HS,
                                               const float* __restrict__ Pbuf) {
  const int bh = blockIdx.y;
  const int e  = blockIdx.x * 256 + threadIdx.x;   // 0..8191 (grid.x = 32)
  float run = 0.f;
#pragma unroll
  for (int c = 0; c < 7; ++c) {
    size_t idx = ((size_t)bh * 7 + c) * 8192 + e;
    float s = HS[idx];                // read BEFORE overwrite (in-place safe)
    run = fmaf(Pbuf[bh * 8 + c], run, s);
    HS[idx] = run;                    // = Hin for chunk c+1
  }
}

// Pass C: full per-chunk scan with correct initial state, emits y
__global__ __launch_bounds__(256) void k_scanC(const float* __restrict__ xc,
    const float* __restrict__ dt, const float* __restrict__ dA,
    const float* __restrict__ Dskip, const float* __restrict__ HS,
    float* __restrict__ y) {
  const int bh = blockIdx.x;                 // 64
  const int pw = blockIdx.y * 4 + (threadIdx.x >> 6);
  const int ch = blockIdx.z;                 // 0..7
  const int b = bh >> 3, h = bh & 7;
  const int lane = threadIdx.x & 63;
  const int ps = lane >> 4, ns = lane & 15;
  const int p  = pw * 4 + ps;
  const int nb = ns * 8;
  const int hp = h * 64 + p;
  const float Dsk = Dskip[h];
  const size_t rowbase = (size_t)b * L_SEQ;
  const int t0 = ch * LC;
  const int t1 = (t0 + LC < L_SEQ) ? t0 + LC : L_SEQ;
  float hs[8];
  if (ch == 0) {
#pragma unroll
    for (int i = 0; i < 8; i++) hs[i] = 0.f;
  } else {
    const float* Hp = HS + (((size_t)bh * 7 + (ch - 1)) * 8192) + (size_t)p * 128 + nb;
    *(float4*)&hs[0] = *(const float4*)Hp;
    *(float4*)&hs[4] = *(const float4*)(Hp + 4);
  }
  Pref s0, s1, s2;
  LDP(s0, t0); LDP(s1, t0 + 1); LDP(s2, t0 + 2);
  int t = t0;
  for (; t + 3 <= t1; t += 3) {
    STEP(s0, t);     if (t + 3 < t1) LDP(s0, t + 3);
    STEP(s1, t + 1); if (t + 4 < t1) LDP(s1, t + 4);
    STEP(s2, t + 2); if (t + 5 < t1) LDP(s2, t + 5);
  }
  if (t     < t1) { STEP(s0, t); }
  if (t + 1 < t1) { STEP(s1, t + 1); }
}

// ============================================================
// K6: y = y*silu(z); y *= rsqrt(mean(y^2)+1e-5)*norm_w   (in-place, row=512)
// ============================================================
__global__ __launch_bounds__(512) void k_norm(float* __restrict__ y,
    const float* __restrict__ zx, const float* __restrict__ norm_w) {
  const int row = blockIdx.x;
  const int c = threadIdx.x;
  float z = zx[(size_t)row * D_IN_PROJ + c];
  float g = z / (1.f + expf(-z));
  float v = y[(size_t)row * D_INNER + c] * g;
  float ss = v * v;
#pragma unroll
  for (int m = 32; m >= 1; m >>= 1) ss += __shfl_xor(ss, m, 64);
  __shared__ float red[8];
  if ((threadIdx.x & 63) == 0) red[threadIdx.x >> 6] = ss;
  __syncthreads();
  float tot = 0.f;
#pragma unroll
  for (int i = 0; i < 8; i++) tot += red[i];
  float scale = rsqrtf(tot * (1.f / 512.f) + 1e-5f);
  y[(size_t)row * D_INNER + c] = v * scale * norm_w[c];
}

// ============================================================
// K8: conv1 (256->8ch, K=16, pad(7,8)) — partial over ic halves, no bias
// ============================================================
__global__ __launch_bounds__(256) void k_conv1(const float* __restrict__ om,
    const float* __restrict__ w, float* __restrict__ yc1a, float* __restrict__ yc1b) {
  const int tt = blockIdx.x, b = blockIdx.y, zc = blockIdx.z;
  const int t0 = tt * 128;
  const int tsub = threadIdx.x >> 1;     // 0..127
  const int ochalf = threadIdx.x & 1;    // 0..1 -> oc base
  __shared__ float inl[143][65];
  __shared__ float wl[64][16][8];
  float acc[4] = {0, 0, 0, 0};
  for (int cc2 = 0; cc2 < 2; cc2++) {
    const int icc = zc * 2 + cc2;        // ic chunk of 64
    __syncthreads();
    for (int i = threadIdx.x; i < 143 * 64; i += 256) {
      int r = i >> 6, cc = i & 63;
      int tin = t0 - 7 + r;
      float v = 0.f;
      if (tin >= 0 && tin < L_SEQ)
        v = om[((size_t)b * L_SEQ + tin) * 256 + icc * 64 + cc];
      inl[r][cc] = v;
    }
    for (int i = threadIdx.x; i < 64 * 16 * 8; i += 256) {
      int oc = i & 7, k = (i >> 3) & 15, ic = i >> 7;
      wl[ic][k][oc] = w[((size_t)oc * 256 + icc * 64 + ic) * 16 + k];
    }
    __syncthreads();
    for (int ic = 0; ic < 64; ic++) {
#pragma unroll
      for (int k = 0; k < 16; k++) {
        float iv = inl[tsub + k][ic];
        float4 wv = *(const float4*)&wl[ic][k][ochalf * 4];
        acc[0] = fmaf(iv, wv.x, acc[0]);
        acc[1] = fmaf(iv, wv.y, acc[1]);
        acc[2] = fmaf(iv, wv.z, acc[2]);
        acc[3] = fmaf(iv, wv.w, acc[3]);
      }
    }
  }
  int t = t0 + tsub;
  if (t < L_SEQ) {
    float* dst = (zc == 0) ? yc1a : yc1b;
#pragma unroll
    for (int j = 0; j < 4; j++)
      dst[((size_t)b * 8 + ochalf * 4 + j) * L_SEQ + t] = acc[j];
  }
}

// ============================================================
// K9: transposed conv (8->4ch, K=16, lhs_dilation=8, pad 15/15)
// ============================================================
__global__ void k_convT(const float* __restrict__ yc1a, const float* __restrict__ yc1b,
                        const float* __restrict__ b1, const float* __restrict__ wT,
                        const float* __restrict__ bT, float* __restrict__ out) {
  const int s = blockIdx.x * 256 + threadIdx.x;  // 16384
  const int c = blockIdx.y, b = blockIdx.z;
  float acc = bT[c];
  const int k0 = (15 - (s & 7)) & 7;
#pragma unroll
  for (int dk = 0; dk < 2; dk++) {
    int k = k0 + 8 * dk;
    int num = s - 15 + k;          // divisible by 8 by construction
    int m = num >> 3;
    if (num >= 0 && m < L_SEQ) {
#pragma unroll
      for (int j = 0; j < 8; j++) {
        float v = yc1a[((size_t)b * 8 + j) * L_SEQ + m]
                + yc1b[((size_t)b * 8 + j) * L_SEQ + m] + b1[j];
        acc = fmaf(v, wT[((size_t)j * 4 + c) * 16 + (15 - k)], acc);
      }
    }
  }
  out[((size_t)b * 4 + c) * L_IN + s] = acc;
}

// ============================================================
extern "C" void kernel_launch(void* const* d_in, const int* in_sizes, int n_in,
                              void* d_out, int out_size, void* d_ws, size_t ws_size,
                              hipStream_t stream) {
  const float* x         = (const float*)d_in[0];
  const float* conv_w    = (const float*)d_in[1];
  const float* conv_b    = (const float*)d_in[2];
  const float* in_proj_w = (const float*)d_in[3];
  const float* conv1d_w  = (const float*)d_in[4];
  const float* conv1d_b  = (const float*)d_in[5];
  const float* dt_bias   = (const float*)d_in[6];
  const float* A_log     = (const float*)d_in[7];
  const float* D_skip    = (const float*)d_in[8];
  const float* norm_w    = (const float*)d_in[9];
  const float* out_proj_w= (const float*)d_in[10];
  const float* conv1_w   = (const float*)d_in[11];
  const float* conv1_b   = (const float*)d_in[12];
  const float* convT_w   = (const float*)d_in[13];
  const float* convT_b   = (const float*)d_in[14];
  float* out = (float*)d_out;
  float* ws  = (float*)d_ws;

  float* u    = ws + OFF_U;
  float* zx   = ws + OFF_ZX;
  float* dtb  = ws + OFF_DT;
  float* dAb  = ws + OFF_DA;
  float* xc   = ws + OFF_XC;
  float* yb   = ws + OFF_Y;
  float* yc1a = ws + OFF_YC1A;
  float* yc1b = ws + OFF_YC1B;
  float* om   = u;            // u dead after in_proj GEMM
  float* HS   = u;            // scan summaries alias u region (3.67M < 4.19M floats)
  float* Pbuf = yc1a;         // 512 floats, yc1a dead until k_conv1

  // 1. front conv + relu -> u (b,t,256)
  k_front<<<dim3(128, 8), 256, 0, stream>>>(x, conv_w, conv_b, u);
  // 2. in_proj: zx = u @ W^T  (16376 x 1288, K=256)
  gemm_nt<<<dim3(11, 128), 256, 0, stream>>>(u, in_proj_w, zx, M_TOK, D_IN_PROJ, 256);
  // 3. dt / dA
  k_dt<<<dim3((M_TOK * NHEADS + 255) / 256), 256, 0, stream>>>(zx, dt_bias, A_log, dtb, dAb);
  // 4. depthwise causal conv + silu -> xc (b,t,768)
  k_dw<<<dim3((int)(((size_t)M_TOK * CONV_DIM + 255) / 256)), 256, 0, stream>>>(
      zx, conv1d_w, conv1d_b, xc);
  // 5. chunked SSM scan -> yb
  k_scanA<<<dim3(64, 4, 7), 256, 0, stream>>>(xc, dtb, dAb, HS, Pbuf);
  k_scanB<<<dim3(32, 64), 256, 0, stream>>>(HS, Pbuf);
  k_scanC<<<dim3(64, 4, 8), 256, 0, stream>>>(xc, dtb, dAb, D_skip, HS, yb);
  // 6. gate + RMSNorm (in place)
  k_norm<<<dim3(M_TOK), 512, 0, stream>>>(yb, zx, norm_w);
  // 7. out_proj: om = yb @ Wout^T  (16376 x 256, K=512)
  gemm_nt<<<dim3(2, 128), 256, 0, stream>>>(yb, out_proj_w, om, M_TOK, 256, D_INNER);
  // 8. conv1 partials (ic split across z)
  k_conv1<<<dim3(16, 8, 2), 256, 0, stream>>>(om, conv1_w, yc1a, yc1b);
  // 9. transposed conv -> out
  k_convT<<<dim3(64, 4, 8), 256, 0, stream>>>(yc1a, yc1b, conv1_b, convT_w, convT_b, out);
}

// Round 3
// 616.206 us; speedup vs baseline: 1.7070x; 1.4917x over previous
//
#include <hip/hip_runtime.h>
#include <cstddef>
#include <cstdint>

// ---------------- problem constants ----------------
constexpr int L_IN   = 16384;
constexpr int L_SEQ  = 2047;          // (16384-16)/8 + 1
constexpr int BATCH  = 8;
constexpr int M_TOK  = BATCH * L_SEQ; // 16376
constexpr int D_INNER = 512;
constexpr int NHEADS  = 8;
constexpr int HEADDIM = 64;
constexpr int D_STATE = 128;
constexpr int CONV_DIM = 768;
constexpr int D_IN_PROJ = 1288;

// SSD chunking
constexpr int QC  = 64;               // chunk length
constexpr int NCH = 32;               // 32*64 = 2048 >= 2047

// ---------------- workspace layout (floats) ----------------
constexpr size_t OFF_U    = 0;                       // 16376*256   = 4,192,256
constexpr size_t OFF_ZX   = OFF_U   + 4192256;       // 16376*1288  = 21,092,288
constexpr size_t OFF_DT   = OFF_ZX  + 21092288;      // 16376*8
constexpr size_t OFF_AW   = OFF_DT  + 131008;        // a = log(dA) (replaces dA)
constexpr size_t OFF_XC   = OFF_AW  + 131008;        // 16376*768
constexpr size_t OFF_Y    = OFF_XC  + 12576768;      // 16376*512
constexpr size_t OFF_YC1A = OFF_Y   + 8384512;       // 8*8*2047
constexpr size_t OFF_YC1B = OFF_YC1A + 131008;
constexpr size_t OFF_HS   = OFF_YC1B + 131008;       // 64bh*32ch*8192 = 16,777,216
// total = 63,547,072 floats ~= 254.2 MB.  ASSUMES ws_size >= 255MB.
// (fallback if this fails: bf16 states aliased into zx's dead xBC columns)

using short8 = __attribute__((ext_vector_type(8))) short;  // 8 bf16
using f32x4  = __attribute__((ext_vector_type(4))) float;
typedef unsigned short ushort_t;

__device__ __forceinline__ ushort_t f2bf(float f) {        // RNE f32->bf16
  uint32_t u = __float_as_uint(f);
  u += 0x7fffu + ((u >> 16) & 1u);
  return (ushort_t)(u >> 16);
}
__device__ __forceinline__ float bf2f(ushort_t h) {
  return __uint_as_float(((uint32_t)h) << 16);
}
#define MFMA16(a, b, c) __builtin_amdgcn_mfma_f32_16x16x32_bf16(a, b, c, 0, 0, 0)

// ============================================================
// K1: front conv (4->256, K=16, stride 8, VALID) + ReLU
// ============================================================
__global__ __launch_bounds__(256) void k_front(const float* __restrict__ x,
    const float* __restrict__ w, const float* __restrict__ cb,
    float* __restrict__ u) {
  const int tb = blockIdx.x;
  const int b  = blockIdx.y;
  const int t0 = tb * 16;
  __shared__ float xs[4][136];
  for (int i = threadIdx.x; i < 4 * 136; i += 256) {
    int ic = i / 136, off = i % 136;
    int gi = t0 * 8 + off;
    xs[ic][off] = (gi < L_IN) ? x[((size_t)b * 4 + ic) * L_IN + gi] : 0.f;
  }
  __syncthreads();
  const int c = threadIdx.x;
  float wreg[64];
#pragma unroll
  for (int q = 0; q < 16; q++)
    *(float4*)&wreg[q * 4] = *(const float4*)(w + (size_t)c * 64 + q * 4);
  const float base = cb[c];
  float acc[16];
#pragma unroll
  for (int ts = 0; ts < 16; ts++) acc[ts] = base;
#pragma unroll
  for (int ic = 0; ic < 4; ic++) {
#pragma unroll
    for (int ts = 0; ts < 16; ts++) {
#pragma unroll
      for (int k = 0; k < 16; k++)
        acc[ts] = fmaf(xs[ic][ts * 8 + k], wreg[ic * 16 + k], acc[ts]);
    }
  }
#pragma unroll
  for (int ts = 0; ts < 16; ts++) {
    int t = t0 + ts;
    if (t < L_SEQ)
      u[((size_t)b * L_SEQ + t) * 256 + c] = fmaxf(acc[ts], 0.f);
  }
}

// ============================================================
// K2/K7: fp32 GEMM NT (unchanged this round)
// ============================================================
__global__ __launch_bounds__(256) void gemm_nt(const float* __restrict__ A,
    const float* __restrict__ B, float* __restrict__ C,
    int M, int N, int K) {
  __shared__ float As[16][132];
  __shared__ float Bs[16][132];
  const int tid = threadIdx.x;
  const int tx = tid & 15, ty = tid >> 4;
  const int m0 = blockIdx.y * 128, n0 = blockIdx.x * 128;
  const int arow = tid >> 1;
  const int akq  = (tid & 1) * 8;
  float acc[8][8] = {};
  for (int k0 = 0; k0 < K; k0 += 16) {
    float4 av0 = {0,0,0,0}, av1 = {0,0,0,0}, bv0 = {0,0,0,0}, bv1 = {0,0,0,0};
    int gm = m0 + arow;
    if (gm < M) {
      const float* p = A + (size_t)gm * K + k0 + akq;
      av0 = *(const float4*)p; av1 = *(const float4*)(p + 4);
    }
    int gn = n0 + arow;
    if (gn < N) {
      const float* p = B + (size_t)gn * K + k0 + akq;
      bv0 = *(const float4*)p; bv1 = *(const float4*)(p + 4);
    }
    __syncthreads();
    As[akq+0][arow]=av0.x; As[akq+1][arow]=av0.y; As[akq+2][arow]=av0.z; As[akq+3][arow]=av0.w;
    As[akq+4][arow]=av1.x; As[akq+5][arow]=av1.y; As[akq+6][arow]=av1.z; As[akq+7][arow]=av1.w;
    Bs[akq+0][arow]=bv0.x; Bs[akq+1][arow]=bv0.y; Bs[akq+2][arow]=bv0.z; Bs[akq+3][arow]=bv0.w;
    Bs[akq+4][arow]=bv1.x; Bs[akq+5][arow]=bv1.y; Bs[akq+6][arow]=bv1.z; Bs[akq+7][arow]=bv1.w;
    __syncthreads();
#pragma unroll
    for (int k = 0; k < 16; k++) {
      float a[8], bb[8];
      *(float4*)&a[0]  = *(const float4*)&As[k][ty * 8];
      *(float4*)&a[4]  = *(const float4*)&As[k][ty * 8 + 4];
      *(float4*)&bb[0] = *(const float4*)&Bs[k][tx * 8];
      *(float4*)&bb[4] = *(const float4*)&Bs[k][tx * 8 + 4];
#pragma unroll
      for (int i = 0; i < 8; i++)
#pragma unroll
        for (int j = 0; j < 8; j++)
          acc[i][j] = fmaf(a[i], bb[j], acc[i][j]);
    }
  }
#pragma unroll
  for (int i = 0; i < 8; i++) {
    int gm = m0 + ty * 8 + i;
    if (gm >= M) break;
    float* crow = C + (size_t)gm * N;
#pragma unroll
    for (int j = 0; j < 8; j++) {
      int gn = n0 + tx * 8 + j;
      if (gn < N) crow[gn] = acc[i][j];
    }
  }
}

// ============================================================
// K3: dt = softplus(...); a = log dA = -exp(A_log)*dt
// ============================================================
__global__ void k_dt(const float* __restrict__ zx, const float* __restrict__ dt_bias,
                     const float* __restrict__ A_log, float* __restrict__ dt,
                     float* __restrict__ aw) {
  int i = blockIdx.x * 256 + threadIdx.x;
  if (i >= M_TOK * NHEADS) return;
  int hd = i & 7;
  int row = i >> 3;
  float v = zx[(size_t)row * D_IN_PROJ + (D_INNER + CONV_DIM) + hd] + dt_bias[hd];
  float sp = (v > 20.f) ? v : log1pf(expf(v));
  dt[i] = sp;
  aw[i] = -expf(A_log[hd]) * sp;
}

// ============================================================
// K4: depthwise causal conv + bias + silu
// ============================================================
__global__ void k_dw(const float* __restrict__ zx, const float* __restrict__ w,
                     const float* __restrict__ bias, float* __restrict__ xc) {
  size_t idx = (size_t)blockIdx.x * 256 + threadIdx.x;
  if (idx >= (size_t)M_TOK * CONV_DIM) return;
  int c = (int)(idx % CONV_DIM);
  int row = (int)(idx / CONV_DIM);
  int t = row % L_SEQ, b = row / L_SEQ;
  float acc = bias[c];
#pragma unroll
  for (int k = 0; k < 4; k++) {
    int tt = t - 3 + k;
    if (tt >= 0)
      acc = fmaf(zx[((size_t)b * L_SEQ + tt) * D_IN_PROJ + D_INNER + c], w[c * 4 + k], acc);
  }
  xc[(size_t)row * CONV_DIM + c] = acc / (1.f + expf(-acc));
}

// ============================================================
// K5a: SSD chunk state summaries.  Ssum[n][p] = sum_s B[s][n]*w_s*x[s][p],
//      w_s = exp(Ltot - Lrel_s)*dt_s.  One block per (chunk, bh), 4 waves.
// ============================================================
__global__ __launch_bounds__(256) void k_ssd_state(const float* __restrict__ xc,
    const float* __restrict__ dtb, const float* __restrict__ aw,
    float* __restrict__ HS, float* __restrict__ Pbuf) {
  const int ch = blockIdx.x, bh = blockIdx.y;
  const int b = bh >> 3, h = bh & 7;
  const int t0 = ch * QC;
  const int valid = (L_SEQ - t0 < QC) ? (L_SEQ - t0) : QC;
  const size_t rowbase = (size_t)b * L_SEQ;
  __shared__ __attribute__((aligned(16))) short sBT[128][72];  // [n][s]
  __shared__ __attribute__((aligned(16))) short sXw[64][72];   // [p][s], w-scaled
  __shared__ float sW[64];
  __shared__ float sLtot;
  const int tid = threadIdx.x;
  if (tid < 64) {
    float aa = 0.f, dd = 0.f;
    if (tid < valid) { size_t r8 = (rowbase + t0 + tid) * 8 + h; aa = aw[r8]; dd = dtb[r8]; }
    float s = aa;
#pragma unroll
    for (int d = 1; d < 64; d <<= 1) { float o = __shfl_up(s, d, 64); if (tid >= d) s += o; }
    float Lt = __shfl(s, 63, 64);
    sW[tid] = expf(Lt - s) * dd;      // exp arg <= 0: safe
    if (tid == 63) sLtot = s;
  }
  __syncthreads();
  for (int i = tid; i < 64 * 32; i += 256) {     // B transpose-stage
    int r = i >> 5, q = (i & 31) * 4;
    float4 v = {0, 0, 0, 0};
    if (r < valid) v = *(const float4*)(xc + (rowbase + t0 + r) * CONV_DIM + 512 + q);
    sBT[q + 0][r] = (short)f2bf(v.x); sBT[q + 1][r] = (short)f2bf(v.y);
    sBT[q + 2][r] = (short)f2bf(v.z); sBT[q + 3][r] = (short)f2bf(v.w);
  }
  for (int i = tid; i < 64 * 16; i += 256) {     // Xw transpose-stage
    int r = i >> 4, q = (i & 15) * 4;
    float4 v = {0, 0, 0, 0};
    if (r < valid) v = *(const float4*)(xc + (rowbase + t0 + r) * CONV_DIM + h * 64 + q);
    float wv = sW[r];
    sXw[q + 0][r] = (short)f2bf(v.x * wv); sXw[q + 1][r] = (short)f2bf(v.y * wv);
    sXw[q + 2][r] = (short)f2bf(v.z * wv); sXw[q + 3][r] = (short)f2bf(v.w * wv);
  }
  __syncthreads();
  const int w = tid >> 6, l15 = tid & 15, lK = (tid & 63) >> 4;
  f32x4 acc[2][4] = {};
  short8 afr[2][2];
#pragma unroll
  for (int j = 0; j < 2; j++)
#pragma unroll
    for (int kt = 0; kt < 2; kt++)
      afr[j][kt] = *(const short8*)&sBT[(w * 2 + j) * 16 + l15][kt * 32 + lK * 8];
#pragma unroll
  for (int pt = 0; pt < 4; pt++) {
#pragma unroll
    for (int kt = 0; kt < 2; kt++) {
      short8 bfr = *(const short8*)&sXw[pt * 16 + l15][kt * 32 + lK * 8];
      acc[0][pt] = MFMA16(afr[0][kt], bfr, acc[0][pt]);
      acc[1][pt] = MFMA16(afr[1][kt], bfr, acc[1][pt]);
    }
  }
  float* dst = HS + ((size_t)bh * NCH + ch) * 8192;
#pragma unroll
  for (int j = 0; j < 2; j++)
#pragma unroll
    for (int pt = 0; pt < 4; pt++)
#pragma unroll
      for (int i = 0; i < 4; i++) {
        int n = (w * 2 + j) * 16 + lK * 4 + i, p = pt * 16 + l15;
        dst[n * 64 + p] = acc[j][pt][i];
      }
  if (tid == 0) Pbuf[bh * NCH + ch] = expf(sLtot);
}

// ============================================================
// K5b: sequential inter-chunk combine (in place).
//      After: HS slot c = state AFTER chunk c (= Hin of chunk c+1).
// ============================================================
__global__ __launch_bounds__(256) void k_ssd_comb(float* __restrict__ HS,
                                                  const float* __restrict__ Pbuf) {
  const int bh = blockIdx.y;
  const int e  = blockIdx.x * 256 + threadIdx.x;   // grid.x = 32 -> 8192
  float run = 0.f;
  for (int c = 0; c < NCH; c++) {
    size_t idx = ((size_t)bh * NCH + c) * 8192 + e;
    float s = HS[idx];
    run = fmaf(Pbuf[bh * NCH + c], run, s);
    HS[idx] = run;
  }
}

// ============================================================
// K5c: SSD output.  y = exp(Lrel_t)*(C@Hin) + (M o (C@B^T))@X + Dsk*x
// ============================================================
__global__ __launch_bounds__(256) void k_ssd_y(const float* __restrict__ xc,
    const float* __restrict__ dtb, const float* __restrict__ aw,
    const float* __restrict__ Dskip, const float* __restrict__ HS,
    float* __restrict__ y) {
  const int ch = blockIdx.x, bh = blockIdx.y;
  const int b = bh >> 3, h = bh & 7;
  const int t0 = ch * QC;
  const int valid = (L_SEQ - t0 < QC) ? (L_SEQ - t0) : QC;
  const size_t rowbase = (size_t)b * L_SEQ;
  __shared__ __attribute__((aligned(16))) short sB[64][136];   // [s][n]
  __shared__ __attribute__((aligned(16))) short sC[64][136];   // [t][n]
  __shared__ __attribute__((aligned(16))) short sH[64][136];   // [p][n] = Hin^T
  __shared__ __attribute__((aligned(16))) short sX[64][72];    // [p][t] = X^T
  __shared__ float sLrel[64], sdt[64], sEL[64];
  short (*sM)[72] = (short(*)[72])&sB[0][0];   // masked G, aliases sB after sync
  const int tid = threadIdx.x;
  if (tid < 64) {
    float aa = 0.f, dd = 0.f;
    if (tid < valid) { size_t r8 = (rowbase + t0 + tid) * 8 + h; aa = aw[r8]; dd = dtb[r8]; }
    float s = aa;
#pragma unroll
    for (int d = 1; d < 64; d <<= 1) { float o = __shfl_up(s, d, 64); if (tid >= d) s += o; }
    sLrel[tid] = s; sdt[tid] = dd; sEL[tid] = expf(s);
  }
  for (int i = tid; i < 64 * 32; i += 256) {   // B and C rows
    int r = i >> 5, q = (i & 31) * 4;
    float4 vb = {0, 0, 0, 0}, vc = {0, 0, 0, 0};
    if (r < valid) {
      const float* rp = xc + (rowbase + t0 + r) * CONV_DIM;
      vb = *(const float4*)(rp + 512 + q);
      vc = *(const float4*)(rp + 640 + q);
    }
    short* pb = &sB[r][q];
    pb[0] = (short)f2bf(vb.x); pb[1] = (short)f2bf(vb.y);
    pb[2] = (short)f2bf(vb.z); pb[3] = (short)f2bf(vb.w);
    short* pc = &sC[r][q];
    pc[0] = (short)f2bf(vc.x); pc[1] = (short)f2bf(vc.y);
    pc[2] = (short)f2bf(vc.z); pc[3] = (short)f2bf(vc.w);
  }
  for (int i = tid; i < 64 * 16; i += 256) {   // X transpose-stage
    int r = i >> 4, q = (i & 15) * 4;
    float4 v = {0, 0, 0, 0};
    if (r < valid) v = *(const float4*)(xc + (rowbase + t0 + r) * CONV_DIM + h * 64 + q);
    sX[q + 0][r] = (short)f2bf(v.x); sX[q + 1][r] = (short)f2bf(v.y);
    sX[q + 2][r] = (short)f2bf(v.z); sX[q + 3][r] = (short)f2bf(v.w);
  }
  for (int i = tid; i < 128 * 16; i += 256) {  // Hin transpose-stage
    int n = i >> 4, q = (i & 15) * 4;
    float4 v = {0, 0, 0, 0};
    if (ch > 0) v = *(const float4*)(HS + ((size_t)bh * NCH + (ch - 1)) * 8192 + n * 64 + q);
    sH[q + 0][n] = (short)f2bf(v.x); sH[q + 1][n] = (short)f2bf(v.y);
    sH[q + 2][n] = (short)f2bf(v.z); sH[q + 3][n] = (short)f2bf(v.w);
  }
  __syncthreads();
  const int w = tid >> 6, l15 = tid & 15, lK = (tid & 63) >> 4;
  short8 aC[4];
#pragma unroll
  for (int kt = 0; kt < 4; kt++)
    aC[kt] = *(const short8*)&sC[w * 16 + l15][kt * 32 + lK * 8];
  // G = C @ B^T  (wave w owns t-tile w)
  f32x4 g[4] = {};
#pragma unroll
  for (int st = 0; st < 4; st++)
#pragma unroll
    for (int kt = 0; kt < 4; kt++)
      g[st] = MFMA16(aC[kt], *(const short8*)&sB[st * 16 + l15][kt * 32 + lK * 8], g[st]);
  __syncthreads();                              // all G reads of sB done (sM aliases it)
  // mask + cast -> sM
#pragma unroll
  for (int st = 0; st < 4; st++)
#pragma unroll
    for (int i = 0; i < 4; i++) {
      int tt = w * 16 + lK * 4 + i, ss = st * 16 + l15;
      float f = (ss <= tt) ? expf(sLrel[tt] - sLrel[ss]) * sdt[ss] : 0.f;
      sM[tt][ss] = (short)f2bf(g[st][i] * f);
    }
  __syncthreads();
  // Y_inter = C @ Hin, then row-scale by exp(Lrel_t)
  f32x4 acc[4] = {};
#pragma unroll
  for (int pt = 0; pt < 4; pt++)
#pragma unroll
    for (int kt = 0; kt < 4; kt++)
      acc[pt] = MFMA16(aC[kt], *(const short8*)&sH[pt * 16 + l15][kt * 32 + lK * 8], acc[pt]);
#pragma unroll
  for (int pt = 0; pt < 4; pt++)
#pragma unroll
    for (int i = 0; i < 4; i++)
      acc[pt][i] *= sEL[w * 16 + lK * 4 + i];
  // Y_intra += M @ X
  short8 aM[2];
#pragma unroll
  for (int kt = 0; kt < 2; kt++)
    aM[kt] = *(const short8*)&sM[w * 16 + l15][kt * 32 + lK * 8];
#pragma unroll
  for (int pt = 0; pt < 4; pt++)
#pragma unroll
    for (int kt = 0; kt < 2; kt++)
      acc[pt] = MFMA16(aM[kt], *(const short8*)&sX[pt * 16 + l15][kt * 32 + lK * 8], acc[pt]);
  const float Dsk = Dskip[h];
#pragma unroll
  for (int pt = 0; pt < 4; pt++)
#pragma unroll
    for (int i = 0; i < 4; i++) {
      int tt = w * 16 + lK * 4 + i;
      if (tt < valid) {
        int pp = pt * 16 + l15;
        y[(rowbase + t0 + tt) * D_INNER + h * 64 + pp] =
            acc[pt][i] + Dsk * bf2f((ushort_t)sX[pp][tt]);
      }
    }
}

// ============================================================
// K6: gate + RMSNorm (in place)
// ============================================================
__global__ __launch_bounds__(512) void k_norm(float* __restrict__ y,
    const float* __restrict__ zx, const float* __restrict__ norm_w) {
  const int row = blockIdx.x;
  const int c = threadIdx.x;
  float z = zx[(size_t)row * D_IN_PROJ + c];
  float g = z / (1.f + expf(-z));
  float v = y[(size_t)row * D_INNER + c] * g;
  float ss = v * v;
#pragma unroll
  for (int m = 32; m >= 1; m >>= 1) ss += __shfl_xor(ss, m, 64);
  __shared__ float red[8];
  if ((threadIdx.x & 63) == 0) red[threadIdx.x >> 6] = ss;
  __syncthreads();
  float tot = 0.f;
#pragma unroll
  for (int i = 0; i < 8; i++) tot += red[i];
  float scale = rsqrtf(tot * (1.f / 512.f) + 1e-5f);
  y[(size_t)row * D_INNER + c] = v * scale * norm_w[c];
}

// ============================================================
// K8: conv1 (256->8ch, K=16, pad(7,8)) partials
// ============================================================
__global__ __launch_bounds__(256) void k_conv1(const float* __restrict__ om,
    const float* __restrict__ w, float* __restrict__ yc1a, float* __restrict__ yc1b) {
  const int tt = blockIdx.x, b = blockIdx.y, zc = blockIdx.z;
  const int t0 = tt * 128;
  const int tsub = threadIdx.x >> 1;
  const int ochalf = threadIdx.x & 1;
  __shared__ float inl[143][65];
  __shared__ float wl[64][16][8];
  float acc[4] = {0, 0, 0, 0};
  for (int cc2 = 0; cc2 < 2; cc2++) {
    const int icc = zc * 2 + cc2;
    __syncthreads();
    for (int i = threadIdx.x; i < 143 * 64; i += 256) {
      int r = i >> 6, cc = i & 63;
      int tin = t0 - 7 + r;
      float v = 0.f;
      if (tin >= 0 && tin < L_SEQ)
        v = om[((size_t)b * L_SEQ + tin) * 256 + icc * 64 + cc];
      inl[r][cc] = v;
    }
    for (int i = threadIdx.x; i < 64 * 16 * 8; i += 256) {
      int oc = i & 7, k = (i >> 3) & 15, ic = i >> 7;
      wl[ic][k][oc] = w[((size_t)oc * 256 + icc * 64 + ic) * 16 + k];
    }
    __syncthreads();
    for (int ic = 0; ic < 64; ic++) {
#pragma unroll
      for (int k = 0; k < 16; k++) {
        float iv = inl[tsub + k][ic];
        float4 wv = *(const float4*)&wl[ic][k][ochalf * 4];
        acc[0] = fmaf(iv, wv.x, acc[0]);
        acc[1] = fmaf(iv, wv.y, acc[1]);
        acc[2] = fmaf(iv, wv.z, acc[2]);
        acc[3] = fmaf(iv, wv.w, acc[3]);
      }
    }
  }
  int t = t0 + tsub;
  if (t < L_SEQ) {
    float* dst = (zc == 0) ? yc1a : yc1b;
#pragma unroll
    for (int j = 0; j < 4; j++)
      dst[((size_t)b * 8 + ochalf * 4 + j) * L_SEQ + t] = acc[j];
  }
}

// ============================================================
// K9: transposed conv (8->4ch, K=16, lhs_dilation=8, pad 15/15)
// ============================================================
__global__ void k_convT(const float* __restrict__ yc1a, const float* __restrict__ yc1b,
                        const float* __restrict__ b1, const float* __restrict__ wT,
                        const float* __restrict__ bT, float* __restrict__ out) {
  const int s = blockIdx.x * 256 + threadIdx.x;
  const int c = blockIdx.y, b = blockIdx.z;
  float acc = bT[c];
  const int k0 = (15 - (s & 7)) & 7;
#pragma unroll
  for (int dk = 0; dk < 2; dk++) {
    int k = k0 + 8 * dk;
    int num = s - 15 + k;
    int m = num >> 3;
    if (num >= 0 && m < L_SEQ) {
#pragma unroll
      for (int j = 0; j < 8; j++) {
        float v = yc1a[((size_t)b * 8 + j) * L_SEQ + m]
                + yc1b[((size_t)b * 8 + j) * L_SEQ + m] + b1[j];
        acc = fmaf(v, wT[((size_t)j * 4 + c) * 16 + (15 - k)], acc);
      }
    }
  }
  out[((size_t)b * 4 + c) * L_IN + s] = acc;
}

// ============================================================
extern "C" void kernel_launch(void* const* d_in, const int* in_sizes, int n_in,
                              void* d_out, int out_size, void* d_ws, size_t ws_size,
                              hipStream_t stream) {
  const float* x         = (const float*)d_in[0];
  const float* conv_w    = (const float*)d_in[1];
  const float* conv_b    = (const float*)d_in[2];
  const float* in_proj_w = (const float*)d_in[3];
  const float* conv1d_w  = (const float*)d_in[4];
  const float* conv1d_b  = (const float*)d_in[5];
  const float* dt_bias   = (const float*)d_in[6];
  const float* A_log     = (const float*)d_in[7];
  const float* D_skip    = (const float*)d_in[8];
  const float* norm_w    = (const float*)d_in[9];
  const float* out_proj_w= (const float*)d_in[10];
  const float* conv1_w   = (const float*)d_in[11];
  const float* conv1_b   = (const float*)d_in[12];
  const float* convT_w   = (const float*)d_in[13];
  const float* convT_b   = (const float*)d_in[14];
  float* out = (float*)d_out;
  float* ws  = (float*)d_ws;

  float* u    = ws + OFF_U;
  float* zx   = ws + OFF_ZX;
  float* dtb  = ws + OFF_DT;
  float* awb  = ws + OFF_AW;
  float* xc   = ws + OFF_XC;
  float* yb   = ws + OFF_Y;
  float* yc1a = ws + OFF_YC1A;
  float* yc1b = ws + OFF_YC1B;
  float* HS   = ws + OFF_HS;
  float* om   = u;            // u dead after in_proj GEMM
  float* Pbuf = yc1a;         // 2048 floats, yc1a dead until k_conv1

  // 1. front conv + relu -> u
  k_front<<<dim3(128, 8), 256, 0, stream>>>(x, conv_w, conv_b, u);
  // 2. in_proj GEMM
  gemm_nt<<<dim3(11, 128), 256, 0, stream>>>(u, in_proj_w, zx, M_TOK, D_IN_PROJ, 256);
  // 3. dt / a
  k_dt<<<dim3((M_TOK * NHEADS + 255) / 256), 256, 0, stream>>>(zx, dt_bias, A_log, dtb, awb);
  // 4. depthwise conv + silu -> xc
  k_dw<<<dim3((int)(((size_t)M_TOK * CONV_DIM + 255) / 256)), 256, 0, stream>>>(
      zx, conv1d_w, conv1d_b, xc);
  // 5. SSD scan (MFMA)
  k_ssd_state<<<dim3(NCH, 64), 256, 0, stream>>>(xc, dtb, awb, HS, Pbuf);
  k_ssd_comb<<<dim3(32, 64), 256, 0, stream>>>(HS, Pbuf);
  k_ssd_y<<<dim3(NCH, 64), 256, 0, stream>>>(xc, dtb, awb, D_skip, HS, yb);
  // 6. gate + RMSNorm
  k_norm<<<dim3(M_TOK), 512, 0, stream>>>(yb, zx, norm_w);
  // 7. out_proj GEMM
  gemm_nt<<<dim3(2, 128), 256, 0, stream>>>(yb, out_proj_w, om, M_TOK, 256, D_INNER);
  // 8. conv1 partials
  k_conv1<<<dim3(16, 8, 2), 256, 0, stream>>>(om, conv1_w, yc1a, yc1b);
  // 9. transposed conv -> out
  k_convT<<<dim3(64, 4, 8), 256, 0, stream>>>(yc1a, yc1b, conv1_b, convT_w, convT_b, out);
}

// Round 4
// 411.618 us; speedup vs baseline: 2.5555x; 1.4970x over previous
//
#include <hip/hip_runtime.h>
#include <cstddef>
#include <cstdint>

// ---------------- problem constants ----------------
constexpr int L_IN   = 16384;
constexpr int L_SEQ  = 2047;          // (16384-16)/8 + 1
constexpr int BATCH  = 8;
constexpr int M_TOK  = BATCH * L_SEQ; // 16376
constexpr int D_INNER = 512;
constexpr int NHEADS  = 8;
constexpr int HEADDIM = 64;
constexpr int D_STATE = 128;
constexpr int CONV_DIM = 768;
constexpr int D_IN_PROJ = 1288;

// SSD chunking
constexpr int QC  = 64;
constexpr int NCH = 32;

// ---------------- workspace layout (floats) ----------------
constexpr size_t OFF_U    = 0;                       // u bf16 (2.1M floats used of 4.19M)
constexpr size_t OFF_ZX   = OFF_U   + 4192256;
constexpr size_t OFF_DT   = OFF_ZX  + 21092288;
constexpr size_t OFF_AW   = OFF_DT  + 131008;
constexpr size_t OFF_XC   = OFF_AW  + 131008;
constexpr size_t OFF_Y    = OFF_XC  + 12576768;
constexpr size_t OFF_YC1A = OFF_Y   + 8384512;
constexpr size_t OFF_YC1B = OFF_YC1A + 131008;
constexpr size_t OFF_HS   = OFF_YC1B + 131008;       // 16,777,216
constexpr size_t OFF_WBIN = OFF_HS  + 16777216;      // 1288*256 bf16 = 164,864 floats
constexpr size_t OFF_WBOUT= OFF_WBIN + 164864;       // 256*512 bf16 = 65,536 floats
// total = 63,777,472 floats ~= 255.1 MB (254.2 passed last round)

using short8 = __attribute__((ext_vector_type(8))) short;  // 8 bf16
using f32x4  = __attribute__((ext_vector_type(4))) float;
typedef unsigned short ushort_t;

__device__ __forceinline__ ushort_t f2bf(float f) {        // RNE f32->bf16
  uint32_t u = __float_as_uint(f);
  u += 0x7fffu + ((u >> 16) & 1u);
  return (ushort_t)(u >> 16);
}
__device__ __forceinline__ float bf2f(ushort_t h) {
  return __uint_as_float(((uint32_t)h) << 16);
}
#define MFMA16(a, b, c) __builtin_amdgcn_mfma_f32_16x16x32_bf16(a, b, c, 0, 0, 0)

// ============================================================
// K0: cast projection weights to bf16 (once per launch, ~0.5MB)
// ============================================================
__global__ void k_cast(const float* __restrict__ w1, const float* __restrict__ w2,
                       ushort_t* __restrict__ o1, ushort_t* __restrict__ o2) {
  int i = blockIdx.x * 256 + threadIdx.x;
  if (i < D_IN_PROJ * 256) o1[i] = f2bf(w1[i]);
  if (i < 256 * D_INNER)   o2[i] = f2bf(w2[i]);
}

// ============================================================
// K1: front conv (4->256, K=16, stride 8, VALID) + ReLU -> u (bf16)
// ============================================================
__global__ __launch_bounds__(256) void k_front(const float* __restrict__ x,
    const float* __restrict__ w, const float* __restrict__ cb,
    ushort_t* __restrict__ u) {
  const int tb = blockIdx.x;
  const int b  = blockIdx.y;
  const int t0 = tb * 16;
  __shared__ float xs[4][136];
  for (int i = threadIdx.x; i < 4 * 136; i += 256) {
    int ic = i / 136, off = i % 136;
    int gi = t0 * 8 + off;
    xs[ic][off] = (gi < L_IN) ? x[((size_t)b * 4 + ic) * L_IN + gi] : 0.f;
  }
  __syncthreads();
  const int c = threadIdx.x;
  float wreg[64];
#pragma unroll
  for (int q = 0; q < 16; q++)
    *(float4*)&wreg[q * 4] = *(const float4*)(w + (size_t)c * 64 + q * 4);
  const float base = cb[c];
  float acc[16];
#pragma unroll
  for (int ts = 0; ts < 16; ts++) acc[ts] = base;
#pragma unroll
  for (int ic = 0; ic < 4; ic++) {
#pragma unroll
    for (int ts = 0; ts < 16; ts++) {
#pragma unroll
      for (int k = 0; k < 16; k++)
        acc[ts] = fmaf(xs[ic][ts * 8 + k], wreg[ic * 16 + k], acc[ts]);
    }
  }
#pragma unroll
  for (int ts = 0; ts < 16; ts++) {
    int t = t0 + ts;
    if (t < L_SEQ)
      u[((size_t)b * L_SEQ + t) * 256 + c] = f2bf(fmaxf(acc[ts], 0.f));
  }
}

// ============================================================
// K2/K7: bf16 MFMA GEMM NT.  C[m][n] = sum_k A[m][k]*B[n][k], fp32 out.
// 128x128 tile, BK=64, 4 waves (2x2), 4x4 16x16 frags/wave.
// LDS 16B-slot XOR swizzle (slot ^= row&7): ds_read_b128 at 8-clk min.
// ============================================================
__global__ __launch_bounds__(256) void gemm_bf16(const ushort_t* __restrict__ A, int lda,
    const ushort_t* __restrict__ B, int ldb, float* __restrict__ C,
    int M, int N, int K) {
  __shared__ __attribute__((aligned(16))) ushort_t sA[128 * 64];
  __shared__ __attribute__((aligned(16))) ushort_t sB[128 * 64];
  const int tid = threadIdx.x;
  const int m0 = blockIdx.y * 128, n0 = blockIdx.x * 128;
  const int w = tid >> 6, lane = tid & 63;
  const int l15 = lane & 15, lK = lane >> 4;
  const int wr = w >> 1, wc = w & 1;
  f32x4 acc[4][4] = {};
  for (int k0 = 0; k0 < K; k0 += 64) {
    __syncthreads();
#pragma unroll
    for (int j = 0; j < 4; j++) {
      int idx = j * 256 + tid;          // 0..1023: row = idx>>3, slot = idx&7
      int r = idx >> 3, s = idx & 7;
      short8 va = {0, 0, 0, 0, 0, 0, 0, 0};
      int gm = m0 + r;
      if (gm < M) va = *(const short8*)(A + (size_t)gm * lda + k0 + s * 8);
      *(short8*)&sA[r * 64 + ((s ^ (r & 7)) * 8)] = va;
      short8 vb = {0, 0, 0, 0, 0, 0, 0, 0};
      int gn = n0 + r;
      if (gn < N) vb = *(const short8*)(B + (size_t)gn * ldb + k0 + s * 8);
      *(short8*)&sB[r * 64 + ((s ^ (r & 7)) * 8)] = vb;
    }
    __syncthreads();
#pragma unroll
    for (int kk = 0; kk < 2; kk++) {
      short8 af[4], bf[4];
#pragma unroll
      for (int mt = 0; mt < 4; mt++) {
        int r = wr * 64 + mt * 16 + l15;
        af[mt] = *(const short8*)&sA[r * 64 + (((kk * 4 + lK) ^ (r & 7)) * 8)];
      }
#pragma unroll
      for (int nt = 0; nt < 4; nt++) {
        int r = wc * 64 + nt * 16 + l15;
        bf[nt] = *(const short8*)&sB[r * 64 + (((kk * 4 + lK) ^ (r & 7)) * 8)];
      }
#pragma unroll
      for (int mt = 0; mt < 4; mt++)
#pragma unroll
        for (int nt = 0; nt < 4; nt++)
          acc[mt][nt] = MFMA16(af[mt], bf[nt], acc[mt][nt]);
    }
  }
#pragma unroll
  for (int mt = 0; mt < 4; mt++)
#pragma unroll
    for (int i = 0; i < 4; i++) {
      int gm = m0 + wr * 64 + mt * 16 + lK * 4 + i;
      if (gm < M) {
        float* crow = C + (size_t)gm * N;
#pragma unroll
        for (int nt = 0; nt < 4; nt++) {
          int gn = n0 + wc * 64 + nt * 16 + l15;
          if (gn < N) crow[gn] = acc[mt][nt][i];
        }
      }
    }
}

// ============================================================
// K3: dt = softplus(...); a = log dA = -exp(A_log)*dt
// ============================================================
__global__ void k_dt(const float* __restrict__ zx, const float* __restrict__ dt_bias,
                     const float* __restrict__ A_log, float* __restrict__ dt,
                     float* __restrict__ aw) {
  int i = blockIdx.x * 256 + threadIdx.x;
  if (i >= M_TOK * NHEADS) return;
  int hd = i & 7;
  int row = i >> 3;
  float v = zx[(size_t)row * D_IN_PROJ + (D_INNER + CONV_DIM) + hd] + dt_bias[hd];
  float sp = (v > 20.f) ? v : log1pf(expf(v));
  dt[i] = sp;
  aw[i] = -expf(A_log[hd]) * sp;
}

// ============================================================
// K4: depthwise causal conv + bias + silu
// ============================================================
__global__ void k_dw(const float* __restrict__ zx, const float* __restrict__ w,
                     const float* __restrict__ bias, float* __restrict__ xc) {
  size_t idx = (size_t)blockIdx.x * 256 + threadIdx.x;
  if (idx >= (size_t)M_TOK * CONV_DIM) return;
  int c = (int)(idx % CONV_DIM);
  int row = (int)(idx / CONV_DIM);
  int t = row % L_SEQ, b = row / L_SEQ;
  float acc = bias[c];
#pragma unroll
  for (int k = 0; k < 4; k++) {
    int tt = t - 3 + k;
    if (tt >= 0)
      acc = fmaf(zx[((size_t)b * L_SEQ + tt) * D_IN_PROJ + D_INNER + c], w[c * 4 + k], acc);
  }
  xc[(size_t)row * CONV_DIM + c] = acc / (1.f + expf(-acc));
}

// ============================================================
// K5a: SSD chunk state summaries
// ============================================================
__global__ __launch_bounds__(256) void k_ssd_state(const float* __restrict__ xc,
    const float* __restrict__ dtb, const float* __restrict__ aw,
    float* __restrict__ HS, float* __restrict__ Pbuf) {
  const int ch = blockIdx.x, bh = blockIdx.y;
  const int b = bh >> 3, h = bh & 7;
  const int t0 = ch * QC;
  const int valid = (L_SEQ - t0 < QC) ? (L_SEQ - t0) : QC;
  const size_t rowbase = (size_t)b * L_SEQ;
  __shared__ __attribute__((aligned(16))) short sBT[128][72];
  __shared__ __attribute__((aligned(16))) short sXw[64][72];
  __shared__ float sW[64];
  __shared__ float sLtot;
  const int tid = threadIdx.x;
  if (tid < 64) {
    float aa = 0.f, dd = 0.f;
    if (tid < valid) { size_t r8 = (rowbase + t0 + tid) * 8 + h; aa = aw[r8]; dd = dtb[r8]; }
    float s = aa;
#pragma unroll
    for (int d = 1; d < 64; d <<= 1) { float o = __shfl_up(s, d, 64); if (tid >= d) s += o; }
    float Lt = __shfl(s, 63, 64);
    sW[tid] = expf(Lt - s) * dd;
    if (tid == 63) sLtot = s;
  }
  __syncthreads();
  for (int i = tid; i < 64 * 32; i += 256) {
    int r = i >> 5, q = (i & 31) * 4;
    float4 v = {0, 0, 0, 0};
    if (r < valid) v = *(const float4*)(xc + (rowbase + t0 + r) * CONV_DIM + 512 + q);
    sBT[q + 0][r] = (short)f2bf(v.x); sBT[q + 1][r] = (short)f2bf(v.y);
    sBT[q + 2][r] = (short)f2bf(v.z); sBT[q + 3][r] = (short)f2bf(v.w);
  }
  for (int i = tid; i < 64 * 16; i += 256) {
    int r = i >> 4, q = (i & 15) * 4;
    float4 v = {0, 0, 0, 0};
    if (r < valid) v = *(const float4*)(xc + (rowbase + t0 + r) * CONV_DIM + h * 64 + q);
    float wv = sW[r];
    sXw[q + 0][r] = (short)f2bf(v.x * wv); sXw[q + 1][r] = (short)f2bf(v.y * wv);
    sXw[q + 2][r] = (short)f2bf(v.z * wv); sXw[q + 3][r] = (short)f2bf(v.w * wv);
  }
  __syncthreads();
  const int w = tid >> 6, l15 = tid & 15, lK = (tid & 63) >> 4;
  f32x4 acc[2][4] = {};
  short8 afr[2][2];
#pragma unroll
  for (int j = 0; j < 2; j++)
#pragma unroll
    for (int kt = 0; kt < 2; kt++)
      afr[j][kt] = *(const short8*)&sBT[(w * 2 + j) * 16 + l15][kt * 32 + lK * 8];
#pragma unroll
  for (int pt = 0; pt < 4; pt++) {
#pragma unroll
    for (int kt = 0; kt < 2; kt++) {
      short8 bfr = *(const short8*)&sXw[pt * 16 + l15][kt * 32 + lK * 8];
      acc[0][pt] = MFMA16(afr[0][kt], bfr, acc[0][pt]);
      acc[1][pt] = MFMA16(afr[1][kt], bfr, acc[1][pt]);
    }
  }
  float* dst = HS + ((size_t)bh * NCH + ch) * 8192;
#pragma unroll
  for (int j = 0; j < 2; j++)
#pragma unroll
    for (int pt = 0; pt < 4; pt++)
#pragma unroll
      for (int i = 0; i < 4; i++) {
        int n = (w * 2 + j) * 16 + lK * 4 + i, p = pt * 16 + l15;
        dst[n * 64 + p] = acc[j][pt][i];
      }
  if (tid == 0) Pbuf[bh * NCH + ch] = expf(sLtot);
}

// ============================================================
// K5b: sequential inter-chunk combine (in place)
// ============================================================
__global__ __launch_bounds__(256) void k_ssd_comb(float* __restrict__ HS,
                                                  const float* __restrict__ Pbuf) {
  const int bh = blockIdx.y;
  const int e  = blockIdx.x * 256 + threadIdx.x;
  float run = 0.f;
  for (int c = 0; c < NCH; c++) {
    size_t idx = ((size_t)bh * NCH + c) * 8192 + e;
    float s = HS[idx];
    run = fmaf(Pbuf[bh * NCH + c], run, s);
    HS[idx] = run;
  }
}

// ============================================================
// K5c: SSD output
// ============================================================
__global__ __launch_bounds__(256) void k_ssd_y(const float* __restrict__ xc,
    const float* __restrict__ dtb, const float* __restrict__ aw,
    const float* __restrict__ Dskip, const float* __restrict__ HS,
    float* __restrict__ y) {
  const int ch = blockIdx.x, bh = blockIdx.y;
  const int b = bh >> 3, h = bh & 7;
  const int t0 = ch * QC;
  const int valid = (L_SEQ - t0 < QC) ? (L_SEQ - t0) : QC;
  const size_t rowbase = (size_t)b * L_SEQ;
  __shared__ __attribute__((aligned(16))) short sB[64][136];
  __shared__ __attribute__((aligned(16))) short sC[64][136];
  __shared__ __attribute__((aligned(16))) short sH[64][136];
  __shared__ __attribute__((aligned(16))) short sX[64][72];
  __shared__ float sLrel[64], sdt[64], sEL[64];
  short (*sM)[72] = (short(*)[72])&sB[0][0];
  const int tid = threadIdx.x;
  if (tid < 64) {
    float aa = 0.f, dd = 0.f;
    if (tid < valid) { size_t r8 = (rowbase + t0 + tid) * 8 + h; aa = aw[r8]; dd = dtb[r8]; }
    float s = aa;
#pragma unroll
    for (int d = 1; d < 64; d <<= 1) { float o = __shfl_up(s, d, 64); if (tid >= d) s += o; }
    sLrel[tid] = s; sdt[tid] = dd; sEL[tid] = expf(s);
  }
  for (int i = tid; i < 64 * 32; i += 256) {
    int r = i >> 5, q = (i & 31) * 4;
    float4 vb = {0, 0, 0, 0}, vc = {0, 0, 0, 0};
    if (r < valid) {
      const float* rp = xc + (rowbase + t0 + r) * CONV_DIM;
      vb = *(const float4*)(rp + 512 + q);
      vc = *(const float4*)(rp + 640 + q);
    }
    short* pb = &sB[r][q];
    pb[0] = (short)f2bf(vb.x); pb[1] = (short)f2bf(vb.y);
    pb[2] = (short)f2bf(vb.z); pb[3] = (short)f2bf(vb.w);
    short* pc = &sC[r][q];
    pc[0] = (short)f2bf(vc.x); pc[1] = (short)f2bf(vc.y);
    pc[2] = (short)f2bf(vc.z); pc[3] = (short)f2bf(vc.w);
  }
  for (int i = tid; i < 64 * 16; i += 256) {
    int r = i >> 4, q = (i & 15) * 4;
    float4 v = {0, 0, 0, 0};
    if (r < valid) v = *(const float4*)(xc + (rowbase + t0 + r) * CONV_DIM + h * 64 + q);
    sX[q + 0][r] = (short)f2bf(v.x); sX[q + 1][r] = (short)f2bf(v.y);
    sX[q + 2][r] = (short)f2bf(v.z); sX[q + 3][r] = (short)f2bf(v.w);
  }
  for (int i = tid; i < 128 * 16; i += 256) {
    int n = i >> 4, q = (i & 15) * 4;
    float4 v = {0, 0, 0, 0};
    if (ch > 0) v = *(const float4*)(HS + ((size_t)bh * NCH + (ch - 1)) * 8192 + n * 64 + q);
    sH[q + 0][n] = (short)f2bf(v.x); sH[q + 1][n] = (short)f2bf(v.y);
    sH[q + 2][n] = (short)f2bf(v.z); sH[q + 3][n] = (short)f2bf(v.w);
  }
  __syncthreads();
  const int w = tid >> 6, l15 = tid & 15, lK = (tid & 63) >> 4;
  short8 aC[4];
#pragma unroll
  for (int kt = 0; kt < 4; kt++)
    aC[kt] = *(const short8*)&sC[w * 16 + l15][kt * 32 + lK * 8];
  f32x4 g[4] = {};
#pragma unroll
  for (int st = 0; st < 4; st++)
#pragma unroll
    for (int kt = 0; kt < 4; kt++)
      g[st] = MFMA16(aC[kt], *(const short8*)&sB[st * 16 + l15][kt * 32 + lK * 8], g[st]);
  __syncthreads();
#pragma unroll
  for (int st = 0; st < 4; st++)
#pragma unroll
    for (int i = 0; i < 4; i++) {
      int tt = w * 16 + lK * 4 + i, ss = st * 16 + l15;
      float f = (ss <= tt) ? expf(sLrel[tt] - sLrel[ss]) * sdt[ss] : 0.f;
      sM[tt][ss] = (short)f2bf(g[st][i] * f);
    }
  __syncthreads();
  f32x4 acc[4] = {};
#pragma unroll
  for (int pt = 0; pt < 4; pt++)
#pragma unroll
    for (int kt = 0; kt < 4; kt++)
      acc[pt] = MFMA16(aC[kt], *(const short8*)&sH[pt * 16 + l15][kt * 32 + lK * 8], acc[pt]);
#pragma unroll
  for (int pt = 0; pt < 4; pt++)
#pragma unroll
    for (int i = 0; i < 4; i++)
      acc[pt][i] *= sEL[w * 16 + lK * 4 + i];
  short8 aM[2];
#pragma unroll
  for (int kt = 0; kt < 2; kt++)
    aM[kt] = *(const short8*)&sM[w * 16 + l15][kt * 32 + lK * 8];
#pragma unroll
  for (int pt = 0; pt < 4; pt++)
#pragma unroll
    for (int kt = 0; kt < 2; kt++)
      acc[pt] = MFMA16(aM[kt], *(const short8*)&sX[pt * 16 + l15][kt * 32 + lK * 8], acc[pt]);
  const float Dsk = Dskip[h];
#pragma unroll
  for (int pt = 0; pt < 4; pt++)
#pragma unroll
    for (int i = 0; i < 4; i++) {
      int tt = w * 16 + lK * 4 + i;
      if (tt < valid) {
        int pp = pt * 16 + l15;
        y[(rowbase + t0 + tt) * D_INNER + h * 64 + pp] =
            acc[pt][i] + Dsk * bf2f((ushort_t)sX[pp][tt]);
      }
    }
}

// ============================================================
// K6: gate + RMSNorm; writes bf16 IN-PLACE into y (reads precede sync)
// ============================================================
__global__ __launch_bounds__(512) void k_norm(float* __restrict__ y,
    const float* __restrict__ zx, const float* __restrict__ norm_w) {
  const int row = blockIdx.x;
  const int c = threadIdx.x;
  float z = zx[(size_t)row * D_IN_PROJ + c];
  float g = z / (1.f + expf(-z));
  float v = y[(size_t)row * D_INNER + c] * g;
  float ss = v * v;
#pragma unroll
  for (int m = 32; m >= 1; m >>= 1) ss += __shfl_xor(ss, m, 64);
  __shared__ float red[8];
  if ((threadIdx.x & 63) == 0) red[threadIdx.x >> 6] = ss;
  __syncthreads();
  float tot = 0.f;
#pragma unroll
  for (int i = 0; i < 8; i++) tot += red[i];
  float scale = rsqrtf(tot * (1.f / 512.f) + 1e-5f);
  ((ushort_t*)(y + (size_t)row * D_INNER))[c] = f2bf(v * scale * norm_w[c]);
}

// ============================================================
// K8: conv1 (256->8ch, K=16, pad(7,8)) partials
// ============================================================
__global__ __launch_bounds__(256) void k_conv1(const float* __restrict__ om,
    const float* __restrict__ w, float* __restrict__ yc1a, float* __restrict__ yc1b) {
  const int tt = blockIdx.x, b = blockIdx.y, zc = blockIdx.z;
  const int t0 = tt * 128;
  const int tsub = threadIdx.x >> 1;
  const int ochalf = threadIdx.x & 1;
  __shared__ float inl[143][65];
  __shared__ float wl[64][16][8];
  float acc[4] = {0, 0, 0, 0};
  for (int cc2 = 0; cc2 < 2; cc2++) {
    const int icc = zc * 2 + cc2;
    __syncthreads();
    for (int i = threadIdx.x; i < 143 * 64; i += 256) {
      int r = i >> 6, cc = i & 63;
      int tin = t0 - 7 + r;
      float v = 0.f;
      if (tin >= 0 && tin < L_SEQ)
        v = om[((size_t)b * L_SEQ + tin) * 256 + icc * 64 + cc];
      inl[r][cc] = v;
    }
    for (int i = threadIdx.x; i < 64 * 16 * 8; i += 256) {
      int oc = i & 7, k = (i >> 3) & 15, ic = i >> 7;
      wl[ic][k][oc] = w[((size_t)oc * 256 + icc * 64 + ic) * 16 + k];
    }
    __syncthreads();
    for (int ic = 0; ic < 64; ic++) {
#pragma unroll
      for (int k = 0; k < 16; k++) {
        float iv = inl[tsub + k][ic];
        float4 wv = *(const float4*)&wl[ic][k][ochalf * 4];
        acc[0] = fmaf(iv, wv.x, acc[0]);
        acc[1] = fmaf(iv, wv.y, acc[1]);
        acc[2] = fmaf(iv, wv.z, acc[2]);
        acc[3] = fmaf(iv, wv.w, acc[3]);
      }
    }
  }
  int t = t0 + tsub;
  if (t < L_SEQ) {
    float* dst = (zc == 0) ? yc1a : yc1b;
#pragma unroll
    for (int j = 0; j < 4; j++)
      dst[((size_t)b * 8 + ochalf * 4 + j) * L_SEQ + t] = acc[j];
  }
}

// ============================================================
// K9: transposed conv (8->4ch, K=16, lhs_dilation=8, pad 15/15)
// ============================================================
__global__ void k_convT(const float* __restrict__ yc1a, const float* __restrict__ yc1b,
                        const float* __restrict__ b1, const float* __restrict__ wT,
                        const float* __restrict__ bT, float* __restrict__ out) {
  const int s = blockIdx.x * 256 + threadIdx.x;
  const int c = blockIdx.y, b = blockIdx.z;
  float acc = bT[c];
  const int k0 = (15 - (s & 7)) & 7;
#pragma unroll
  for (int dk = 0; dk < 2; dk++) {
    int k = k0 + 8 * dk;
    int num = s - 15 + k;
    int m = num >> 3;
    if (num >= 0 && m < L_SEQ) {
#pragma unroll
      for (int j = 0; j < 8; j++) {
        float v = yc1a[((size_t)b * 8 + j) * L_SEQ + m]
                + yc1b[((size_t)b * 8 + j) * L_SEQ + m] + b1[j];
        acc = fmaf(v, wT[((size_t)j * 4 + c) * 16 + (15 - k)], acc);
      }
    }
  }
  out[((size_t)b * 4 + c) * L_IN + s] = acc;
}

// ============================================================
extern "C" void kernel_launch(void* const* d_in, const int* in_sizes, int n_in,
                              void* d_out, int out_size, void* d_ws, size_t ws_size,
                              hipStream_t stream) {
  const float* x         = (const float*)d_in[0];
  const float* conv_w    = (const float*)d_in[1];
  const float* conv_b    = (const float*)d_in[2];
  const float* in_proj_w = (const float*)d_in[3];
  const float* conv1d_w  = (const float*)d_in[4];
  const float* conv1d_b  = (const float*)d_in[5];
  const float* dt_bias   = (const float*)d_in[6];
  const float* A_log     = (const float*)d_in[7];
  const float* D_skip    = (const float*)d_in[8];
  const float* norm_w    = (const float*)d_in[9];
  const float* out_proj_w= (const float*)d_in[10];
  const float* conv1_w   = (const float*)d_in[11];
  const float* conv1_b   = (const float*)d_in[12];
  const float* convT_w   = (const float*)d_in[13];
  const float* convT_b   = (const float*)d_in[14];
  float* out = (float*)d_out;
  float* ws  = (float*)d_ws;

  ushort_t* ub  = (ushort_t*)(ws + OFF_U);
  float* zx   = ws + OFF_ZX;
  float* dtb  = ws + OFF_DT;
  float* awb  = ws + OFF_AW;
  float* xc   = ws + OFF_XC;
  float* yb   = ws + OFF_Y;
  float* yc1a = ws + OFF_YC1A;
  float* yc1b = ws + OFF_YC1B;
  float* HS   = ws + OFF_HS;
  ushort_t* wbin  = (ushort_t*)(ws + OFF_WBIN);
  ushort_t* wbout = (ushort_t*)(ws + OFF_WBOUT);
  float* om   = ws + OFF_U;   // u region dead after in_proj GEMM
  float* Pbuf = yc1a;         // 2048 floats, yc1a dead until k_conv1

  // 0. weight casts
  k_cast<<<dim3((D_IN_PROJ * 256 + 255) / 256), 256, 0, stream>>>(
      in_proj_w, out_proj_w, wbin, wbout);
  // 1. front conv + relu -> u (bf16)
  k_front<<<dim3(128, 8), 256, 0, stream>>>(x, conv_w, conv_b, ub);
  // 2. in_proj: zx = u @ W^T (bf16 MFMA)
  gemm_bf16<<<dim3(11, 128), 256, 0, stream>>>(ub, 256, wbin, 256, zx,
                                               M_TOK, D_IN_PROJ, 256);
  // 3. dt / a
  k_dt<<<dim3((M_TOK * NHEADS + 255) / 256), 256, 0, stream>>>(zx, dt_bias, A_log, dtb, awb);
  // 4. depthwise conv + silu -> xc
  k_dw<<<dim3((int)(((size_t)M_TOK * CONV_DIM + 255) / 256)), 256, 0, stream>>>(
      zx, conv1d_w, conv1d_b, xc);
  // 5. SSD scan (MFMA)
  k_ssd_state<<<dim3(NCH, 64), 256, 0, stream>>>(xc, dtb, awb, HS, Pbuf);
  k_ssd_comb<<<dim3(32, 64), 256, 0, stream>>>(HS, Pbuf);
  k_ssd_y<<<dim3(NCH, 64), 256, 0, stream>>>(xc, dtb, awb, D_skip, HS, yb);
  // 6. gate + RMSNorm -> bf16 in place
  k_norm<<<dim3(M_TOK), 512, 0, stream>>>(yb, zx, norm_w);
  // 7. out_proj: om = y @ Wout^T (bf16 MFMA; y rows are 1024-ushort strided)
  gemm_bf16<<<dim3(2, 128), 256, 0, stream>>>((ushort_t*)yb, 1024, wbout, 512, om,
                                              M_TOK, 256, D_INNER);
  // 8. conv1 partials
  k_conv1<<<dim3(16, 8, 2), 256, 0, stream>>>(om, conv1_w, yc1a, yc1b);
  // 9. transposed conv -> out
  k_convT<<<dim3(64, 4, 8), 256, 0, stream>>>(yc1a, yc1b, conv1_b, convT_w, convT_b, out);
}

// Round 5
// 308.278 us; speedup vs baseline: 3.4121x; 1.3352x over previous
//
#include <hip/hip_runtime.h>
#include <cstddef>
#include <cstdint>

// ---------------- problem constants ----------------
constexpr int L_IN   = 16384;
constexpr int L_SEQ  = 2047;          // (16384-16)/8 + 1
constexpr int BATCH  = 8;
constexpr int M_TOK  = BATCH * L_SEQ; // 16376
constexpr int D_INNER = 512;
constexpr int NHEADS  = 8;
constexpr int HEADDIM = 64;
constexpr int D_STATE = 128;
constexpr int CONV_DIM = 768;
constexpr int D_IN_PROJ = 1288;

// SSD chunking
constexpr int QC  = 64;
constexpr int NCH = 32;

// ---------------- workspace layout (floats) ----------------
constexpr size_t OFF_U    = 0;                       // ub bf16 = 2,096,128 floats
constexpr size_t OFF_PB   = OFF_U   + 2096128;       // im2col patches bf16 = 524,032 floats
constexpr size_t OFF_ZX   = OFF_U   + 4192256;       // (om fp32 reuses full U region later)
constexpr size_t OFF_DT   = OFF_ZX  + 21092288;
constexpr size_t OFF_AW   = OFF_DT  + 131008;
constexpr size_t OFF_XC   = OFF_AW  + 131008;        // xc bf16 (6.3M of 12.6M floats used)
constexpr size_t OFF_Y    = OFF_XC  + 12576768;
constexpr size_t OFF_YC1A = OFF_Y   + 8384512;
constexpr size_t OFF_YC1B = OFF_YC1A + 131008;
constexpr size_t OFF_HS   = OFF_YC1B + 131008;       // 16,777,216
constexpr size_t OFF_WBIN = OFF_HS  + 16777216;      // 1288*256 bf16
constexpr size_t OFF_WBOUT= OFF_WBIN + 164864;       // 256*512 bf16
constexpr size_t OFF_WBF  = OFF_WBOUT + 65536;       // 256*64 bf16 = 8192 floats
// total = 63,785,664 floats ~= 255.1 MB (255.1 passed last round)

using short8 = __attribute__((ext_vector_type(8))) short;  // 8 bf16
using f32x4  = __attribute__((ext_vector_type(4))) float;
typedef unsigned short ushort_t;

__device__ __forceinline__ ushort_t f2bf(float f) {        // RNE f32->bf16
  uint32_t u = __float_as_uint(f);
  u += 0x7fffu + ((u >> 16) & 1u);
  return (ushort_t)(u >> 16);
}
__device__ __forceinline__ float bf2f(ushort_t h) {
  return __uint_as_float(((uint32_t)h) << 16);
}
#define MFMA16(a, b, c) __builtin_amdgcn_mfma_f32_16x16x32_bf16(a, b, c, 0, 0, 0)

// ============================================================
// K0: cast weights to bf16 (in_proj, out_proj, front conv)
// ============================================================
__global__ void k_cast(const float* __restrict__ w1, const float* __restrict__ w2,
                       const float* __restrict__ w3,
                       ushort_t* __restrict__ o1, ushort_t* __restrict__ o2,
                       ushort_t* __restrict__ o3) {
  int i = blockIdx.x * 256 + threadIdx.x;
  if (i < D_IN_PROJ * 256) o1[i] = f2bf(w1[i]);
  if (i < 256 * D_INNER)   o2[i] = f2bf(w2[i]);
  if (i < 256 * 64)        o3[i] = f2bf(w3[i]);
}

// ============================================================
// K1a: im2col for front conv.  PB[row][ic*16+k] = x[b][ic][t*8+k] (bf16)
//      row = b*L_SEQ+t.  t*8+k <= 16383 always: no boundary handling.
// ============================================================
__global__ __launch_bounds__(256) void k_im2col(const float* __restrict__ x,
                                                ushort_t* __restrict__ PB) {
  int idx = blockIdx.x * 256 + threadIdx.x;     // row*8 + oct
  if (idx >= M_TOK * 8) return;
  int oct = idx & 7, row = idx >> 3;
  int t = row % L_SEQ, b = row / L_SEQ;
  int ic = oct >> 1, k0 = (oct & 1) * 8;
  const float* src = x + ((size_t)b * 4 + ic) * L_IN + t * 8 + k0;
  float4 a0 = *(const float4*)src;
  float4 a1 = *(const float4*)(src + 4);
  short8 o;
  o[0] = (short)f2bf(a0.x); o[1] = (short)f2bf(a0.y);
  o[2] = (short)f2bf(a0.z); o[3] = (short)f2bf(a0.w);
  o[4] = (short)f2bf(a1.x); o[5] = (short)f2bf(a1.y);
  o[6] = (short)f2bf(a1.z); o[7] = (short)f2bf(a1.w);
  *(short8*)(PB + (size_t)row * 64 + oct * 8) = o;
}

// ============================================================
// K2: bf16 MFMA GEMM NT.  C[m][n] = sum_k A[m][k]*B[n][k].
// 128x128 tile, BK=64, 4 waves, LDS XOR swizzle.
// EPI=0: fp32 store.  EPI=1: +bias, relu, bf16 packed-pair store.
// ============================================================
template<int EPI>
__global__ __launch_bounds__(256) void gemm_bf16(const ushort_t* __restrict__ A, int lda,
    const ushort_t* __restrict__ B, int ldb, float* __restrict__ C,
    const float* __restrict__ bias, int M, int N, int K) {
  __shared__ __attribute__((aligned(16))) ushort_t sA[128 * 64];
  __shared__ __attribute__((aligned(16))) ushort_t sB[128 * 64];
  const int tid = threadIdx.x;
  const int m0 = blockIdx.y * 128, n0 = blockIdx.x * 128;
  const int w = tid >> 6, lane = tid & 63;
  const int l15 = lane & 15, lK = lane >> 4;
  const int wr = w >> 1, wc = w & 1;
  f32x4 acc[4][4] = {};
  for (int k0 = 0; k0 < K; k0 += 64) {
    __syncthreads();
#pragma unroll
    for (int j = 0; j < 4; j++) {
      int idx = j * 256 + tid;
      int r = idx >> 3, s = idx & 7;
      short8 va = {0, 0, 0, 0, 0, 0, 0, 0};
      int gm = m0 + r;
      if (gm < M) va = *(const short8*)(A + (size_t)gm * lda + k0 + s * 8);
      *(short8*)&sA[r * 64 + ((s ^ (r & 7)) * 8)] = va;
      short8 vb = {0, 0, 0, 0, 0, 0, 0, 0};
      int gn = n0 + r;
      if (gn < N) vb = *(const short8*)(B + (size_t)gn * ldb + k0 + s * 8);
      *(short8*)&sB[r * 64 + ((s ^ (r & 7)) * 8)] = vb;
    }
    __syncthreads();
#pragma unroll
    for (int kk = 0; kk < 2; kk++) {
      short8 af[4], bf[4];
#pragma unroll
      for (int mt = 0; mt < 4; mt++) {
        int r = wr * 64 + mt * 16 + l15;
        af[mt] = *(const short8*)&sA[r * 64 + (((kk * 4 + lK) ^ (r & 7)) * 8)];
      }
#pragma unroll
      for (int nt = 0; nt < 4; nt++) {
        int r = wc * 64 + nt * 16 + l15;
        bf[nt] = *(const short8*)&sB[r * 64 + (((kk * 4 + lK) ^ (r & 7)) * 8)];
      }
#pragma unroll
      for (int mt = 0; mt < 4; mt++)
#pragma unroll
        for (int nt = 0; nt < 4; nt++)
          acc[mt][nt] = MFMA16(af[mt], bf[nt], acc[mt][nt]);
    }
  }
  if constexpr (EPI == 0) {
#pragma unroll
    for (int mt = 0; mt < 4; mt++)
#pragma unroll
      for (int i = 0; i < 4; i++) {
        int gm = m0 + wr * 64 + mt * 16 + lK * 4 + i;
        if (gm < M) {
          float* crow = C + (size_t)gm * N;
#pragma unroll
          for (int nt = 0; nt < 4; nt++) {
            int gn = n0 + wc * 64 + nt * 16 + l15;
            if (gn < N) crow[gn] = acc[mt][nt][i];
          }
        }
      }
  } else {
    // bias + relu + bf16; pack lane pairs (l15 even/odd) into one 4B store
    ushort_t* Cb = (ushort_t*)C;
#pragma unroll
    for (int mt = 0; mt < 4; mt++)
#pragma unroll
      for (int i = 0; i < 4; i++) {
        int gm = m0 + wr * 64 + mt * 16 + lK * 4 + i;
#pragma unroll
        for (int nt = 0; nt < 4; nt++) {
          int gn = n0 + wc * 64 + nt * 16 + l15;
          float v = fmaxf(acc[mt][nt][i] + bias[gn], 0.f);
          uint32_t mine = f2bf(v);
          uint32_t other = (uint32_t)__shfl_xor((int)mine, 1, 64);
          if (((lane & 1) == 0) && gm < M)
            *(uint32_t*)(Cb + (size_t)gm * N + gn) = mine | (other << 16);
        }
      }
  }
}

// ============================================================
// K3: dt = softplus(...); a = log dA = -exp(A_log)*dt
// ============================================================
__global__ void k_dt(const float* __restrict__ zx, const float* __restrict__ dt_bias,
                     const float* __restrict__ A_log, float* __restrict__ dt,
                     float* __restrict__ aw) {
  int i = blockIdx.x * 256 + threadIdx.x;
  if (i >= M_TOK * NHEADS) return;
  int hd = i & 7;
  int row = i >> 3;
  float v = zx[(size_t)row * D_IN_PROJ + (D_INNER + CONV_DIM) + hd] + dt_bias[hd];
  float sp = (v > 20.f) ? v : log1pf(expf(v));
  dt[i] = sp;
  aw[i] = -expf(A_log[hd]) * sp;
}

// ============================================================
// K4: depthwise causal conv + bias + silu -> xc (bf16, packed 4B stores)
//     2 channels per thread
// ============================================================
__global__ void k_dw(const float* __restrict__ zx, const float* __restrict__ w,
                     const float* __restrict__ bias, ushort_t* __restrict__ xcb) {
  size_t idx = (size_t)blockIdx.x * 256 + threadIdx.x;
  if (idx >= (size_t)M_TOK * 384) return;
  int cp = (int)(idx % 384);
  int c = cp * 2;
  int row = (int)(idx / 384);
  int t = row % L_SEQ, b = row / L_SEQ;
  float acc0 = bias[c], acc1 = bias[c + 1];
  float w0[4], w1[4];
#pragma unroll
  for (int k = 0; k < 4; k++) { w0[k] = w[c * 4 + k]; w1[k] = w[(c + 1) * 4 + k]; }
#pragma unroll
  for (int k = 0; k < 4; k++) {
    int tt = t - 3 + k;
    if (tt >= 0) {
      const float* p = zx + ((size_t)b * L_SEQ + tt) * D_IN_PROJ + D_INNER + c;
      float2 v = *(const float2*)p;
      acc0 = fmaf(v.x, w0[k], acc0);
      acc1 = fmaf(v.y, w1[k], acc1);
    }
  }
  float s0 = acc0 / (1.f + expf(-acc0));
  float s1 = acc1 / (1.f + expf(-acc1));
  uint32_t packed = (uint32_t)f2bf(s0) | ((uint32_t)f2bf(s1) << 16);
  *(uint32_t*)(xcb + (size_t)row * CONV_DIM + c) = packed;
}

// ============================================================
// K5a: SSD chunk state summaries (xc now bf16)
// ============================================================
__global__ __launch_bounds__(256) void k_ssd_state(const ushort_t* __restrict__ xcb,
    const float* __restrict__ dtb, const float* __restrict__ aw,
    float* __restrict__ HS, float* __restrict__ Pbuf) {
  const int ch = blockIdx.x, bh = blockIdx.y;
  const int b = bh >> 3, h = bh & 7;
  const int t0 = ch * QC;
  const int valid = (L_SEQ - t0 < QC) ? (L_SEQ - t0) : QC;
  const size_t rowbase = (size_t)b * L_SEQ;
  __shared__ __attribute__((aligned(16))) short sBT[128][72];
  __shared__ __attribute__((aligned(16))) short sXw[64][72];
  __shared__ float sW[64];
  __shared__ float sLtot;
  const int tid = threadIdx.x;
  if (tid < 64) {
    float aa = 0.f, dd = 0.f;
    if (tid < valid) { size_t r8 = (rowbase + t0 + tid) * 8 + h; aa = aw[r8]; dd = dtb[r8]; }
    float s = aa;
#pragma unroll
    for (int d = 1; d < 64; d <<= 1) { float o = __shfl_up(s, d, 64); if (tid >= d) s += o; }
    float Lt = __shfl(s, 63, 64);
    sW[tid] = expf(Lt - s) * dd;
    if (tid == 63) sLtot = s;
  }
  __syncthreads();
  for (int i = tid; i < 64 * 16; i += 256) {       // B transpose-stage
    int r = i >> 4, q = (i & 15) * 8;
    short8 v = {0, 0, 0, 0, 0, 0, 0, 0};
    if (r < valid) v = *(const short8*)(xcb + (rowbase + t0 + r) * CONV_DIM + 512 + q);
#pragma unroll
    for (int j = 0; j < 8; j++) sBT[q + j][r] = v[j];
  }
  for (int i = tid; i < 64 * 8; i += 256) {        // Xw transpose-stage (rescale)
    int r = i >> 3, q = (i & 7) * 8;
    short8 v = {0, 0, 0, 0, 0, 0, 0, 0};
    if (r < valid) v = *(const short8*)(xcb + (rowbase + t0 + r) * CONV_DIM + h * 64 + q);
    float wv = sW[r];
#pragma unroll
    for (int j = 0; j < 8; j++) sXw[q + j][r] = (short)f2bf(bf2f((ushort_t)v[j]) * wv);
  }
  __syncthreads();
  const int w = tid >> 6, l15 = tid & 15, lK = (tid & 63) >> 4;
  f32x4 acc[2][4] = {};
  short8 afr[2][2];
#pragma unroll
  for (int j = 0; j < 2; j++)
#pragma unroll
    for (int kt = 0; kt < 2; kt++)
      afr[j][kt] = *(const short8*)&sBT[(w * 2 + j) * 16 + l15][kt * 32 + lK * 8];
#pragma unroll
  for (int pt = 0; pt < 4; pt++) {
#pragma unroll
    for (int kt = 0; kt < 2; kt++) {
      short8 bfr = *(const short8*)&sXw[pt * 16 + l15][kt * 32 + lK * 8];
      acc[0][pt] = MFMA16(afr[0][kt], bfr, acc[0][pt]);
      acc[1][pt] = MFMA16(afr[1][kt], bfr, acc[1][pt]);
    }
  }
  float* dst = HS + ((size_t)bh * NCH + ch) * 8192;
#pragma unroll
  for (int j = 0; j < 2; j++)
#pragma unroll
    for (int pt = 0; pt < 4; pt++)
#pragma unroll
      for (int i = 0; i < 4; i++) {
        int n = (w * 2 + j) * 16 + lK * 4 + i, p = pt * 16 + l15;
        dst[n * 64 + p] = acc[j][pt][i];
      }
  if (tid == 0) Pbuf[bh * NCH + ch] = expf(sLtot);
}

// ============================================================
// K5b: sequential inter-chunk combine (in place)
// ============================================================
__global__ __launch_bounds__(256) void k_ssd_comb(float* __restrict__ HS,
                                                  const float* __restrict__ Pbuf) {
  const int bh = blockIdx.y;
  const int e  = blockIdx.x * 256 + threadIdx.x;
  float run = 0.f;
  for (int c = 0; c < NCH; c++) {
    size_t idx = ((size_t)bh * NCH + c) * 8192 + e;
    float s = HS[idx];
    run = fmaf(Pbuf[bh * NCH + c], run, s);
    HS[idx] = run;
  }
}

// ============================================================
// K5c: SSD output (xc now bf16)
// ============================================================
__global__ __launch_bounds__(256) void k_ssd_y(const ushort_t* __restrict__ xcb,
    const float* __restrict__ dtb, const float* __restrict__ aw,
    const float* __restrict__ Dskip, const float* __restrict__ HS,
    float* __restrict__ y) {
  const int ch = blockIdx.x, bh = blockIdx.y;
  const int b = bh >> 3, h = bh & 7;
  const int t0 = ch * QC;
  const int valid = (L_SEQ - t0 < QC) ? (L_SEQ - t0) : QC;
  const size_t rowbase = (size_t)b * L_SEQ;
  __shared__ __attribute__((aligned(16))) short sB[64][136];
  __shared__ __attribute__((aligned(16))) short sC[64][136];
  __shared__ __attribute__((aligned(16))) short sH[64][136];
  __shared__ __attribute__((aligned(16))) short sX[64][72];
  __shared__ float sLrel[64], sdt[64], sEL[64];
  short (*sM)[72] = (short(*)[72])&sB[0][0];
  const int tid = threadIdx.x;
  if (tid < 64) {
    float aa = 0.f, dd = 0.f;
    if (tid < valid) { size_t r8 = (rowbase + t0 + tid) * 8 + h; aa = aw[r8]; dd = dtb[r8]; }
    float s = aa;
#pragma unroll
    for (int d = 1; d < 64; d <<= 1) { float o = __shfl_up(s, d, 64); if (tid >= d) s += o; }
    sLrel[tid] = s; sdt[tid] = dd; sEL[tid] = expf(s);
  }
  for (int i = tid; i < 64 * 16; i += 256) {       // B and C rows (direct bf16 copy)
    int r = i >> 4, q = (i & 15) * 8;
    short8 vb = {0, 0, 0, 0, 0, 0, 0, 0}, vc = {0, 0, 0, 0, 0, 0, 0, 0};
    if (r < valid) {
      const ushort_t* rp = xcb + (rowbase + t0 + r) * CONV_DIM;
      vb = *(const short8*)(rp + 512 + q);
      vc = *(const short8*)(rp + 640 + q);
    }
#pragma unroll
    for (int j = 0; j < 8; j++) { sB[r][q + j] = vb[j]; sC[r][q + j] = vc[j]; }
  }
  for (int i = tid; i < 64 * 8; i += 256) {        // X transpose-stage
    int r = i >> 3, q = (i & 7) * 8;
    short8 v = {0, 0, 0, 0, 0, 0, 0, 0};
    if (r < valid) v = *(const short8*)(xcb + (rowbase + t0 + r) * CONV_DIM + h * 64 + q);
#pragma unroll
    for (int j = 0; j < 8; j++) sX[q + j][r] = v[j];
  }
  for (int i = tid; i < 128 * 16; i += 256) {      // Hin transpose-stage (fp32 src)
    int n = i >> 4, q = (i & 15) * 4;
    float4 v = {0, 0, 0, 0};
    if (ch > 0) v = *(const float4*)(HS + ((size_t)bh * NCH + (ch - 1)) * 8192 + n * 64 + q);
    sH[q + 0][n] = (short)f2bf(v.x); sH[q + 1][n] = (short)f2bf(v.y);
    sH[q + 2][n] = (short)f2bf(v.z); sH[q + 3][n] = (short)f2bf(v.w);
  }
  __syncthreads();
  const int w = tid >> 6, l15 = tid & 15, lK = (tid & 63) >> 4;
  short8 aC[4];
#pragma unroll
  for (int kt = 0; kt < 4; kt++)
    aC[kt] = *(const short8*)&sC[w * 16 + l15][kt * 32 + lK * 8];
  f32x4 g[4] = {};
#pragma unroll
  for (int st = 0; st < 4; st++)
#pragma unroll
    for (int kt = 0; kt < 4; kt++)
      g[st] = MFMA16(aC[kt], *(const short8*)&sB[st * 16 + l15][kt * 32 + lK * 8], g[st]);
  __syncthreads();
#pragma unroll
  for (int st = 0; st < 4; st++)
#pragma unroll
    for (int i = 0; i < 4; i++) {
      int tt = w * 16 + lK * 4 + i, ss = st * 16 + l15;
      float f = (ss <= tt) ? expf(sLrel[tt] - sLrel[ss]) * sdt[ss] : 0.f;
      sM[tt][ss] = (short)f2bf(g[st][i] * f);
    }
  __syncthreads();
  f32x4 acc[4] = {};
#pragma unroll
  for (int pt = 0; pt < 4; pt++)
#pragma unroll
    for (int kt = 0; kt < 4; kt++)
      acc[pt] = MFMA16(aC[kt], *(const short8*)&sH[pt * 16 + l15][kt * 32 + lK * 8], acc[pt]);
#pragma unroll
  for (int pt = 0; pt < 4; pt++)
#pragma unroll
    for (int i = 0; i < 4; i++)
      acc[pt][i] *= sEL[w * 16 + lK * 4 + i];
  short8 aM[2];
#pragma unroll
  for (int kt = 0; kt < 2; kt++)
    aM[kt] = *(const short8*)&sM[w * 16 + l15][kt * 32 + lK * 8];
#pragma unroll
  for (int pt = 0; pt < 4; pt++)
#pragma unroll
    for (int kt = 0; kt < 2; kt++)
      acc[pt] = MFMA16(aM[kt], *(const short8*)&sX[pt * 16 + l15][kt * 32 + lK * 8], acc[pt]);
  const float Dsk = Dskip[h];
#pragma unroll
  for (int pt = 0; pt < 4; pt++)
#pragma unroll
    for (int i = 0; i < 4; i++) {
      int tt = w * 16 + lK * 4 + i;
      if (tt < valid) {
        int pp = pt * 16 + l15;
        y[(rowbase + t0 + tt) * D_INNER + h * 64 + pp] =
            acc[pt][i] + Dsk * bf2f((ushort_t)sX[pp][tt]);
      }
    }
}

// ============================================================
// K6: gate + RMSNorm; bf16 in-place, packed 4B stores
// ============================================================
__global__ __launch_bounds__(512) void k_norm(float* __restrict__ y,
    const float* __restrict__ zx, const float* __restrict__ norm_w) {
  const int row = blockIdx.x;
  const int c = threadIdx.x;
  float z = zx[(size_t)row * D_IN_PROJ + c];
  float g = z / (1.f + expf(-z));
  float v = y[(size_t)row * D_INNER + c] * g;
  float ss = v * v;
#pragma unroll
  for (int m = 32; m >= 1; m >>= 1) ss += __shfl_xor(ss, m, 64);
  __shared__ float red[8];
  if ((threadIdx.x & 63) == 0) red[threadIdx.x >> 6] = ss;
  __syncthreads();
  float tot = 0.f;
#pragma unroll
  for (int i = 0; i < 8; i++) tot += red[i];
  float scale = rsqrtf(tot * (1.f / 512.f) + 1e-5f);
  uint32_t mine = f2bf(v * scale * norm_w[c]);
  uint32_t other = (uint32_t)__shfl_xor((int)mine, 1, 64);
  if ((c & 1) == 0)
    *(uint32_t*)((ushort_t*)(y + (size_t)row * D_INNER) + c) = mine | (other << 16);
}

// ============================================================
// K8: conv1 (256->8ch, K=16, pad(7,8)) partials
// ============================================================
__global__ __launch_bounds__(256) void k_conv1(const float* __restrict__ om,
    const float* __restrict__ w, float* __restrict__ yc1a, float* __restrict__ yc1b) {
  const int tt = blockIdx.x, b = blockIdx.y, zc = blockIdx.z;
  const int t0 = tt * 128;
  const int tsub = threadIdx.x >> 1;
  const int ochalf = threadIdx.x & 1;
  __shared__ float inl[143][65];
  __shared__ float wl[64][16][8];
  float acc[4] = {0, 0, 0, 0};
  for (int cc2 = 0; cc2 < 2; cc2++) {
    const int icc = zc * 2 + cc2;
    __syncthreads();
    for (int i = threadIdx.x; i < 143 * 64; i += 256) {
      int r = i >> 6, cc = i & 63;
      int tin = t0 - 7 + r;
      float v = 0.f;
      if (tin >= 0 && tin < L_SEQ)
        v = om[((size_t)b * L_SEQ + tin) * 256 + icc * 64 + cc];
      inl[r][cc] = v;
    }
    for (int i = threadIdx.x; i < 64 * 16 * 8; i += 256) {
      int oc = i & 7, k = (i >> 3) & 15, ic = i >> 7;
      wl[ic][k][oc] = w[((size_t)oc * 256 + icc * 64 + ic) * 16 + k];
    }
    __syncthreads();
    for (int ic = 0; ic < 64; ic++) {
#pragma unroll
      for (int k = 0; k < 16; k++) {
        float iv = inl[tsub + k][ic];
        float4 wv = *(const float4*)&wl[ic][k][ochalf * 4];
        acc[0] = fmaf(iv, wv.x, acc[0]);
        acc[1] = fmaf(iv, wv.y, acc[1]);
        acc[2] = fmaf(iv, wv.z, acc[2]);
        acc[3] = fmaf(iv, wv.w, acc[3]);
      }
    }
  }
  int t = t0 + tsub;
  if (t < L_SEQ) {
    float* dst = (zc == 0) ? yc1a : yc1b;
#pragma unroll
    for (int j = 0; j < 4; j++)
      dst[((size_t)b * 8 + ochalf * 4 + j) * L_SEQ + t] = acc[j];
  }
}

// ============================================================
// K9: transposed conv (8->4ch, K=16, lhs_dilation=8, pad 15/15)
// ============================================================
__global__ void k_convT(const float* __restrict__ yc1a, const float* __restrict__ yc1b,
                        const float* __restrict__ b1, const float* __restrict__ wT,
                        const float* __restrict__ bT, float* __restrict__ out) {
  const int s = blockIdx.x * 256 + threadIdx.x;
  const int c = blockIdx.y, b = blockIdx.z;
  float acc = bT[c];
  const int k0 = (15 - (s & 7)) & 7;
#pragma unroll
  for (int dk = 0; dk < 2; dk++) {
    int k = k0 + 8 * dk;
    int num = s - 15 + k;
    int m = num >> 3;
    if (num >= 0 && m < L_SEQ) {
#pragma unroll
      for (int j = 0; j < 8; j++) {
        float v = yc1a[((size_t)b * 8 + j) * L_SEQ + m]
                + yc1b[((size_t)b * 8 + j) * L_SEQ + m] + b1[j];
        acc = fmaf(v, wT[((size_t)j * 4 + c) * 16 + (15 - k)], acc);
      }
    }
  }
  out[((size_t)b * 4 + c) * L_IN + s] = acc;
}

// ============================================================
extern "C" void kernel_launch(void* const* d_in, const int* in_sizes, int n_in,
                              void* d_out, int out_size, void* d_ws, size_t ws_size,
                              hipStream_t stream) {
  const float* x         = (const float*)d_in[0];
  const float* conv_w    = (const float*)d_in[1];
  const float* conv_b    = (const float*)d_in[2];
  const float* in_proj_w = (const float*)d_in[3];
  const float* conv1d_w  = (const float*)d_in[4];
  const float* conv1d_b  = (const float*)d_in[5];
  const float* dt_bias   = (const float*)d_in[6];
  const float* A_log     = (const float*)d_in[7];
  const float* D_skip    = (const float*)d_in[8];
  const float* norm_w    = (const float*)d_in[9];
  const float* out_proj_w= (const float*)d_in[10];
  const float* conv1_w   = (const float*)d_in[11];
  const float* conv1_b   = (const float*)d_in[12];
  const float* convT_w   = (const float*)d_in[13];
  const float* convT_b   = (const float*)d_in[14];
  float* out = (float*)d_out;
  float* ws  = (float*)d_ws;

  ushort_t* ub   = (ushort_t*)(ws + OFF_U);
  ushort_t* PB   = (ushort_t*)(ws + OFF_PB);
  float* zx   = ws + OFF_ZX;
  float* dtb  = ws + OFF_DT;
  float* awb  = ws + OFF_AW;
  ushort_t* xcb = (ushort_t*)(ws + OFF_XC);
  float* yb   = ws + OFF_Y;
  float* yc1a = ws + OFF_YC1A;
  float* yc1b = ws + OFF_YC1B;
  float* HS   = ws + OFF_HS;
  ushort_t* wbin  = (ushort_t*)(ws + OFF_WBIN);
  ushort_t* wbout = (ushort_t*)(ws + OFF_WBOUT);
  ushort_t* wbf   = (ushort_t*)(ws + OFF_WBF);
  float* om   = ws + OFF_U;   // u region dead after in_proj GEMM
  float* Pbuf = yc1a;

  // 0. weight casts
  k_cast<<<dim3((D_IN_PROJ * 256 + 255) / 256), 256, 0, stream>>>(
      in_proj_w, out_proj_w, conv_w, wbin, wbout, wbf);
  // 1. front conv as im2col + MFMA GEMM (bias+relu+bf16 epilogue)
  k_im2col<<<dim3((M_TOK * 8 + 255) / 256), 256, 0, stream>>>(x, PB);
  gemm_bf16<1><<<dim3(2, 128), 256, 0, stream>>>(PB, 64, wbf, 64, (float*)ub,
                                                 conv_b, M_TOK, 256, 64);
  // 2. in_proj: zx = u @ W^T (bf16 MFMA)
  gemm_bf16<0><<<dim3(11, 128), 256, 0, stream>>>(ub, 256, wbin, 256, zx,
                                                  nullptr, M_TOK, D_IN_PROJ, 256);
  // 3. dt / a
  k_dt<<<dim3((M_TOK * NHEADS + 255) / 256), 256, 0, stream>>>(zx, dt_bias, A_log, dtb, awb);
  // 4. depthwise conv + silu -> xc (bf16)
  k_dw<<<dim3((int)(((size_t)M_TOK * 384 + 255) / 256)), 256, 0, stream>>>(
      zx, conv1d_w, conv1d_b, xcb);
  // 5. SSD scan (MFMA)
  k_ssd_state<<<dim3(NCH, 64), 256, 0, stream>>>(xcb, dtb, awb, HS, Pbuf);
  k_ssd_comb<<<dim3(32, 64), 256, 0, stream>>>(HS, Pbuf);
  k_ssd_y<<<dim3(NCH, 64), 256, 0, stream>>>(xcb, dtb, awb, D_skip, HS, yb);
  // 6. gate + RMSNorm -> bf16 in place
  k_norm<<<dim3(M_TOK), 512, 0, stream>>>(yb, zx, norm_w);
  // 7. out_proj: om = y @ Wout^T (bf16 MFMA)
  gemm_bf16<0><<<dim3(2, 128), 256, 0, stream>>>((ushort_t*)yb, 1024, wbout, 512, om,
                                                 nullptr, M_TOK, 256, D_INNER);
  // 8. conv1 partials
  k_conv1<<<dim3(16, 8, 2), 256, 0, stream>>>(om, conv1_w, yc1a, yc1b);
  // 9. transposed conv -> out
  k_convT<<<dim3(64, 4, 8), 256, 0, stream>>>(yc1a, yc1b, conv1_b, convT_w, convT_b, out);
}

// Round 6
// 264.900 us; speedup vs baseline: 3.9709x; 1.1637x over previous
//
#include <hip/hip_runtime.h>
#include <cstddef>
#include <cstdint>

// ---------------- problem constants ----------------
constexpr int L_IN   = 16384;
constexpr int L_SEQ  = 2047;          // (16384-16)/8 + 1
constexpr int BATCH  = 8;
constexpr int M_TOK  = BATCH * L_SEQ; // 16376
constexpr int D_INNER = 512;
constexpr int NHEADS  = 8;
constexpr int HEADDIM = 64;
constexpr int D_STATE = 128;
constexpr int CONV_DIM = 768;
constexpr int D_IN_PROJ = 1288;

// SSD chunking
constexpr int QC  = 64;
constexpr int NCH = 32;

// ---------------- workspace layout (floats) ----------------
constexpr size_t OFF_U    = 0;                       // ub bf16 / later Y fp32 (2.1M floats)
constexpr size_t OFF_PB   = OFF_U   + 2096128;       // im2col patches bf16
constexpr size_t OFF_ZX   = OFF_U   + 4192256;
constexpr size_t OFF_DT   = OFF_ZX  + 21092288;
constexpr size_t OFF_AW   = OFF_DT  + 131008;
constexpr size_t OFF_XC   = OFF_AW  + 131008;        // xc bf16
constexpr size_t OFF_Y    = OFF_XC  + 12576768;
constexpr size_t OFF_YC1A = OFF_Y   + 8384512;       // yc1 (single, b1 folded)
constexpr size_t OFF_YC1B = OFF_YC1A + 131008;       // Pbuf lives here now
constexpr size_t OFF_HS   = OFF_YC1B + 131008;       // bf16 now: 16.7M ushorts (8.4M fl)
constexpr size_t OFF_WBIN = OFF_HS  + 16777216;      // keep offsets (HS shrank, gap ok)
constexpr size_t OFF_WBOUT= OFF_WBIN + 164864;
constexpr size_t OFF_WBF  = OFF_WBOUT + 65536;       // 256*64 bf16
constexpr size_t OFF_W2   = OFF_WBF + 8192;          // 128*512 bf16 = 32768 floats
// total = 63,818,432 floats ~= 255.3 MB (255.1 passed in R4/R5)

using short8 = __attribute__((ext_vector_type(8))) short;  // 8 bf16
using f32x4  = __attribute__((ext_vector_type(4))) float;
typedef unsigned short ushort_t;

__device__ __forceinline__ ushort_t f2bf(float f) {        // RNE f32->bf16
  uint32_t u = __float_as_uint(f);
  u += 0x7fffu + ((u >> 16) & 1u);
  return (ushort_t)(u >> 16);
}
__device__ __forceinline__ float bf2f(ushort_t h) {
  return __uint_as_float(((uint32_t)h) << 16);
}
#define MFMA16(a, b, c) __builtin_amdgcn_mfma_f32_16x16x32_bf16(a, b, c, 0, 0, 0)

// ============================================================
// K0: cast weights to bf16 (in_proj, out_proj[unused now but cheap], front conv)
// ============================================================
__global__ void k_cast(const float* __restrict__ w1, const float* __restrict__ w3,
                       ushort_t* __restrict__ o1, ushort_t* __restrict__ o3) {
  int i = blockIdx.x * 256 + threadIdx.x;
  if (i < D_IN_PROJ * 256) o1[i] = f2bf(w1[i]);
  if (i < 256 * 64)        o3[i] = f2bf(w3[i]);
}

// ============================================================
// K0b: W2[r=oc*16+k][d] = sum_ic w1[oc][ic][k] * wout[ic][d]   (-> bf16)
//      Fuses conv1 into out_proj.  128 blocks x 256 thr, 2 cols/thr.
// ============================================================
__global__ __launch_bounds__(256) void k_wcomb(const float* __restrict__ w1,
    const float* __restrict__ wout, ushort_t* __restrict__ W2b) {
  const int r = blockIdx.x;           // 0..127
  const int oc = r >> 4, k = r & 15;
  const int d0 = threadIdx.x;
  float acc0 = 0.f, acc1 = 0.f;
  for (int o = 0; o < 256; o++) {
    float wv = w1[((size_t)oc * 256 + o) * 16 + k];
    acc0 = fmaf(wv, wout[(size_t)o * 512 + d0], acc0);
    acc1 = fmaf(wv, wout[(size_t)o * 512 + d0 + 256], acc1);
  }
  W2b[(size_t)r * 512 + d0]       = f2bf(acc0);
  W2b[(size_t)r * 512 + d0 + 256] = f2bf(acc1);
}

// ============================================================
// K1a: im2col for front conv (no boundary handling needed)
// ============================================================
__global__ __launch_bounds__(256) void k_im2col(const float* __restrict__ x,
                                                ushort_t* __restrict__ PB) {
  int idx = blockIdx.x * 256 + threadIdx.x;
  if (idx >= M_TOK * 8) return;
  int oct = idx & 7, row = idx >> 3;
  int t = row % L_SEQ, b = row / L_SEQ;
  int ic = oct >> 1, k0 = (oct & 1) * 8;
  const float* src = x + ((size_t)b * 4 + ic) * L_IN + t * 8 + k0;
  float4 a0 = *(const float4*)src;
  float4 a1 = *(const float4*)(src + 4);
  short8 o;
  o[0] = (short)f2bf(a0.x); o[1] = (short)f2bf(a0.y);
  o[2] = (short)f2bf(a0.z); o[3] = (short)f2bf(a0.w);
  o[4] = (short)f2bf(a1.x); o[5] = (short)f2bf(a1.y);
  o[6] = (short)f2bf(a1.z); o[7] = (short)f2bf(a1.w);
  *(short8*)(PB + (size_t)row * 64 + oct * 8) = o;
}

// ============================================================
// K2: bf16 MFMA GEMM NT.  128x128 tile, BK=64, 4 waves, LDS XOR swizzle.
// EPI=0: fp32 store.  EPI=1: +bias, relu, bf16 packed-pair store.
// ============================================================
template<int EPI>
__global__ __launch_bounds__(256) void gemm_bf16(const ushort_t* __restrict__ A, int lda,
    const ushort_t* __restrict__ B, int ldb, float* __restrict__ C,
    const float* __restrict__ bias, int M, int N, int K) {
  __shared__ __attribute__((aligned(16))) ushort_t sA[128 * 64];
  __shared__ __attribute__((aligned(16))) ushort_t sB[128 * 64];
  const int tid = threadIdx.x;
  const int m0 = blockIdx.y * 128, n0 = blockIdx.x * 128;
  const int w = tid >> 6, lane = tid & 63;
  const int l15 = lane & 15, lK = lane >> 4;
  const int wr = w >> 1, wc = w & 1;
  f32x4 acc[4][4] = {};
  for (int k0 = 0; k0 < K; k0 += 64) {
    __syncthreads();
#pragma unroll
    for (int j = 0; j < 4; j++) {
      int idx = j * 256 + tid;
      int r = idx >> 3, s = idx & 7;
      short8 va = {0, 0, 0, 0, 0, 0, 0, 0};
      int gm = m0 + r;
      if (gm < M) va = *(const short8*)(A + (size_t)gm * lda + k0 + s * 8);
      *(short8*)&sA[r * 64 + ((s ^ (r & 7)) * 8)] = va;
      short8 vb = {0, 0, 0, 0, 0, 0, 0, 0};
      int gn = n0 + r;
      if (gn < N) vb = *(const short8*)(B + (size_t)gn * ldb + k0 + s * 8);
      *(short8*)&sB[r * 64 + ((s ^ (r & 7)) * 8)] = vb;
    }
    __syncthreads();
#pragma unroll
    for (int kk = 0; kk < 2; kk++) {
      short8 af[4], bf[4];
#pragma unroll
      for (int mt = 0; mt < 4; mt++) {
        int r = wr * 64 + mt * 16 + l15;
        af[mt] = *(const short8*)&sA[r * 64 + (((kk * 4 + lK) ^ (r & 7)) * 8)];
      }
#pragma unroll
      for (int nt = 0; nt < 4; nt++) {
        int r = wc * 64 + nt * 16 + l15;
        bf[nt] = *(const short8*)&sB[r * 64 + (((kk * 4 + lK) ^ (r & 7)) * 8)];
      }
#pragma unroll
      for (int mt = 0; mt < 4; mt++)
#pragma unroll
        for (int nt = 0; nt < 4; nt++)
          acc[mt][nt] = MFMA16(af[mt], bf[nt], acc[mt][nt]);
    }
  }
  if constexpr (EPI == 0) {
#pragma unroll
    for (int mt = 0; mt < 4; mt++)
#pragma unroll
      for (int i = 0; i < 4; i++) {
        int gm = m0 + wr * 64 + mt * 16 + lK * 4 + i;
        if (gm < M) {
          float* crow = C + (size_t)gm * N;
#pragma unroll
          for (int nt = 0; nt < 4; nt++) {
            int gn = n0 + wc * 64 + nt * 16 + l15;
            if (gn < N) crow[gn] = acc[mt][nt][i];
          }
        }
      }
  } else {
    ushort_t* Cb = (ushort_t*)C;
#pragma unroll
    for (int mt = 0; mt < 4; mt++)
#pragma unroll
      for (int i = 0; i < 4; i++) {
        int gm = m0 + wr * 64 + mt * 16 + lK * 4 + i;
#pragma unroll
        for (int nt = 0; nt < 4; nt++) {
          int gn = n0 + wc * 64 + nt * 16 + l15;
          float v = fmaxf(acc[mt][nt][i] + bias[gn], 0.f);
          uint32_t mine = f2bf(v);
          uint32_t other = (uint32_t)__shfl_xor((int)mine, 1, 64);
          if (((lane & 1) == 0) && gm < M)
            *(uint32_t*)(Cb + (size_t)gm * N + gn) = mine | (other << 16);
        }
      }
  }
}

// ============================================================
// K3: dt = softplus(...); a = log dA = -exp(A_log)*dt
// ============================================================
__global__ void k_dt(const float* __restrict__ zx, const float* __restrict__ dt_bias,
                     const float* __restrict__ A_log, float* __restrict__ dt,
                     float* __restrict__ aw) {
  int i = blockIdx.x * 256 + threadIdx.x;
  if (i >= M_TOK * NHEADS) return;
  int hd = i & 7;
  int row = i >> 3;
  float v = zx[(size_t)row * D_IN_PROJ + (D_INNER + CONV_DIM) + hd] + dt_bias[hd];
  float sp = (v > 20.f) ? v : log1pf(expf(v));
  dt[i] = sp;
  aw[i] = -expf(A_log[hd]) * sp;
}

// ============================================================
// K4: depthwise causal conv + bias + silu -> xc (bf16, packed 4B stores)
// ============================================================
__global__ void k_dw(const float* __restrict__ zx, const float* __restrict__ w,
                     const float* __restrict__ bias, ushort_t* __restrict__ xcb) {
  size_t idx = (size_t)blockIdx.x * 256 + threadIdx.x;
  if (idx >= (size_t)M_TOK * 384) return;
  int cp = (int)(idx % 384);
  int c = cp * 2;
  int row = (int)(idx / 384);
  int t = row % L_SEQ, b = row / L_SEQ;
  float acc0 = bias[c], acc1 = bias[c + 1];
  float w0[4], w1[4];
#pragma unroll
  for (int k = 0; k < 4; k++) { w0[k] = w[c * 4 + k]; w1[k] = w[(c + 1) * 4 + k]; }
#pragma unroll
  for (int k = 0; k < 4; k++) {
    int tt = t - 3 + k;
    if (tt >= 0) {
      const float* p = zx + ((size_t)b * L_SEQ + tt) * D_IN_PROJ + D_INNER + c;
      float2 v = *(const float2*)p;
      acc0 = fmaf(v.x, w0[k], acc0);
      acc1 = fmaf(v.y, w1[k], acc1);
    }
  }
  float s0 = acc0 / (1.f + expf(-acc0));
  float s1 = acc1 / (1.f + expf(-acc1));
  uint32_t packed = (uint32_t)f2bf(s0) | ((uint32_t)f2bf(s1) << 16);
  *(uint32_t*)(xcb + (size_t)row * CONV_DIM + c) = packed;
}

// ============================================================
// K5a: SSD chunk state summaries -> HS (bf16, packed-pair stores)
// ============================================================
__global__ __launch_bounds__(256) void k_ssd_state(const ushort_t* __restrict__ xcb,
    const float* __restrict__ dtb, const float* __restrict__ aw,
    ushort_t* __restrict__ HSb, float* __restrict__ Pbuf) {
  const int ch = blockIdx.x, bh = blockIdx.y;
  const int b = bh >> 3, h = bh & 7;
  const int t0 = ch * QC;
  const int valid = (L_SEQ - t0 < QC) ? (L_SEQ - t0) : QC;
  const size_t rowbase = (size_t)b * L_SEQ;
  __shared__ __attribute__((aligned(16))) short sBT[128][72];
  __shared__ __attribute__((aligned(16))) short sXw[64][72];
  __shared__ float sW[64];
  __shared__ float sLtot;
  const int tid = threadIdx.x;
  if (tid < 64) {
    float aa = 0.f, dd = 0.f;
    if (tid < valid) { size_t r8 = (rowbase + t0 + tid) * 8 + h; aa = aw[r8]; dd = dtb[r8]; }
    float s = aa;
#pragma unroll
    for (int d = 1; d < 64; d <<= 1) { float o = __shfl_up(s, d, 64); if (tid >= d) s += o; }
    float Lt = __shfl(s, 63, 64);
    sW[tid] = expf(Lt - s) * dd;
    if (tid == 63) sLtot = s;
  }
  __syncthreads();
  for (int i = tid; i < 64 * 16; i += 256) {
    int r = i >> 4, q = (i & 15) * 8;
    short8 v = {0, 0, 0, 0, 0, 0, 0, 0};
    if (r < valid) v = *(const short8*)(xcb + (rowbase + t0 + r) * CONV_DIM + 512 + q);
#pragma unroll
    for (int j = 0; j < 8; j++) sBT[q + j][r] = v[j];
  }
  for (int i = tid; i < 64 * 8; i += 256) {
    int r = i >> 3, q = (i & 7) * 8;
    short8 v = {0, 0, 0, 0, 0, 0, 0, 0};
    if (r < valid) v = *(const short8*)(xcb + (rowbase + t0 + r) * CONV_DIM + h * 64 + q);
    float wv = sW[r];
#pragma unroll
    for (int j = 0; j < 8; j++) sXw[q + j][r] = (short)f2bf(bf2f((ushort_t)v[j]) * wv);
  }
  __syncthreads();
  const int w = tid >> 6, l15 = tid & 15, lK = (tid & 63) >> 4;
  f32x4 acc[2][4] = {};
  short8 afr[2][2];
#pragma unroll
  for (int j = 0; j < 2; j++)
#pragma unroll
    for (int kt = 0; kt < 2; kt++)
      afr[j][kt] = *(const short8*)&sBT[(w * 2 + j) * 16 + l15][kt * 32 + lK * 8];
#pragma unroll
  for (int pt = 0; pt < 4; pt++) {
#pragma unroll
    for (int kt = 0; kt < 2; kt++) {
      short8 bfr = *(const short8*)&sXw[pt * 16 + l15][kt * 32 + lK * 8];
      acc[0][pt] = MFMA16(afr[0][kt], bfr, acc[0][pt]);
      acc[1][pt] = MFMA16(afr[1][kt], bfr, acc[1][pt]);
    }
  }
  ushort_t* dst = HSb + ((size_t)bh * NCH + ch) * 8192;
#pragma unroll
  for (int j = 0; j < 2; j++)
#pragma unroll
    for (int pt = 0; pt < 4; pt++)
#pragma unroll
      for (int i = 0; i < 4; i++) {
        int n = (w * 2 + j) * 16 + lK * 4 + i, p = pt * 16 + l15;
        uint32_t mine = f2bf(acc[j][pt][i]);
        uint32_t other = (uint32_t)__shfl_xor((int)mine, 1, 64);
        if ((l15 & 1) == 0)
          *(uint32_t*)(dst + n * 64 + p) = mine | (other << 16);
      }
  if (tid == 0) Pbuf[bh * NCH + ch] = expf(sLtot);
}

// ============================================================
// K5b: sequential inter-chunk combine (in place, bf16 pairs, fp32 registers)
// ============================================================
__global__ __launch_bounds__(256) void k_ssd_comb(ushort_t* __restrict__ HSb,
                                                  const float* __restrict__ Pbuf) {
  const int bh = blockIdx.y;
  const int e2 = blockIdx.x * 256 + threadIdx.x;   // grid.x=16 -> 4096 pairs
  float run0 = 0.f, run1 = 0.f;
  for (int c = 0; c < NCH; c++) {
    size_t idx = ((size_t)bh * NCH + c) * 8192 + (size_t)e2 * 2;
    uint32_t pk = *(const uint32_t*)(HSb + idx);
    float P = Pbuf[bh * NCH + c];
    run0 = fmaf(P, run0, bf2f((ushort_t)(pk & 0xffff)));
    run1 = fmaf(P, run1, bf2f((ushort_t)(pk >> 16)));
    *(uint32_t*)(HSb + idx) = (uint32_t)f2bf(run0) | ((uint32_t)f2bf(run1) << 16);
  }
}

// ============================================================
// K5c: SSD output (HS bf16)
// ============================================================
__global__ __launch_bounds__(256) void k_ssd_y(const ushort_t* __restrict__ xcb,
    const float* __restrict__ dtb, const float* __restrict__ aw,
    const float* __restrict__ Dskip, const ushort_t* __restrict__ HSb,
    float* __restrict__ y) {
  const int ch = blockIdx.x, bh = blockIdx.y;
  const int b = bh >> 3, h = bh & 7;
  const int t0 = ch * QC;
  const int valid = (L_SEQ - t0 < QC) ? (L_SEQ - t0) : QC;
  const size_t rowbase = (size_t)b * L_SEQ;
  __shared__ __attribute__((aligned(16))) short sB[64][136];
  __shared__ __attribute__((aligned(16))) short sC[64][136];
  __shared__ __attribute__((aligned(16))) short sH[64][136];
  __shared__ __attribute__((aligned(16))) short sX[64][72];
  __shared__ float sLrel[64], sdt[64], sEL[64];
  short (*sM)[72] = (short(*)[72])&sB[0][0];
  const int tid = threadIdx.x;
  if (tid < 64) {
    float aa = 0.f, dd = 0.f;
    if (tid < valid) { size_t r8 = (rowbase + t0 + tid) * 8 + h; aa = aw[r8]; dd = dtb[r8]; }
    float s = aa;
#pragma unroll
    for (int d = 1; d < 64; d <<= 1) { float o = __shfl_up(s, d, 64); if (tid >= d) s += o; }
    sLrel[tid] = s; sdt[tid] = dd; sEL[tid] = expf(s);
  }
  for (int i = tid; i < 64 * 16; i += 256) {
    int r = i >> 4, q = (i & 15) * 8;
    short8 vb = {0, 0, 0, 0, 0, 0, 0, 0}, vc = {0, 0, 0, 0, 0, 0, 0, 0};
    if (r < valid) {
      const ushort_t* rp = xcb + (rowbase + t0 + r) * CONV_DIM;
      vb = *(const short8*)(rp + 512 + q);
      vc = *(const short8*)(rp + 640 + q);
    }
#pragma unroll
    for (int j = 0; j < 8; j++) { sB[r][q + j] = vb[j]; sC[r][q + j] = vc[j]; }
  }
  for (int i = tid; i < 64 * 8; i += 256) {
    int r = i >> 3, q = (i & 7) * 8;
    short8 v = {0, 0, 0, 0, 0, 0, 0, 0};
    if (r < valid) v = *(const short8*)(xcb + (rowbase + t0 + r) * CONV_DIM + h * 64 + q);
#pragma unroll
    for (int j = 0; j < 8; j++) sX[q + j][r] = v[j];
  }
  for (int i = tid; i < 128 * 8; i += 256) {       // Hin transpose-stage (bf16 src)
    int n = i >> 3, q = (i & 7) * 8;
    short8 v = {0, 0, 0, 0, 0, 0, 0, 0};
    if (ch > 0) v = *(const short8*)(HSb + ((size_t)bh * NCH + (ch - 1)) * 8192 + n * 64 + q);
#pragma unroll
    for (int j = 0; j < 8; j++) sH[q + j][n] = v[j];
  }
  __syncthreads();
  const int w = tid >> 6, l15 = tid & 15, lK = (tid & 63) >> 4;
  short8 aC[4];
#pragma unroll
  for (int kt = 0; kt < 4; kt++)
    aC[kt] = *(const short8*)&sC[w * 16 + l15][kt * 32 + lK * 8];
  f32x4 g[4] = {};
#pragma unroll
  for (int st = 0; st < 4; st++)
#pragma unroll
    for (int kt = 0; kt < 4; kt++)
      g[st] = MFMA16(aC[kt], *(const short8*)&sB[st * 16 + l15][kt * 32 + lK * 8], g[st]);
  __syncthreads();
#pragma unroll
  for (int st = 0; st < 4; st++)
#pragma unroll
    for (int i = 0; i < 4; i++) {
      int tt = w * 16 + lK * 4 + i, ss = st * 16 + l15;
      float f = (ss <= tt) ? expf(sLrel[tt] - sLrel[ss]) * sdt[ss] : 0.f;
      sM[tt][ss] = (short)f2bf(g[st][i] * f);
    }
  __syncthreads();
  f32x4 acc[4] = {};
#pragma unroll
  for (int pt = 0; pt < 4; pt++)
#pragma unroll
    for (int kt = 0; kt < 4; kt++)
      acc[pt] = MFMA16(aC[kt], *(const short8*)&sH[pt * 16 + l15][kt * 32 + lK * 8], acc[pt]);
#pragma unroll
  for (int pt = 0; pt < 4; pt++)
#pragma unroll
    for (int i = 0; i < 4; i++)
      acc[pt][i] *= sEL[w * 16 + lK * 4 + i];
  short8 aM[2];
#pragma unroll
  for (int kt = 0; kt < 2; kt++)
    aM[kt] = *(const short8*)&sM[w * 16 + l15][kt * 32 + lK * 8];
#pragma unroll
  for (int pt = 0; pt < 4; pt++)
#pragma unroll
    for (int kt = 0; kt < 2; kt++)
      acc[pt] = MFMA16(aM[kt], *(const short8*)&sX[pt * 16 + l15][kt * 32 + lK * 8], acc[pt]);
  const float Dsk = Dskip[h];
#pragma unroll
  for (int pt = 0; pt < 4; pt++)
#pragma unroll
    for (int i = 0; i < 4; i++) {
      int tt = w * 16 + lK * 4 + i;
      if (tt < valid) {
        int pp = pt * 16 + l15;
        y[(rowbase + t0 + tt) * D_INNER + h * 64 + pp] =
            acc[pt][i] + Dsk * bf2f((ushort_t)sX[pp][tt]);
      }
    }
}

// ============================================================
// K6: gate + RMSNorm; bf16 in-place, packed 4B stores
// ============================================================
__global__ __launch_bounds__(512) void k_norm(float* __restrict__ y,
    const float* __restrict__ zx, const float* __restrict__ norm_w) {
  const int row = blockIdx.x;
  const int c = threadIdx.x;
  float z = zx[(size_t)row * D_IN_PROJ + c];
  float g = z / (1.f + expf(-z));
  float v = y[(size_t)row * D_INNER + c] * g;
  float ss = v * v;
#pragma unroll
  for (int m = 32; m >= 1; m >>= 1) ss += __shfl_xor(ss, m, 64);
  __shared__ float red[8];
  if ((threadIdx.x & 63) == 0) red[threadIdx.x >> 6] = ss;
  __syncthreads();
  float tot = 0.f;
#pragma unroll
  for (int i = 0; i < 8; i++) tot += red[i];
  float scale = rsqrtf(tot * (1.f / 512.f) + 1e-5f);
  uint32_t mine = f2bf(v * scale * norm_w[c]);
  uint32_t other = (uint32_t)__shfl_xor((int)mine, 1, 64);
  if ((c & 1) == 0)
    *(uint32_t*)((ushort_t*)(y + (size_t)row * D_INNER) + c) = mine | (other << 16);
}

// ============================================================
// K8: diagonal gather-reduce: yc1[b][j][t] = b1[j] + sum_k Y[b,t-7+k][j*16+k]
// ============================================================
__global__ void k_red(const float* __restrict__ Y, const float* __restrict__ b1,
                      float* __restrict__ yc1) {
  int idx = blockIdx.x * 256 + threadIdx.x;   // (b*8+j)*L_SEQ + t
  if (idx >= BATCH * 8 * L_SEQ) return;
  int t = idx % L_SEQ;
  int bj = idx / L_SEQ;
  int j = bj & 7, b = bj >> 3;
  float acc = b1[j];
  const float* Yb = Y + (size_t)b * L_SEQ * 128;
#pragma unroll
  for (int k = 0; k < 16; k++) {
    int tt = t - 7 + k;
    if (tt >= 0 && tt < L_SEQ) acc += Yb[(size_t)tt * 128 + j * 16 + k];
  }
  yc1[idx] = acc;
}

// ============================================================
// K9: transposed conv (8->4ch, K=16, lhs_dilation=8, pad 15/15)
// ============================================================
__global__ void k_convT(const float* __restrict__ yc1,
                        const float* __restrict__ wT,
                        const float* __restrict__ bT, float* __restrict__ out) {
  const int s = blockIdx.x * 256 + threadIdx.x;
  const int c = blockIdx.y, b = blockIdx.z;
  float acc = bT[c];
  const int k0 = (15 - (s & 7)) & 7;
#pragma unroll
  for (int dk = 0; dk < 2; dk++) {
    int k = k0 + 8 * dk;
    int num = s - 15 + k;
    int m = num >> 3;
    if (num >= 0 && m < L_SEQ) {
#pragma unroll
      for (int j = 0; j < 8; j++) {
        float v = yc1[((size_t)b * 8 + j) * L_SEQ + m];
        acc = fmaf(v, wT[((size_t)j * 4 + c) * 16 + (15 - k)], acc);
      }
    }
  }
  out[((size_t)b * 4 + c) * L_IN + s] = acc;
}

// ============================================================
extern "C" void kernel_launch(void* const* d_in, const int* in_sizes, int n_in,
                              void* d_out, int out_size, void* d_ws, size_t ws_size,
                              hipStream_t stream) {
  const float* x         = (const float*)d_in[0];
  const float* conv_w    = (const float*)d_in[1];
  const float* conv_b    = (const float*)d_in[2];
  const float* in_proj_w = (const float*)d_in[3];
  const float* conv1d_w  = (const float*)d_in[4];
  const float* conv1d_b  = (const float*)d_in[5];
  const float* dt_bias   = (const float*)d_in[6];
  const float* A_log     = (const float*)d_in[7];
  const float* D_skip    = (const float*)d_in[8];
  const float* norm_w    = (const float*)d_in[9];
  const float* out_proj_w= (const float*)d_in[10];
  const float* conv1_w   = (const float*)d_in[11];
  const float* conv1_b   = (const float*)d_in[12];
  const float* convT_w   = (const float*)d_in[13];
  const float* convT_b   = (const float*)d_in[14];
  float* out = (float*)d_out;
  float* ws  = (float*)d_ws;

  ushort_t* ub   = (ushort_t*)(ws + OFF_U);
  ushort_t* PB   = (ushort_t*)(ws + OFF_PB);
  float* zx   = ws + OFF_ZX;
  float* dtb  = ws + OFF_DT;
  float* awb  = ws + OFF_AW;
  ushort_t* xcb = (ushort_t*)(ws + OFF_XC);
  float* yb   = ws + OFF_Y;
  float* yc1  = ws + OFF_YC1A;
  float* HSf  = ws + OFF_HS;
  ushort_t* HSb = (ushort_t*)HSf;
  ushort_t* wbin  = (ushort_t*)(ws + OFF_WBIN);
  ushort_t* wbf   = (ushort_t*)(ws + OFF_WBF);
  ushort_t* W2b   = (ushort_t*)(ws + OFF_W2);
  float* Yg   = ws + OFF_U;   // combined-GEMM output (U region dead after in_proj)
  float* Pbuf = ws + OFF_YC1B;

  // 0. weight casts + combined out_proj*conv1 weight
  k_cast<<<dim3((D_IN_PROJ * 256 + 255) / 256), 256, 0, stream>>>(
      in_proj_w, conv_w, wbin, wbf);
  k_wcomb<<<dim3(128), 256, 0, stream>>>(conv1_w, out_proj_w, W2b);
  // 1. front conv as im2col + MFMA GEMM
  k_im2col<<<dim3((M_TOK * 8 + 255) / 256), 256, 0, stream>>>(x, PB);
  gemm_bf16<1><<<dim3(2, 128), 256, 0, stream>>>(PB, 64, wbf, 64, (float*)ub,
                                                 conv_b, M_TOK, 256, 64);
  // 2. in_proj: zx = u @ W^T
  gemm_bf16<0><<<dim3(11, 128), 256, 0, stream>>>(ub, 256, wbin, 256, zx,
                                                  nullptr, M_TOK, D_IN_PROJ, 256);
  // 3. dt / a
  k_dt<<<dim3((M_TOK * NHEADS + 255) / 256), 256, 0, stream>>>(zx, dt_bias, A_log, dtb, awb);
  // 4. depthwise conv + silu -> xc (bf16)
  k_dw<<<dim3((int)(((size_t)M_TOK * 384 + 255) / 256)), 256, 0, stream>>>(
      zx, conv1d_w, conv1d_b, xcb);
  // 5. SSD scan (MFMA, bf16 states)
  k_ssd_state<<<dim3(NCH, 64), 256, 0, stream>>>(xcb, dtb, awb, HSb, Pbuf);
  k_ssd_comb<<<dim3(16, 64), 256, 0, stream>>>(HSb, Pbuf);
  k_ssd_y<<<dim3(NCH, 64), 256, 0, stream>>>(xcb, dtb, awb, D_skip, HSb, yb);
  // 6. gate + RMSNorm -> bf16 in place
  k_norm<<<dim3(M_TOK), 512, 0, stream>>>(yb, zx, norm_w);
  // 7. combined out_proj+conv1 GEMM: Y = ynorm @ W2^T  (M=16376,N=128,K=512)
  gemm_bf16<0><<<dim3(1, 128), 256, 0, stream>>>((ushort_t*)yb, 1024, W2b, 512, Yg,
                                                 nullptr, M_TOK, 128, D_INNER);
  // 8. diagonal gather-reduce -> yc1 (b1 folded)
  k_red<<<dim3((BATCH * 8 * L_SEQ + 255) / 256), 256, 0, stream>>>(Yg, conv1_b, yc1);
  // 9. transposed conv -> out
  k_convT<<<dim3(64, 4, 8), 256, 0, stream>>>(yc1, convT_w, convT_b, out);
}

// Round 8
// 263.152 us; speedup vs baseline: 3.9972x; 1.0066x over previous
//
#include <hip/hip_runtime.h>
#include <cstddef>
#include <cstdint>

// ---------------- problem constants ----------------
constexpr int L_IN   = 16384;
constexpr int L_SEQ  = 2047;          // (16384-16)/8 + 1
constexpr int BATCH  = 8;
constexpr int M_TOK  = BATCH * L_SEQ; // 16376
constexpr int D_INNER = 512;
constexpr int NHEADS  = 8;
constexpr int HEADDIM = 64;
constexpr int D_STATE = 128;
constexpr int CONV_DIM = 768;
constexpr int D_IN_PROJ = 1288;

// SSD chunking
constexpr int QC  = 64;
constexpr int NCH = 32;

// ---------------- workspace layout (float slots) ----------------
// R7 BUG FIX: zb needs M_TOK*512 ushorts = 4,192,256 float slots (was 2,096,128
// -> zb/xbcb overlap corrupted half the tokens). All offsets re-derived:
constexpr size_t OFF_U    = 0;                       // ub bf16 (2,096,128) / later Yg fp32
constexpr size_t OFF_PB   = OFF_U   + 2096128;       // im2col bf16 (524,032)
constexpr size_t OFF_ZB   = OFF_U   + 4192256;       // z bf16 [row][512] = 4,192,256
constexpr size_t OFF_XBC  = OFF_ZB  + 4192256;       // xBC bf16 [row][768] = 6,288,384
constexpr size_t OFF_DT   = OFF_XBC + 6288384;       // dt fp32 [row][8] = 131,008
constexpr size_t OFF_AW   = OFF_DT  + 131008;        // aw fp32 = 131,008
constexpr size_t OFF_XC   = OFF_AW  + 131008;        // xc bf16 [row][768] = 6,288,384
constexpr size_t OFF_Y    = OFF_XC  + 6288384;       // y bf16 [row][512] = 4,192,256
constexpr size_t OFF_YC1  = OFF_Y   + 4192256;       // yc1 fp32 = 131,008
constexpr size_t OFF_PBUF = OFF_YC1 + 131008;        // Pbuf fp32 = 2,048
constexpr size_t OFF_HS   = OFF_PBUF + 2048;         // HS bf16 = 8,388,608
constexpr size_t OFF_WBIN = OFF_HS  + 8388608;       // 164,864
constexpr size_t OFF_WBF  = OFF_WBIN + 164864;       // 8,192
constexpr size_t OFF_W2   = OFF_WBF + 8192;          // 32,768
// total = 34,143,040 floats ~= 136.6 MB (255MB available)

using short8 = __attribute__((ext_vector_type(8))) short;  // 8 bf16
using f32x4  = __attribute__((ext_vector_type(4))) float;
typedef unsigned short ushort_t;

__device__ __forceinline__ ushort_t f2bf(float f) {        // RNE f32->bf16
  uint32_t u = __float_as_uint(f);
  u += 0x7fffu + ((u >> 16) & 1u);
  return (ushort_t)(u >> 16);
}
__device__ __forceinline__ float bf2f(ushort_t h) {
  return __uint_as_float(((uint32_t)h) << 16);
}
#define MFMA16(a, b, c) __builtin_amdgcn_mfma_f32_16x16x32_bf16(a, b, c, 0, 0, 0)

// ============================================================
// K0: cast weights to bf16 (in_proj, front conv)
// ============================================================
__global__ void k_cast(const float* __restrict__ w1, const float* __restrict__ w3,
                       ushort_t* __restrict__ o1, ushort_t* __restrict__ o3) {
  int i = blockIdx.x * 256 + threadIdx.x;
  if (i < D_IN_PROJ * 256) o1[i] = f2bf(w1[i]);
  if (i < 256 * 64)        o3[i] = f2bf(w3[i]);
}

// ============================================================
// K0b: W2[r=oc*16+k][d] = sum_ic w1[oc][ic][k] * wout[ic][d]   (-> bf16)
// ============================================================
__global__ __launch_bounds__(256) void k_wcomb(const float* __restrict__ w1,
    const float* __restrict__ wout, ushort_t* __restrict__ W2b) {
  const int r = blockIdx.x;           // 0..127
  const int oc = r >> 4, k = r & 15;
  const int d0 = threadIdx.x;
  float acc0 = 0.f, acc1 = 0.f;
  for (int o = 0; o < 256; o++) {
    float wv = w1[((size_t)oc * 256 + o) * 16 + k];
    acc0 = fmaf(wv, wout[(size_t)o * 512 + d0], acc0);
    acc1 = fmaf(wv, wout[(size_t)o * 512 + d0 + 256], acc1);
  }
  W2b[(size_t)r * 512 + d0]       = f2bf(acc0);
  W2b[(size_t)r * 512 + d0 + 256] = f2bf(acc1);
}

// ============================================================
// K1a: im2col for front conv (no boundary handling needed)
// ============================================================
__global__ __launch_bounds__(256) void k_im2col(const float* __restrict__ x,
                                                ushort_t* __restrict__ PB) {
  int idx = blockIdx.x * 256 + threadIdx.x;
  if (idx >= M_TOK * 8) return;
  int oct = idx & 7, row = idx >> 3;
  int t = row % L_SEQ, b = row / L_SEQ;
  int ic = oct >> 1, k0 = (oct & 1) * 8;
  const float* src = x + ((size_t)b * 4 + ic) * L_IN + t * 8 + k0;
  float4 a0 = *(const float4*)src;
  float4 a1 = *(const float4*)(src + 4);
  short8 o;
  o[0] = (short)f2bf(a0.x); o[1] = (short)f2bf(a0.y);
  o[2] = (short)f2bf(a0.z); o[3] = (short)f2bf(a0.w);
  o[4] = (short)f2bf(a1.x); o[5] = (short)f2bf(a1.y);
  o[6] = (short)f2bf(a1.z); o[7] = (short)f2bf(a1.w);
  *(short8*)(PB + (size_t)row * 64 + oct * 8) = o;
}

// ============================================================
// K2: bf16 MFMA GEMM NT.  128x128 tile, BK=64, 4 waves, LDS XOR swizzle.
// EPI=0: fp32 store.  EPI=1: +bias, relu, bf16 packed store.
// EPI=2: in_proj region-split epilogue (z->zb, xBC->xbcb, dt fused).
// ============================================================
template<int EPI>
__global__ __launch_bounds__(256) void gemm_bf16(const ushort_t* __restrict__ A, int lda,
    const ushort_t* __restrict__ B, int ldb, float* __restrict__ C,
    const float* __restrict__ bias, int M, int N, int K,
    ushort_t* __restrict__ zb, ushort_t* __restrict__ xbcb,
    float* __restrict__ dtb, float* __restrict__ awb,
    const float* __restrict__ dt_bias, const float* __restrict__ A_log) {
  __shared__ __attribute__((aligned(16))) ushort_t sA[128 * 64];
  __shared__ __attribute__((aligned(16))) ushort_t sB[128 * 64];
  const int tid = threadIdx.x;
  const int m0 = blockIdx.y * 128, n0 = blockIdx.x * 128;
  const int w = tid >> 6, lane = tid & 63;
  const int l15 = lane & 15, lK = lane >> 4;
  const int wr = w >> 1, wc = w & 1;
  f32x4 acc[4][4] = {};
  for (int k0 = 0; k0 < K; k0 += 64) {
    __syncthreads();
#pragma unroll
    for (int j = 0; j < 4; j++) {
      int idx = j * 256 + tid;
      int r = idx >> 3, s = idx & 7;
      short8 va = {0, 0, 0, 0, 0, 0, 0, 0};
      int gm = m0 + r;
      if (gm < M) va = *(const short8*)(A + (size_t)gm * lda + k0 + s * 8);
      *(short8*)&sA[r * 64 + ((s ^ (r & 7)) * 8)] = va;
      short8 vb = {0, 0, 0, 0, 0, 0, 0, 0};
      int gn = n0 + r;
      if (gn < N) vb = *(const short8*)(B + (size_t)gn * ldb + k0 + s * 8);
      *(short8*)&sB[r * 64 + ((s ^ (r & 7)) * 8)] = vb;
    }
    __syncthreads();
#pragma unroll
    for (int kk = 0; kk < 2; kk++) {
      short8 af[4], bf[4];
#pragma unroll
      for (int mt = 0; mt < 4; mt++) {
        int r = wr * 64 + mt * 16 + l15;
        af[mt] = *(const short8*)&sA[r * 64 + (((kk * 4 + lK) ^ (r & 7)) * 8)];
      }
#pragma unroll
      for (int nt = 0; nt < 4; nt++) {
        int r = wc * 64 + nt * 16 + l15;
        bf[nt] = *(const short8*)&sB[r * 64 + (((kk * 4 + lK) ^ (r & 7)) * 8)];
      }
#pragma unroll
      for (int mt = 0; mt < 4; mt++)
#pragma unroll
        for (int nt = 0; nt < 4; nt++)
          acc[mt][nt] = MFMA16(af[mt], bf[nt], acc[mt][nt]);
    }
  }
  if constexpr (EPI == 0) {
#pragma unroll
    for (int mt = 0; mt < 4; mt++)
#pragma unroll
      for (int i = 0; i < 4; i++) {
        int gm = m0 + wr * 64 + mt * 16 + lK * 4 + i;
        if (gm < M) {
          float* crow = C + (size_t)gm * N;
#pragma unroll
          for (int nt = 0; nt < 4; nt++) {
            int gn = n0 + wc * 64 + nt * 16 + l15;
            if (gn < N) crow[gn] = acc[mt][nt][i];
          }
        }
      }
  } else if constexpr (EPI == 1) {
    ushort_t* Cb = (ushort_t*)C;
#pragma unroll
    for (int mt = 0; mt < 4; mt++)
#pragma unroll
      for (int i = 0; i < 4; i++) {
        int gm = m0 + wr * 64 + mt * 16 + lK * 4 + i;
#pragma unroll
        for (int nt = 0; nt < 4; nt++) {
          int gn = n0 + wc * 64 + nt * 16 + l15;
          float v = fmaxf(acc[mt][nt][i] + bias[gn], 0.f);
          uint32_t mine = f2bf(v);
          uint32_t other = (uint32_t)__shfl_xor((int)mine, 1, 64);
          if (((lane & 1) == 0) && gm < M)
            *(uint32_t*)(Cb + (size_t)gm * N + gn) = mine | (other << 16);
        }
      }
  } else {
    // EPI==2: region split. n-tile boundaries (512, 1280) are 128-aligned,
    // so each block takes exactly one uniform branch.
    if (n0 < 1280) {
      ushort_t* dst = (n0 < 512) ? zb : xbcb;
      const int ldd  = (n0 < 512) ? 512 : 768;
      const int coff = (n0 < 512) ? 0 : 512;
#pragma unroll
      for (int mt = 0; mt < 4; mt++)
#pragma unroll
        for (int i = 0; i < 4; i++) {
          int gm = m0 + wr * 64 + mt * 16 + lK * 4 + i;
#pragma unroll
          for (int nt = 0; nt < 4; nt++) {
            int gn = n0 + wc * 64 + nt * 16 + l15;
            uint32_t mine = f2bf(acc[mt][nt][i]);
            uint32_t other = (uint32_t)__shfl_xor((int)mine, 1, 64);
            if (((lane & 1) == 0) && gm < M)
              *(uint32_t*)(dst + (size_t)gm * ldd + (gn - coff)) = mine | (other << 16);
          }
        }
    } else {
      // dt tile: fused softplus + aw (k_dt eliminated)
#pragma unroll
      for (int mt = 0; mt < 4; mt++)
#pragma unroll
        for (int i = 0; i < 4; i++) {
          int gm = m0 + wr * 64 + mt * 16 + lK * 4 + i;
          if (gm >= M) continue;
#pragma unroll
          for (int nt = 0; nt < 4; nt++) {
            int gn = n0 + wc * 64 + nt * 16 + l15;
            if (gn < N) {
              int hd = gn - 1280;
              float v = acc[mt][nt][i] + dt_bias[hd];
              float sp = (v > 20.f) ? v : log1pf(expf(v));
              dtb[(size_t)gm * 8 + hd] = sp;
              awb[(size_t)gm * 8 + hd] = -expf(A_log[hd]) * sp;
            }
          }
        }
    }
  }
}

// ============================================================
// K4: depthwise causal conv + bias + silu.  bf16 in/out, 4 ch/thread.
// ============================================================
__global__ void k_dw(const ushort_t* __restrict__ xbcb, const float* __restrict__ w,
                     const float* __restrict__ bias, ushort_t* __restrict__ xcb) {
  size_t idx = (size_t)blockIdx.x * 256 + threadIdx.x;
  if (idx >= (size_t)M_TOK * 192) return;
  int cq = (int)(idx % 192);
  int c = cq * 4;
  int row = (int)(idx / 192);
  int t = row % L_SEQ;
  int rowb = row - t;                  // b*L_SEQ
  float acc[4] = {bias[c], bias[c + 1], bias[c + 2], bias[c + 3]};
  float wr[4][4];
#pragma unroll
  for (int j = 0; j < 4; j++)
#pragma unroll
    for (int k = 0; k < 4; k++) wr[j][k] = w[(c + j) * 4 + k];
#pragma unroll
  for (int k = 0; k < 4; k++) {
    int tt = t - 3 + k;
    if (tt >= 0) {
      uint2 pk = *(const uint2*)(xbcb + (size_t)(rowb + tt) * CONV_DIM + c);
      acc[0] = fmaf(bf2f((ushort_t)(pk.x & 0xffff)), wr[0][k], acc[0]);
      acc[1] = fmaf(bf2f((ushort_t)(pk.x >> 16)),    wr[1][k], acc[1]);
      acc[2] = fmaf(bf2f((ushort_t)(pk.y & 0xffff)), wr[2][k], acc[2]);
      acc[3] = fmaf(bf2f((ushort_t)(pk.y >> 16)),    wr[3][k], acc[3]);
    }
  }
  float s0 = acc[0] / (1.f + expf(-acc[0]));
  float s1 = acc[1] / (1.f + expf(-acc[1]));
  float s2 = acc[2] / (1.f + expf(-acc[2]));
  float s3 = acc[3] / (1.f + expf(-acc[3]));
  uint2 o;
  o.x = (uint32_t)f2bf(s0) | ((uint32_t)f2bf(s1) << 16);
  o.y = (uint32_t)f2bf(s2) | ((uint32_t)f2bf(s3) << 16);
  *(uint2*)(xcb + (size_t)row * CONV_DIM + c) = o;
}

// ============================================================
// K5a: SSD chunk state summaries -> HS (bf16, packed-pair stores)
// ============================================================
__global__ __launch_bounds__(256) void k_ssd_state(const ushort_t* __restrict__ xcb,
    const float* __restrict__ dtb, const float* __restrict__ aw,
    ushort_t* __restrict__ HSb, float* __restrict__ Pbuf) {
  const int ch = blockIdx.x, bh = blockIdx.y;
  const int b = bh >> 3, h = bh & 7;
  const int t0 = ch * QC;
  const int valid = (L_SEQ - t0 < QC) ? (L_SEQ - t0) : QC;
  const size_t rowbase = (size_t)b * L_SEQ;
  __shared__ __attribute__((aligned(16))) short sBT[128][72];
  __shared__ __attribute__((aligned(16))) short sXw[64][72];
  __shared__ float sW[64];
  __shared__ float sLtot;
  const int tid = threadIdx.x;
  if (tid < 64) {
    float aa = 0.f, dd = 0.f;
    if (tid < valid) { size_t r8 = (rowbase + t0 + tid) * 8 + h; aa = aw[r8]; dd = dtb[r8]; }
    float s = aa;
#pragma unroll
    for (int d = 1; d < 64; d <<= 1) { float o = __shfl_up(s, d, 64); if (tid >= d) s += o; }
    float Lt = __shfl(s, 63, 64);
    sW[tid] = expf(Lt - s) * dd;
    if (tid == 63) sLtot = s;
  }
  __syncthreads();
  for (int i = tid; i < 64 * 16; i += 256) {
    int r = i >> 4, q = (i & 15) * 8;
    short8 v = {0, 0, 0, 0, 0, 0, 0, 0};
    if (r < valid) v = *(const short8*)(xcb + (rowbase + t0 + r) * CONV_DIM + 512 + q);
#pragma unroll
    for (int j = 0; j < 8; j++) sBT[q + j][r] = v[j];
  }
  for (int i = tid; i < 64 * 8; i += 256) {
    int r = i >> 3, q = (i & 7) * 8;
    short8 v = {0, 0, 0, 0, 0, 0, 0, 0};
    if (r < valid) v = *(const short8*)(xcb + (rowbase + t0 + r) * CONV_DIM + h * 64 + q);
    float wv = sW[r];
#pragma unroll
    for (int j = 0; j < 8; j++) sXw[q + j][r] = (short)f2bf(bf2f((ushort_t)v[j]) * wv);
  }
  __syncthreads();
  const int w = tid >> 6, l15 = tid & 15, lK = (tid & 63) >> 4;
  f32x4 acc[2][4] = {};
  short8 afr[2][2];
#pragma unroll
  for (int j = 0; j < 2; j++)
#pragma unroll
    for (int kt = 0; kt < 2; kt++)
      afr[j][kt] = *(const short8*)&sBT[(w * 2 + j) * 16 + l15][kt * 32 + lK * 8];
#pragma unroll
  for (int pt = 0; pt < 4; pt++) {
#pragma unroll
    for (int kt = 0; kt < 2; kt++) {
      short8 bfr = *(const short8*)&sXw[pt * 16 + l15][kt * 32 + lK * 8];
      acc[0][pt] = MFMA16(afr[0][kt], bfr, acc[0][pt]);
      acc[1][pt] = MFMA16(afr[1][kt], bfr, acc[1][pt]);
    }
  }
  ushort_t* dst = HSb + ((size_t)bh * NCH + ch) * 8192;
#pragma unroll
  for (int j = 0; j < 2; j++)
#pragma unroll
    for (int pt = 0; pt < 4; pt++)
#pragma unroll
      for (int i = 0; i < 4; i++) {
        int n = (w * 2 + j) * 16 + lK * 4 + i, p = pt * 16 + l15;
        uint32_t mine = f2bf(acc[j][pt][i]);
        uint32_t other = (uint32_t)__shfl_xor((int)mine, 1, 64);
        if ((l15 & 1) == 0)
          *(uint32_t*)(dst + n * 64 + p) = mine | (other << 16);
      }
  if (tid == 0) Pbuf[bh * NCH + ch] = expf(sLtot);
}

// ============================================================
// K5b: sequential inter-chunk combine (in place, bf16 pairs, fp32 registers)
// ============================================================
__global__ __launch_bounds__(256) void k_ssd_comb(ushort_t* __restrict__ HSb,
                                                  const float* __restrict__ Pbuf) {
  const int bh = blockIdx.y;
  const int e2 = blockIdx.x * 256 + threadIdx.x;   // grid.x=16 -> 4096 pairs
  float run0 = 0.f, run1 = 0.f;
  for (int c = 0; c < NCH; c++) {
    size_t idx = ((size_t)bh * NCH + c) * 8192 + (size_t)e2 * 2;
    uint32_t pk = *(const uint32_t*)(HSb + idx);
    float P = Pbuf[bh * NCH + c];
    run0 = fmaf(P, run0, bf2f((ushort_t)(pk & 0xffff)));
    run1 = fmaf(P, run1, bf2f((ushort_t)(pk >> 16)));
    *(uint32_t*)(HSb + idx) = (uint32_t)f2bf(run0) | ((uint32_t)f2bf(run1) << 16);
  }
}

// ============================================================
// K5c: SSD output -> y bf16 (packed-pair stores)
// ============================================================
__global__ __launch_bounds__(256) void k_ssd_y(const ushort_t* __restrict__ xcb,
    const float* __restrict__ dtb, const float* __restrict__ aw,
    const float* __restrict__ Dskip, const ushort_t* __restrict__ HSb,
    ushort_t* __restrict__ y16) {
  const int ch = blockIdx.x, bh = blockIdx.y;
  const int b = bh >> 3, h = bh & 7;
  const int t0 = ch * QC;
  const int valid = (L_SEQ - t0 < QC) ? (L_SEQ - t0) : QC;
  const size_t rowbase = (size_t)b * L_SEQ;
  __shared__ __attribute__((aligned(16))) short sB[64][136];
  __shared__ __attribute__((aligned(16))) short sC[64][136];
  __shared__ __attribute__((aligned(16))) short sH[64][136];
  __shared__ __attribute__((aligned(16))) short sX[64][72];
  __shared__ float sLrel[64], sdt[64], sEL[64];
  short (*sM)[72] = (short(*)[72])&sB[0][0];
  const int tid = threadIdx.x;
  if (tid < 64) {
    float aa = 0.f, dd = 0.f;
    if (tid < valid) { size_t r8 = (rowbase + t0 + tid) * 8 + h; aa = aw[r8]; dd = dtb[r8]; }
    float s = aa;
#pragma unroll
    for (int d = 1; d < 64; d <<= 1) { float o = __shfl_up(s, d, 64); if (tid >= d) s += o; }
    sLrel[tid] = s; sdt[tid] = dd; sEL[tid] = expf(s);
  }
  for (int i = tid; i < 64 * 16; i += 256) {
    int r = i >> 4, q = (i & 15) * 8;
    short8 vb = {0, 0, 0, 0, 0, 0, 0, 0}, vc = {0, 0, 0, 0, 0, 0, 0, 0};
    if (r < valid) {
      const ushort_t* rp = xcb + (rowbase + t0 + r) * CONV_DIM;
      vb = *(const short8*)(rp + 512 + q);
      vc = *(const short8*)(rp + 640 + q);
    }
#pragma unroll
    for (int j = 0; j < 8; j++) { sB[r][q + j] = vb[j]; sC[r][q + j] = vc[j]; }
  }
  for (int i = tid; i < 64 * 8; i += 256) {
    int r = i >> 3, q = (i & 7) * 8;
    short8 v = {0, 0, 0, 0, 0, 0, 0, 0};
    if (r < valid) v = *(const short8*)(xcb + (rowbase + t0 + r) * CONV_DIM + h * 64 + q);
#pragma unroll
    for (int j = 0; j < 8; j++) sX[q + j][r] = v[j];
  }
  for (int i = tid; i < 128 * 8; i += 256) {
    int n = i >> 3, q = (i & 7) * 8;
    short8 v = {0, 0, 0, 0, 0, 0, 0, 0};
    if (ch > 0) v = *(const short8*)(HSb + ((size_t)bh * NCH + (ch - 1)) * 8192 + n * 64 + q);
#pragma unroll
    for (int j = 0; j < 8; j++) sH[q + j][n] = v[j];
  }
  __syncthreads();
  const int w = tid >> 6, l15 = tid & 15, lK = (tid & 63) >> 4;
  short8 aC[4];
#pragma unroll
  for (int kt = 0; kt < 4; kt++)
    aC[kt] = *(const short8*)&sC[w * 16 + l15][kt * 32 + lK * 8];
  f32x4 g[4] = {};
#pragma unroll
  for (int st = 0; st < 4; st++)
#pragma unroll
    for (int kt = 0; kt < 4; kt++)
      g[st] = MFMA16(aC[kt], *(const short8*)&sB[st * 16 + l15][kt * 32 + lK * 8], g[st]);
  __syncthreads();
#pragma unroll
  for (int st = 0; st < 4; st++)
#pragma unroll
    for (int i = 0; i < 4; i++) {
      int tt = w * 16 + lK * 4 + i, ss = st * 16 + l15;
      float f = (ss <= tt) ? expf(sLrel[tt] - sLrel[ss]) * sdt[ss] : 0.f;
      sM[tt][ss] = (short)f2bf(g[st][i] * f);
    }
  __syncthreads();
  f32x4 acc[4] = {};
#pragma unroll
  for (int pt = 0; pt < 4; pt++)
#pragma unroll
    for (int kt = 0; kt < 4; kt++)
      acc[pt] = MFMA16(aC[kt], *(const short8*)&sH[pt * 16 + l15][kt * 32 + lK * 8], acc[pt]);
#pragma unroll
  for (int pt = 0; pt < 4; pt++)
#pragma unroll
    for (int i = 0; i < 4; i++)
      acc[pt][i] *= sEL[w * 16 + lK * 4 + i];
  short8 aM[2];
#pragma unroll
  for (int kt = 0; kt < 2; kt++)
    aM[kt] = *(const short8*)&sM[w * 16 + l15][kt * 32 + lK * 8];
#pragma unroll
  for (int pt = 0; pt < 4; pt++)
#pragma unroll
    for (int kt = 0; kt < 2; kt++)
      acc[pt] = MFMA16(aM[kt], *(const short8*)&sX[pt * 16 + l15][kt * 32 + lK * 8], acc[pt]);
  const float Dsk = Dskip[h];
#pragma unroll
  for (int pt = 0; pt < 4; pt++)
#pragma unroll
    for (int i = 0; i < 4; i++) {
      int tt = w * 16 + lK * 4 + i;
      int pp = pt * 16 + l15;
      float v = acc[pt][i] + Dsk * bf2f((ushort_t)sX[pp][tt]);
      uint32_t mine = f2bf(v);
      uint32_t other = (uint32_t)__shfl_xor((int)mine, 1, 64);
      if (((l15 & 1) == 0) && tt < valid)
        *(uint32_t*)(y16 + (rowbase + t0 + tt) * D_INNER + h * 64 + pp) = mine | (other << 16);
    }
}

// ============================================================
// K6: gate + RMSNorm; bf16 in/out (in place), packed 4B stores
// ============================================================
__global__ __launch_bounds__(512) void k_norm(ushort_t* __restrict__ y16,
    const ushort_t* __restrict__ zb, const float* __restrict__ norm_w) {
  const int row = blockIdx.x;
  const int c = threadIdx.x;
  float z = bf2f(zb[(size_t)row * 512 + c]);
  float g = z / (1.f + expf(-z));
  float v = bf2f(y16[(size_t)row * D_INNER + c]) * g;
  float ss = v * v;
#pragma unroll
  for (int m = 32; m >= 1; m >>= 1) ss += __shfl_xor(ss, m, 64);
  __shared__ float red[8];
  if ((threadIdx.x & 63) == 0) red[threadIdx.x >> 6] = ss;
  __syncthreads();
  float tot = 0.f;
#pragma unroll
  for (int i = 0; i < 8; i++) tot += red[i];
  float scale = rsqrtf(tot * (1.f / 512.f) + 1e-5f);
  uint32_t mine = f2bf(v * scale * norm_w[c]);
  uint32_t other = (uint32_t)__shfl_xor((int)mine, 1, 64);
  if ((c & 1) == 0)
    *(uint32_t*)(y16 + (size_t)row * D_INNER + c) = mine | (other << 16);
}

// ============================================================
// K8: diagonal gather-reduce: yc1[b][j][t] = b1[j] + sum_k Y[b,t-7+k][j*16+k]
// ============================================================
__global__ void k_red(const float* __restrict__ Y, const float* __restrict__ b1,
                      float* __restrict__ yc1) {
  int idx = blockIdx.x * 256 + threadIdx.x;
  if (idx >= BATCH * 8 * L_SEQ) return;
  int t = idx % L_SEQ;
  int bj = idx / L_SEQ;
  int j = bj & 7, b = bj >> 3;
  float acc = b1[j];
  const float* Yb = Y + (size_t)b * L_SEQ * 128;
#pragma unroll
  for (int k = 0; k < 16; k++) {
    int tt = t - 7 + k;
    if (tt >= 0 && tt < L_SEQ) acc += Yb[(size_t)tt * 128 + j * 16 + k];
  }
  yc1[idx] = acc;
}

// ============================================================
// K9: transposed conv (8->4ch, K=16, lhs_dilation=8, pad 15/15)
// ============================================================
__global__ void k_convT(const float* __restrict__ yc1,
                        const float* __restrict__ wT,
                        const float* __restrict__ bT, float* __restrict__ out) {
  const int s = blockIdx.x * 256 + threadIdx.x;
  const int c = blockIdx.y, b = blockIdx.z;
  float acc = bT[c];
  const int k0 = (15 - (s & 7)) & 7;
#pragma unroll
  for (int dk = 0; dk < 2; dk++) {
    int k = k0 + 8 * dk;
    int num = s - 15 + k;
    int m = num >> 3;
    if (num >= 0 && m < L_SEQ) {
#pragma unroll
      for (int j = 0; j < 8; j++) {
        float v = yc1[((size_t)b * 8 + j) * L_SEQ + m];
        acc = fmaf(v, wT[((size_t)j * 4 + c) * 16 + (15 - k)], acc);
      }
    }
  }
  out[((size_t)b * 4 + c) * L_IN + s] = acc;
}

// ============================================================
extern "C" void kernel_launch(void* const* d_in, const int* in_sizes, int n_in,
                              void* d_out, int out_size, void* d_ws, size_t ws_size,
                              hipStream_t stream) {
  const float* x         = (const float*)d_in[0];
  const float* conv_w    = (const float*)d_in[1];
  const float* conv_b    = (const float*)d_in[2];
  const float* in_proj_w = (const float*)d_in[3];
  const float* conv1d_w  = (const float*)d_in[4];
  const float* conv1d_b  = (const float*)d_in[5];
  const float* dt_bias   = (const float*)d_in[6];
  const float* A_log     = (const float*)d_in[7];
  const float* D_skip    = (const float*)d_in[8];
  const float* norm_w    = (const float*)d_in[9];
  const float* out_proj_w= (const float*)d_in[10];
  const float* conv1_w   = (const float*)d_in[11];
  const float* conv1_b   = (const float*)d_in[12];
  const float* convT_w   = (const float*)d_in[13];
  const float* convT_b   = (const float*)d_in[14];
  float* out = (float*)d_out;
  float* ws  = (float*)d_ws;

  ushort_t* ub   = (ushort_t*)(ws + OFF_U);
  ushort_t* PB   = (ushort_t*)(ws + OFF_PB);
  ushort_t* zb   = (ushort_t*)(ws + OFF_ZB);
  ushort_t* xbcb = (ushort_t*)(ws + OFF_XBC);
  float* dtb  = ws + OFF_DT;
  float* awb  = ws + OFF_AW;
  ushort_t* xcb = (ushort_t*)(ws + OFF_XC);
  ushort_t* y16 = (ushort_t*)(ws + OFF_Y);
  float* yc1  = ws + OFF_YC1;
  float* Pbuf = ws + OFF_PBUF;
  ushort_t* HSb = (ushort_t*)(ws + OFF_HS);
  ushort_t* wbin  = (ushort_t*)(ws + OFF_WBIN);
  ushort_t* wbf   = (ushort_t*)(ws + OFF_WBF);
  ushort_t* W2b   = (ushort_t*)(ws + OFF_W2);
  float* Yg   = ws + OFF_U;   // U region dead after in_proj GEMM

  // 0. weight casts + combined out_proj*conv1 weight
  k_cast<<<dim3((D_IN_PROJ * 256 + 255) / 256), 256, 0, stream>>>(
      in_proj_w, conv_w, wbin, wbf);
  k_wcomb<<<dim3(128), 256, 0, stream>>>(conv1_w, out_proj_w, W2b);
  // 1. front conv as im2col + MFMA GEMM
  k_im2col<<<dim3((M_TOK * 8 + 255) / 256), 256, 0, stream>>>(x, PB);
  gemm_bf16<1><<<dim3(2, 128), 256, 0, stream>>>(PB, 64, wbf, 64, (float*)ub,
      conv_b, M_TOK, 256, 64, nullptr, nullptr, nullptr, nullptr, nullptr, nullptr);
  // 2. in_proj GEMM with region-split epilogue (z->zb, xBC->xbcb, dt fused)
  gemm_bf16<2><<<dim3(11, 128), 256, 0, stream>>>(ub, 256, wbin, 256, nullptr,
      nullptr, M_TOK, D_IN_PROJ, 256, zb, xbcb, dtb, awb, dt_bias, A_log);
  // 4. depthwise conv + silu -> xc (bf16 in/out)
  k_dw<<<dim3((int)(((size_t)M_TOK * 192 + 255) / 256)), 256, 0, stream>>>(
      xbcb, conv1d_w, conv1d_b, xcb);
  // 5. SSD scan (MFMA, bf16 states)
  k_ssd_state<<<dim3(NCH, 64), 256, 0, stream>>>(xcb, dtb, awb, HSb, Pbuf);
  k_ssd_comb<<<dim3(16, 64), 256, 0, stream>>>(HSb, Pbuf);
  k_ssd_y<<<dim3(NCH, 64), 256, 0, stream>>>(xcb, dtb, awb, D_skip, HSb, y16);
  // 6. gate + RMSNorm (bf16 in place)
  k_norm<<<dim3(M_TOK), 512, 0, stream>>>(y16, zb, norm_w);
  // 7. combined out_proj+conv1 GEMM: Y = ynorm @ W2^T  (M=16376,N=128,K=512)
  gemm_bf16<0><<<dim3(1, 128), 256, 0, stream>>>(y16, 512, W2b, 512, Yg,
      nullptr, M_TOK, 128, D_INNER, nullptr, nullptr, nullptr, nullptr, nullptr, nullptr);
  // 8. diagonal gather-reduce -> yc1 (b1 folded)
  k_red<<<dim3((BATCH * 8 * L_SEQ + 255) / 256), 256, 0, stream>>>(Yg, conv1_b, yc1);
  // 9. transposed conv -> out
  k_convT<<<dim3(64, 4, 8), 256, 0, stream>>>(yc1, convT_w, convT_b, out);
}

// Round 9
// 219.591 us; speedup vs baseline: 4.7902x; 1.1984x over previous
//
#include <hip/hip_runtime.h>
#include <cstddef>
#include <cstdint>

// ---------------- problem constants ----------------
constexpr int L_IN   = 16384;
constexpr int L_SEQ  = 2047;          // (16384-16)/8 + 1
constexpr int BATCH  = 8;
constexpr int M_TOK  = BATCH * L_SEQ; // 16376
constexpr int D_INNER = 512;
constexpr int NHEADS  = 8;
constexpr int HEADDIM = 64;
constexpr int D_STATE = 128;
constexpr int CONV_DIM = 768;
constexpr int D_IN_PROJ = 1288;

// SSD chunking
constexpr int QC  = 64;
constexpr int NCH = 32;

// ---------------- workspace layout (float slots) ----------------
constexpr size_t OFF_U    = 0;                       // ub bf16 (2,096,128) / later Yg fp32
constexpr size_t OFF_PB   = OFF_U   + 2096128;       // im2col bf16 (524,032)
constexpr size_t OFF_ZB   = OFF_U   + 4192256;       // z bf16 [row][512] = 4,192,256
constexpr size_t OFF_XBC  = OFF_ZB  + 4192256;       // xBC bf16 [row][768] = 6,288,384
constexpr size_t OFF_DT   = OFF_XBC + 6288384;       // dt fp32 [row][8] = 131,008
constexpr size_t OFF_AW   = OFF_DT  + 131008;        // aw fp32 = 131,008
constexpr size_t OFF_XC   = OFF_AW  + 131008;        // xc bf16 [row][768] = 6,288,384
constexpr size_t OFF_Y    = OFF_XC  + 6288384;       // y bf16 [row][512] = 4,192,256
constexpr size_t OFF_YC1  = OFF_Y   + 4192256;       // yc1 fp32 = 131,008
constexpr size_t OFF_PBUF = OFF_YC1 + 131008;        // Pbuf fp32 = 2,048
constexpr size_t OFF_HS   = OFF_PBUF + 2048;         // HS bf16 = 8,388,608
constexpr size_t OFF_WBIN = OFF_HS  + 8388608;       // 164,864
constexpr size_t OFF_WBF  = OFF_WBIN + 164864;       // 8,192
constexpr size_t OFF_W2   = OFF_WBF + 8192;          // 32,768
// total ~= 136.6 MB

using short8 = __attribute__((ext_vector_type(8))) short;  // 8 bf16
using f32x4  = __attribute__((ext_vector_type(4))) float;
typedef unsigned short ushort_t;

__device__ __forceinline__ ushort_t f2bf(float f) {        // RNE f32->bf16
  uint32_t u = __float_as_uint(f);
  u += 0x7fffu + ((u >> 16) & 1u);
  return (ushort_t)(u >> 16);
}
__device__ __forceinline__ float bf2f(ushort_t h) {
  return __uint_as_float(((uint32_t)h) << 16);
}
#define MFMA16(a, b, c) __builtin_amdgcn_mfma_f32_16x16x32_bf16(a, b, c, 0, 0, 0)

// ============================================================
// K_prep: merged {im2col | weight casts | W2 combine} by blockIdx range.
//   blocks [0,512):    im2col  (idx = bid*256+tid < M_TOK*8)
//   blocks [512,1800):  cast in_proj + front-conv weights
//   blocks [1800,1928): W2[r][d] = sum_ic conv1_w[oc][ic][k]*wout[ic][d], r=oc*16+k
// ============================================================
__global__ __launch_bounds__(256) void k_prep(const float* __restrict__ x,
    const float* __restrict__ w1, const float* __restrict__ w3,
    const float* __restrict__ conv1_w, const float* __restrict__ wout,
    ushort_t* __restrict__ PB, ushort_t* __restrict__ o1, ushort_t* __restrict__ o3,
    ushort_t* __restrict__ W2b) {
  const int bid = blockIdx.x;
  const int tid = threadIdx.x;
  if (bid < 512) {
    int idx = bid * 256 + tid;
    if (idx >= M_TOK * 8) return;
    int oct = idx & 7, row = idx >> 3;
    int t = row % L_SEQ, b = row / L_SEQ;
    int ic = oct >> 1, k0 = (oct & 1) * 8;
    const float* src = x + ((size_t)b * 4 + ic) * L_IN + t * 8 + k0;
    float4 a0 = *(const float4*)src;
    float4 a1 = *(const float4*)(src + 4);
    short8 o;
    o[0] = (short)f2bf(a0.x); o[1] = (short)f2bf(a0.y);
    o[2] = (short)f2bf(a0.z); o[3] = (short)f2bf(a0.w);
    o[4] = (short)f2bf(a1.x); o[5] = (short)f2bf(a1.y);
    o[6] = (short)f2bf(a1.z); o[7] = (short)f2bf(a1.w);
    *(short8*)(PB + (size_t)row * 64 + oct * 8) = o;
  } else if (bid < 1800) {
    int i = (bid - 512) * 256 + tid;
    if (i < D_IN_PROJ * 256) o1[i] = f2bf(w1[i]);
    if (i < 256 * 64)        o3[i] = f2bf(w3[i]);
  } else {
    const int r = bid - 1800;          // 0..127
    const int oc = r >> 4, k = r & 15;
    const int d0 = tid;
    float acc0 = 0.f, acc1 = 0.f;
    for (int o = 0; o < 256; o++) {
      float wv = conv1_w[((size_t)oc * 256 + o) * 16 + k];
      acc0 = fmaf(wv, wout[(size_t)o * 512 + d0], acc0);
      acc1 = fmaf(wv, wout[(size_t)o * 512 + d0 + 256], acc1);
    }
    W2b[(size_t)r * 512 + d0]       = f2bf(acc0);
    W2b[(size_t)r * 512 + d0 + 256] = f2bf(acc1);
  }
}

// ============================================================
// K2: bf16 MFMA GEMM NT.  128x128 tile, BK=64, 4 waves, LDS XOR swizzle.
// EPI=0: fp32 store.  EPI=1: +bias, relu, bf16 packed store.
// EPI=2: in_proj region-split epilogue (z->zb, xBC->xbcb, dt fused).
// ============================================================
template<int EPI>
__global__ __launch_bounds__(256) void gemm_bf16(const ushort_t* __restrict__ A, int lda,
    const ushort_t* __restrict__ B, int ldb, float* __restrict__ C,
    const float* __restrict__ bias, int M, int N, int K,
    ushort_t* __restrict__ zb, ushort_t* __restrict__ xbcb,
    float* __restrict__ dtb, float* __restrict__ awb,
    const float* __restrict__ dt_bias, const float* __restrict__ A_log) {
  __shared__ __attribute__((aligned(16))) ushort_t sA[128 * 64];
  __shared__ __attribute__((aligned(16))) ushort_t sB[128 * 64];
  const int tid = threadIdx.x;
  const int m0 = blockIdx.y * 128, n0 = blockIdx.x * 128;
  const int w = tid >> 6, lane = tid & 63;
  const int l15 = lane & 15, lK = lane >> 4;
  const int wr = w >> 1, wc = w & 1;
  f32x4 acc[4][4] = {};
  for (int k0 = 0; k0 < K; k0 += 64) {
    __syncthreads();
#pragma unroll
    for (int j = 0; j < 4; j++) {
      int idx = j * 256 + tid;
      int r = idx >> 3, s = idx & 7;
      short8 va = {0, 0, 0, 0, 0, 0, 0, 0};
      int gm = m0 + r;
      if (gm < M) va = *(const short8*)(A + (size_t)gm * lda + k0 + s * 8);
      *(short8*)&sA[r * 64 + ((s ^ (r & 7)) * 8)] = va;
      short8 vb = {0, 0, 0, 0, 0, 0, 0, 0};
      int gn = n0 + r;
      if (gn < N) vb = *(const short8*)(B + (size_t)gn * ldb + k0 + s * 8);
      *(short8*)&sB[r * 64 + ((s ^ (r & 7)) * 8)] = vb;
    }
    __syncthreads();
#pragma unroll
    for (int kk = 0; kk < 2; kk++) {
      short8 af[4], bf[4];
#pragma unroll
      for (int mt = 0; mt < 4; mt++) {
        int r = wr * 64 + mt * 16 + l15;
        af[mt] = *(const short8*)&sA[r * 64 + (((kk * 4 + lK) ^ (r & 7)) * 8)];
      }
#pragma unroll
      for (int nt = 0; nt < 4; nt++) {
        int r = wc * 64 + nt * 16 + l15;
        bf[nt] = *(const short8*)&sB[r * 64 + (((kk * 4 + lK) ^ (r & 7)) * 8)];
      }
#pragma unroll
      for (int mt = 0; mt < 4; mt++)
#pragma unroll
        for (int nt = 0; nt < 4; nt++)
          acc[mt][nt] = MFMA16(af[mt], bf[nt], acc[mt][nt]);
    }
  }
  if constexpr (EPI == 0) {
#pragma unroll
    for (int mt = 0; mt < 4; mt++)
#pragma unroll
      for (int i = 0; i < 4; i++) {
        int gm = m0 + wr * 64 + mt * 16 + lK * 4 + i;
        if (gm < M) {
          float* crow = C + (size_t)gm * N;
#pragma unroll
          for (int nt = 0; nt < 4; nt++) {
            int gn = n0 + wc * 64 + nt * 16 + l15;
            if (gn < N) crow[gn] = acc[mt][nt][i];
          }
        }
      }
  } else if constexpr (EPI == 1) {
    ushort_t* Cb = (ushort_t*)C;
#pragma unroll
    for (int mt = 0; mt < 4; mt++)
#pragma unroll
      for (int i = 0; i < 4; i++) {
        int gm = m0 + wr * 64 + mt * 16 + lK * 4 + i;
#pragma unroll
        for (int nt = 0; nt < 4; nt++) {
          int gn = n0 + wc * 64 + nt * 16 + l15;
          float v = fmaxf(acc[mt][nt][i] + bias[gn], 0.f);
          uint32_t mine = f2bf(v);
          uint32_t other = (uint32_t)__shfl_xor((int)mine, 1, 64);
          if (((lane & 1) == 0) && gm < M)
            *(uint32_t*)(Cb + (size_t)gm * N + gn) = mine | (other << 16);
        }
      }
  } else {
    if (n0 < 1280) {
      ushort_t* dst = (n0 < 512) ? zb : xbcb;
      const int ldd  = (n0 < 512) ? 512 : 768;
      const int coff = (n0 < 512) ? 0 : 512;
#pragma unroll
      for (int mt = 0; mt < 4; mt++)
#pragma unroll
        for (int i = 0; i < 4; i++) {
          int gm = m0 + wr * 64 + mt * 16 + lK * 4 + i;
#pragma unroll
          for (int nt = 0; nt < 4; nt++) {
            int gn = n0 + wc * 64 + nt * 16 + l15;
            uint32_t mine = f2bf(acc[mt][nt][i]);
            uint32_t other = (uint32_t)__shfl_xor((int)mine, 1, 64);
            if (((lane & 1) == 0) && gm < M)
              *(uint32_t*)(dst + (size_t)gm * ldd + (gn - coff)) = mine | (other << 16);
          }
        }
    } else {
      // dt tile: fused softplus + aw (k_dt eliminated)
#pragma unroll
      for (int mt = 0; mt < 4; mt++)
#pragma unroll
        for (int i = 0; i < 4; i++) {
          int gm = m0 + wr * 64 + mt * 16 + lK * 4 + i;
          if (gm >= M) continue;
#pragma unroll
          for (int nt = 0; nt < 4; nt++) {
            int gn = n0 + wc * 64 + nt * 16 + l15;
            if (gn < N) {
              int hd = gn - 1280;
              float v = acc[mt][nt][i] + dt_bias[hd];
              float sp = (v > 20.f) ? v : log1pf(expf(v));
              dtb[(size_t)gm * 8 + hd] = sp;
              awb[(size_t)gm * 8 + hd] = -expf(A_log[hd]) * sp;
            }
          }
        }
    }
  }
}

// ============================================================
// K4: depthwise causal conv + bias + silu, t-blocked sliding window.
//     Block = (b, t-block of 4 rows), 192 threads (one 4-ch quad each).
//     7 row-loads -> 4 outputs: tap reuse is in-register, XCD-immune.
// ============================================================
__global__ __launch_bounds__(192) void k_dw(const ushort_t* __restrict__ xbcb,
    const float* __restrict__ w, const float* __restrict__ bias,
    ushort_t* __restrict__ xcb) {
  const int bid = blockIdx.x;          // b*512 + tb
  const int tb = bid & 511, b = bid >> 9;
  const int t0 = tb * 4;
  const int c = threadIdx.x * 4;
  const size_t rowb = (size_t)b * L_SEQ;
  float wr[4][4];
#pragma unroll
  for (int j = 0; j < 4; j++)
#pragma unroll
    for (int k = 0; k < 4; k++) wr[j][k] = w[(c + j) * 4 + k];
  const float4 bs = {bias[c], bias[c + 1], bias[c + 2], bias[c + 3]};
  float v[7][4];
#pragma unroll
  for (int r = 0; r < 7; r++) {
    int tt = t0 - 3 + r;
    if (tt >= 0 && tt < L_SEQ) {
      uint2 pk = *(const uint2*)(xbcb + (rowb + tt) * CONV_DIM + c);
      v[r][0] = bf2f((ushort_t)(pk.x & 0xffff));
      v[r][1] = bf2f((ushort_t)(pk.x >> 16));
      v[r][2] = bf2f((ushort_t)(pk.y & 0xffff));
      v[r][3] = bf2f((ushort_t)(pk.y >> 16));
    } else {
      v[r][0] = v[r][1] = v[r][2] = v[r][3] = 0.f;
    }
  }
#pragma unroll
  for (int o = 0; o < 4; o++) {
    int t = t0 + o;
    if (t >= L_SEQ) break;
    float a0 = bs.x, a1 = bs.y, a2 = bs.z, a3 = bs.w;
#pragma unroll
    for (int k = 0; k < 4; k++) {
      a0 = fmaf(v[o + k][0], wr[0][k], a0);
      a1 = fmaf(v[o + k][1], wr[1][k], a1);
      a2 = fmaf(v[o + k][2], wr[2][k], a2);
      a3 = fmaf(v[o + k][3], wr[3][k], a3);
    }
    float s0 = a0 / (1.f + expf(-a0));
    float s1 = a1 / (1.f + expf(-a1));
    float s2 = a2 / (1.f + expf(-a2));
    float s3 = a3 / (1.f + expf(-a3));
    uint2 ov;
    ov.x = (uint32_t)f2bf(s0) | ((uint32_t)f2bf(s1) << 16);
    ov.y = (uint32_t)f2bf(s2) | ((uint32_t)f2bf(s3) << 16);
    *(uint2*)(xcb + (rowb + t) * CONV_DIM + c) = ov;
  }
}

// ============================================================
// K5a: SSD chunk state summaries -> HS (bf16, packed-pair stores)
// ============================================================
__global__ __launch_bounds__(256) void k_ssd_state(const ushort_t* __restrict__ xcb,
    const float* __restrict__ dtb, const float* __restrict__ aw,
    ushort_t* __restrict__ HSb, float* __restrict__ Pbuf) {
  const int ch = blockIdx.x, bh = blockIdx.y;
  const int b = bh >> 3, h = bh & 7;
  const int t0 = ch * QC;
  const int valid = (L_SEQ - t0 < QC) ? (L_SEQ - t0) : QC;
  const size_t rowbase = (size_t)b * L_SEQ;
  __shared__ __attribute__((aligned(16))) short sBT[128][72];
  __shared__ __attribute__((aligned(16))) short sXw[64][72];
  __shared__ float sW[64];
  __shared__ float sLtot;
  const int tid = threadIdx.x;
  if (tid < 64) {
    float aa = 0.f, dd = 0.f;
    if (tid < valid) { size_t r8 = (rowbase + t0 + tid) * 8 + h; aa = aw[r8]; dd = dtb[r8]; }
    float s = aa;
#pragma unroll
    for (int d = 1; d < 64; d <<= 1) { float o = __shfl_up(s, d, 64); if (tid >= d) s += o; }
    float Lt = __shfl(s, 63, 64);
    sW[tid] = expf(Lt - s) * dd;
    if (tid == 63) sLtot = s;
  }
  __syncthreads();
  for (int i = tid; i < 64 * 16; i += 256) {
    int r = i >> 4, q = (i & 15) * 8;
    short8 v = {0, 0, 0, 0, 0, 0, 0, 0};
    if (r < valid) v = *(const short8*)(xcb + (rowbase + t0 + r) * CONV_DIM + 512 + q);
#pragma unroll
    for (int j = 0; j < 8; j++) sBT[q + j][r] = v[j];
  }
  for (int i = tid; i < 64 * 8; i += 256) {
    int r = i >> 3, q = (i & 7) * 8;
    short8 v = {0, 0, 0, 0, 0, 0, 0, 0};
    if (r < valid) v = *(const short8*)(xcb + (rowbase + t0 + r) * CONV_DIM + h * 64 + q);
    float wv = sW[r];
#pragma unroll
    for (int j = 0; j < 8; j++) sXw[q + j][r] = (short)f2bf(bf2f((ushort_t)v[j]) * wv);
  }
  __syncthreads();
  const int w = tid >> 6, l15 = tid & 15, lK = (tid & 63) >> 4;
  f32x4 acc[2][4] = {};
  short8 afr[2][2];
#pragma unroll
  for (int j = 0; j < 2; j++)
#pragma unroll
    for (int kt = 0; kt < 2; kt++)
      afr[j][kt] = *(const short8*)&sBT[(w * 2 + j) * 16 + l15][kt * 32 + lK * 8];
#pragma unroll
  for (int pt = 0; pt < 4; pt++) {
#pragma unroll
    for (int kt = 0; kt < 2; kt++) {
      short8 bfr = *(const short8*)&sXw[pt * 16 + l15][kt * 32 + lK * 8];
      acc[0][pt] = MFMA16(afr[0][kt], bfr, acc[0][pt]);
      acc[1][pt] = MFMA16(afr[1][kt], bfr, acc[1][pt]);
    }
  }
  ushort_t* dst = HSb + ((size_t)bh * NCH + ch) * 8192;
#pragma unroll
  for (int j = 0; j < 2; j++)
#pragma unroll
    for (int pt = 0; pt < 4; pt++)
#pragma unroll
      for (int i = 0; i < 4; i++) {
        int n = (w * 2 + j) * 16 + lK * 4 + i, p = pt * 16 + l15;
        uint32_t mine = f2bf(acc[j][pt][i]);
        uint32_t other = (uint32_t)__shfl_xor((int)mine, 1, 64);
        if ((l15 & 1) == 0)
          *(uint32_t*)(dst + n * 64 + p) = mine | (other << 16);
      }
  if (tid == 0) Pbuf[bh * NCH + ch] = expf(sLtot);
}

// ============================================================
// K5b: sequential inter-chunk combine (in place, bf16 pairs, fp32 registers)
// ============================================================
__global__ __launch_bounds__(256) void k_ssd_comb(ushort_t* __restrict__ HSb,
                                                  const float* __restrict__ Pbuf) {
  const int bh = blockIdx.y;
  const int e2 = blockIdx.x * 256 + threadIdx.x;   // grid.x=16 -> 4096 pairs
  float run0 = 0.f, run1 = 0.f;
  for (int c = 0; c < NCH; c++) {
    size_t idx = ((size_t)bh * NCH + c) * 8192 + (size_t)e2 * 2;
    uint32_t pk = *(const uint32_t*)(HSb + idx);
    float P = Pbuf[bh * NCH + c];
    run0 = fmaf(P, run0, bf2f((ushort_t)(pk & 0xffff)));
    run1 = fmaf(P, run1, bf2f((ushort_t)(pk >> 16)));
    *(uint32_t*)(HSb + idx) = (uint32_t)f2bf(run0) | ((uint32_t)f2bf(run1) << 16);
  }
}

// ============================================================
// K5c: SSD output -> y bf16 (packed-pair stores)
// ============================================================
__global__ __launch_bounds__(256) void k_ssd_y(const ushort_t* __restrict__ xcb,
    const float* __restrict__ dtb, const float* __restrict__ aw,
    const float* __restrict__ Dskip, const ushort_t* __restrict__ HSb,
    ushort_t* __restrict__ y16) {
  const int ch = blockIdx.x, bh = blockIdx.y;
  const int b = bh >> 3, h = bh & 7;
  const int t0 = ch * QC;
  const int valid = (L_SEQ - t0 < QC) ? (L_SEQ - t0) : QC;
  const size_t rowbase = (size_t)b * L_SEQ;
  __shared__ __attribute__((aligned(16))) short sB[64][136];
  __shared__ __attribute__((aligned(16))) short sC[64][136];
  __shared__ __attribute__((aligned(16))) short sH[64][136];
  __shared__ __attribute__((aligned(16))) short sX[64][72];
  __shared__ float sLrel[64], sdt[64], sEL[64];
  short (*sM)[72] = (short(*)[72])&sB[0][0];
  const int tid = threadIdx.x;
  if (tid < 64) {
    float aa = 0.f, dd = 0.f;
    if (tid < valid) { size_t r8 = (rowbase + t0 + tid) * 8 + h; aa = aw[r8]; dd = dtb[r8]; }
    float s = aa;
#pragma unroll
    for (int d = 1; d < 64; d <<= 1) { float o = __shfl_up(s, d, 64); if (tid >= d) s += o; }
    sLrel[tid] = s; sdt[tid] = dd; sEL[tid] = expf(s);
  }
  for (int i = tid; i < 64 * 16; i += 256) {
    int r = i >> 4, q = (i & 15) * 8;
    short8 vb = {0, 0, 0, 0, 0, 0, 0, 0}, vc = {0, 0, 0, 0, 0, 0, 0, 0};
    if (r < valid) {
      const ushort_t* rp = xcb + (rowbase + t0 + r) * CONV_DIM;
      vb = *(const short8*)(rp + 512 + q);
      vc = *(const short8*)(rp + 640 + q);
    }
#pragma unroll
    for (int j = 0; j < 8; j++) { sB[r][q + j] = vb[j]; sC[r][q + j] = vc[j]; }
  }
  for (int i = tid; i < 64 * 8; i += 256) {
    int r = i >> 3, q = (i & 7) * 8;
    short8 v = {0, 0, 0, 0, 0, 0, 0, 0};
    if (r < valid) v = *(const short8*)(xcb + (rowbase + t0 + r) * CONV_DIM + h * 64 + q);
#pragma unroll
    for (int j = 0; j < 8; j++) sX[q + j][r] = v[j];
  }
  for (int i = tid; i < 128 * 8; i += 256) {
    int n = i >> 3, q = (i & 7) * 8;
    short8 v = {0, 0, 0, 0, 0, 0, 0, 0};
    if (ch > 0) v = *(const short8*)(HSb + ((size_t)bh * NCH + (ch - 1)) * 8192 + n * 64 + q);
#pragma unroll
    for (int j = 0; j < 8; j++) sH[q + j][n] = v[j];
  }
  __syncthreads();
  const int w = tid >> 6, l15 = tid & 15, lK = (tid & 63) >> 4;
  short8 aC[4];
#pragma unroll
  for (int kt = 0; kt < 4; kt++)
    aC[kt] = *(const short8*)&sC[w * 16 + l15][kt * 32 + lK * 8];
  f32x4 g[4] = {};
#pragma unroll
  for (int st = 0; st < 4; st++)
#pragma unroll
    for (int kt = 0; kt < 4; kt++)
      g[st] = MFMA16(aC[kt], *(const short8*)&sB[st * 16 + l15][kt * 32 + lK * 8], g[st]);
  __syncthreads();
#pragma unroll
  for (int st = 0; st < 4; st++)
#pragma unroll
    for (int i = 0; i < 4; i++) {
      int tt = w * 16 + lK * 4 + i, ss = st * 16 + l15;
      float f = (ss <= tt) ? expf(sLrel[tt] - sLrel[ss]) * sdt[ss] : 0.f;
      sM[tt][ss] = (short)f2bf(g[st][i] * f);
    }
  __syncthreads();
  f32x4 acc[4] = {};
#pragma unroll
  for (int pt = 0; pt < 4; pt++)
#pragma unroll
    for (int kt = 0; kt < 4; kt++)
      acc[pt] = MFMA16(aC[kt], *(const short8*)&sH[pt * 16 + l15][kt * 32 + lK * 8], acc[pt]);
#pragma unroll
  for (int pt = 0; pt < 4; pt++)
#pragma unroll
    for (int i = 0; i < 4; i++)
      acc[pt][i] *= sEL[w * 16 + lK * 4 + i];
  short8 aM[2];
#pragma unroll
  for (int kt = 0; kt < 2; kt++)
    aM[kt] = *(const short8*)&sM[w * 16 + l15][kt * 32 + lK * 8];
#pragma unroll
  for (int pt = 0; pt < 4; pt++)
#pragma unroll
    for (int kt = 0; kt < 2; kt++)
      acc[pt] = MFMA16(aM[kt], *(const short8*)&sX[pt * 16 + l15][kt * 32 + lK * 8], acc[pt]);
  const float Dsk = Dskip[h];
#pragma unroll
  for (int pt = 0; pt < 4; pt++)
#pragma unroll
    for (int i = 0; i < 4; i++) {
      int tt = w * 16 + lK * 4 + i;
      int pp = pt * 16 + l15;
      float v = acc[pt][i] + Dsk * bf2f((ushort_t)sX[pp][tt]);
      uint32_t mine = f2bf(v);
      uint32_t other = (uint32_t)__shfl_xor((int)mine, 1, 64);
      if (((l15 & 1) == 0) && tt < valid)
        *(uint32_t*)(y16 + (rowbase + t0 + tt) * D_INNER + h * 64 + pp) = mine | (other << 16);
    }
}

// ============================================================
// K6: gate + RMSNorm, wave-per-row (64 lanes x 8 ch), short8 16B I/O
// ============================================================
__global__ __launch_bounds__(256) void k_norm(ushort_t* __restrict__ y16,
    const ushort_t* __restrict__ zb, const float* __restrict__ norm_w) {
  const int row = blockIdx.x * 4 + (threadIdx.x >> 6);
  const int lane = threadIdx.x & 63;
  const int c0 = lane * 8;
  ushort_t* yrow = y16 + (size_t)row * D_INNER;
  short8 yv = *(const short8*)(yrow + c0);
  short8 zv = *(const short8*)(zb + (size_t)row * 512 + c0);
  float v[8];
  float ss = 0.f;
#pragma unroll
  for (int j = 0; j < 8; j++) {
    float z = bf2f((ushort_t)zv[j]);
    float g = z / (1.f + expf(-z));
    v[j] = bf2f((ushort_t)yv[j]) * g;
    ss += v[j] * v[j];
  }
#pragma unroll
  for (int m = 32; m >= 1; m >>= 1) ss += __shfl_xor(ss, m, 64);
  float scale = rsqrtf(ss * (1.f / 512.f) + 1e-5f);
  float4 nw0 = *(const float4*)(norm_w + c0);
  float4 nw1 = *(const float4*)(norm_w + c0 + 4);
  short8 o;
  o[0] = (short)f2bf(v[0] * scale * nw0.x); o[1] = (short)f2bf(v[1] * scale * nw0.y);
  o[2] = (short)f2bf(v[2] * scale * nw0.z); o[3] = (short)f2bf(v[3] * scale * nw0.w);
  o[4] = (short)f2bf(v[4] * scale * nw1.x); o[5] = (short)f2bf(v[5] * scale * nw1.y);
  o[6] = (short)f2bf(v[6] * scale * nw1.z); o[7] = (short)f2bf(v[7] * scale * nw1.w);
  *(short8*)(yrow + c0) = o;
}

// ============================================================
// K8: diagonal gather-reduce: yc1[b][j][t] = b1[j] + sum_k Y[b,t-7+k][j*16+k]
// ============================================================
__global__ void k_red(const float* __restrict__ Y, const float* __restrict__ b1,
                      float* __restrict__ yc1) {
  int idx = blockIdx.x * 256 + threadIdx.x;
  if (idx >= BATCH * 8 * L_SEQ) return;
  int t = idx % L_SEQ;
  int bj = idx / L_SEQ;
  int j = bj & 7, b = bj >> 3;
  float acc = b1[j];
  const float* Yb = Y + (size_t)b * L_SEQ * 128;
#pragma unroll
  for (int k = 0; k < 16; k++) {
    int tt = t - 7 + k;
    if (tt >= 0 && tt < L_SEQ) acc += Yb[(size_t)tt * 128 + j * 16 + k];
  }
  yc1[idx] = acc;
}

// ============================================================
// K9: transposed conv (8->4ch, K=16, lhs_dilation=8, pad 15/15)
// ============================================================
__global__ void k_convT(const float* __restrict__ yc1,
                        const float* __restrict__ wT,
                        const float* __restrict__ bT, float* __restrict__ out) {
  const int s = blockIdx.x * 256 + threadIdx.x;
  const int c = blockIdx.y, b = blockIdx.z;
  float acc = bT[c];
  const int k0 = (15 - (s & 7)) & 7;
#pragma unroll
  for (int dk = 0; dk < 2; dk++) {
    int k = k0 + 8 * dk;
    int num = s - 15 + k;
    int m = num >> 3;
    if (num >= 0 && m < L_SEQ) {
#pragma unroll
      for (int j = 0; j < 8; j++) {
        float v = yc1[((size_t)b * 8 + j) * L_SEQ + m];
        acc = fmaf(v, wT[((size_t)j * 4 + c) * 16 + (15 - k)], acc);
      }
    }
  }
  out[((size_t)b * 4 + c) * L_IN + s] = acc;
}

// ============================================================
extern "C" void kernel_launch(void* const* d_in, const int* in_sizes, int n_in,
                              void* d_out, int out_size, void* d_ws, size_t ws_size,
                              hipStream_t stream) {
  const float* x         = (const float*)d_in[0];
  const float* conv_w    = (const float*)d_in[1];
  const float* conv_b    = (const float*)d_in[2];
  const float* in_proj_w = (const float*)d_in[3];
  const float* conv1d_w  = (const float*)d_in[4];
  const float* conv1d_b  = (const float*)d_in[5];
  const float* dt_bias   = (const float*)d_in[6];
  const float* A_log     = (const float*)d_in[7];
  const float* D_skip    = (const float*)d_in[8];
  const float* norm_w    = (const float*)d_in[9];
  const float* out_proj_w= (const float*)d_in[10];
  const float* conv1_w   = (const float*)d_in[11];
  const float* conv1_b   = (const float*)d_in[12];
  const float* convT_w   = (const float*)d_in[13];
  const float* convT_b   = (const float*)d_in[14];
  float* out = (float*)d_out;
  float* ws  = (float*)d_ws;

  ushort_t* ub   = (ushort_t*)(ws + OFF_U);
  ushort_t* PB   = (ushort_t*)(ws + OFF_PB);
  ushort_t* zb   = (ushort_t*)(ws + OFF_ZB);
  ushort_t* xbcb = (ushort_t*)(ws + OFF_XBC);
  float* dtb  = ws + OFF_DT;
  float* awb  = ws + OFF_AW;
  ushort_t* xcb = (ushort_t*)(ws + OFF_XC);
  ushort_t* y16 = (ushort_t*)(ws + OFF_Y);
  float* yc1  = ws + OFF_YC1;
  float* Pbuf = ws + OFF_PBUF;
  ushort_t* HSb = (ushort_t*)(ws + OFF_HS);
  ushort_t* wbin  = (ushort_t*)(ws + OFF_WBIN);
  ushort_t* wbf   = (ushort_t*)(ws + OFF_WBF);
  ushort_t* W2b   = (ushort_t*)(ws + OFF_W2);
  float* Yg   = ws + OFF_U;   // U region dead after in_proj GEMM

  // 0. merged prep: im2col + weight casts + W2 combine
  k_prep<<<dim3(1928), 256, 0, stream>>>(x, in_proj_w, conv_w, conv1_w, out_proj_w,
                                         PB, wbin, wbf, W2b);
  // 1. front conv GEMM (bias+relu+bf16 epilogue)
  gemm_bf16<1><<<dim3(2, 128), 256, 0, stream>>>(PB, 64, wbf, 64, (float*)ub,
      conv_b, M_TOK, 256, 64, nullptr, nullptr, nullptr, nullptr, nullptr, nullptr);
  // 2. in_proj GEMM with region-split epilogue (z->zb, xBC->xbcb, dt fused)
  gemm_bf16<2><<<dim3(11, 128), 256, 0, stream>>>(ub, 256, wbin, 256, nullptr,
      nullptr, M_TOK, D_IN_PROJ, 256, zb, xbcb, dtb, awb, dt_bias, A_log);
  // 4. depthwise conv + silu, t-blocked sliding window
  k_dw<<<dim3(BATCH * 512), 192, 0, stream>>>(xbcb, conv1d_w, conv1d_b, xcb);
  // 5. SSD scan (MFMA, bf16 states)
  k_ssd_state<<<dim3(NCH, 64), 256, 0, stream>>>(xcb, dtb, awb, HSb, Pbuf);
  k_ssd_comb<<<dim3(16, 64), 256, 0, stream>>>(HSb, Pbuf);
  k_ssd_y<<<dim3(NCH, 64), 256, 0, stream>>>(xcb, dtb, awb, D_skip, HSb, y16);
  // 6. gate + RMSNorm (wave-per-row, bf16 in place)
  k_norm<<<dim3(M_TOK / 4), 256, 0, stream>>>(y16, zb, norm_w);
  // 7. combined out_proj+conv1 GEMM: Y = ynorm @ W2^T  (M=16376,N=128,K=512)
  gemm_bf16<0><<<dim3(1, 128), 256, 0, stream>>>(y16, 512, W2b, 512, Yg,
      nullptr, M_TOK, 128, D_INNER, nullptr, nullptr, nullptr, nullptr, nullptr, nullptr);
  // 8. diagonal gather-reduce -> yc1 (b1 folded)
  k_red<<<dim3((BATCH * 8 * L_SEQ + 255) / 256), 256, 0, stream>>>(Yg, conv1_b, yc1);
  // 9. transposed conv -> out
  k_convT<<<dim3(64, 4, 8), 256, 0, stream>>>(yc1, convT_w, convT_b, out);
}

// Round 10
// 199.210 us; speedup vs baseline: 5.2803x; 1.1023x over previous
//
#include <hip/hip_runtime.h>
#include <cstddef>
#include <cstdint>

// ---------------- problem constants ----------------
constexpr int L_IN   = 16384;
constexpr int L_SEQ  = 2047;          // (16384-16)/8 + 1
constexpr int BATCH  = 8;
constexpr int M_TOK  = BATCH * L_SEQ; // 16376
constexpr int D_INNER = 512;
constexpr int NHEADS  = 8;
constexpr int HEADDIM = 64;
constexpr int D_STATE = 128;
constexpr int CONV_DIM = 768;
constexpr int D_IN_PROJ = 1288;

// SSD chunking
constexpr int QC  = 64;
constexpr int NCH = 32;

// ---------------- workspace layout (float slots) ----------------
constexpr size_t OFF_U    = 0;                       // ub bf16 (2,096,128) / later Yg fp32
constexpr size_t OFF_PB   = OFF_U   + 2096128;       // im2col bf16 (524,032)
constexpr size_t OFF_ZB   = OFF_U   + 4192256;       // z bf16 [row][512] = 4,192,256
constexpr size_t OFF_XBC  = OFF_ZB  + 4192256;       // xBC bf16 [row][768] = 6,288,384
constexpr size_t OFF_DT   = OFF_XBC + 6288384;       // dt fp32 [row][8] = 131,008
constexpr size_t OFF_AW   = OFF_DT  + 131008;        // aw fp32 = 131,008
constexpr size_t OFF_XC   = OFF_AW  + 131008;        // xc bf16 [row][768] = 6,288,384
constexpr size_t OFF_Y    = OFF_XC  + 6288384;       // y bf16 [row][512] = 4,192,256
constexpr size_t OFF_YC1  = OFF_Y   + 4192256;       // yc1 fp32 = 131,008
constexpr size_t OFF_PBUF = OFF_YC1 + 131008;        // Pbuf fp32 = 2,048
constexpr size_t OFF_HS   = OFF_PBUF + 2048;         // HS bf16 = 8,388,608
constexpr size_t OFF_WBIN = OFF_HS  + 8388608;       // 164,864
constexpr size_t OFF_WBF  = OFF_WBIN + 164864;       // 8,192
constexpr size_t OFF_W2   = OFF_WBF + 8192;          // 32,768
// total ~= 136.6 MB
// OOB-read audit for unguarded global_load_lds staging (all stay inside ws):
//   A=PB over-reads 8 rows -> slack before OFF_ZB; A=ub over-reads -> PB region;
//   A=y16 -> yc1 region; B=wbin (+120 rows) -> wbf; B=wbf (N exact) none;
//   B=W2b: N=128 exact, K=512 exact -> none.  Garbage rows only feed acc
//   elements whose stores are guarded by gm<M / gn<N.

using short8 = __attribute__((ext_vector_type(8))) short;  // 8 bf16
using f32x4  = __attribute__((ext_vector_type(4))) float;
typedef unsigned short ushort_t;

__device__ __forceinline__ ushort_t f2bf(float f) {        // RNE f32->bf16
  uint32_t u = __float_as_uint(f);
  u += 0x7fffu + ((u >> 16) & 1u);
  return (ushort_t)(u >> 16);
}
__device__ __forceinline__ float bf2f(ushort_t h) {
  return __uint_as_float(((uint32_t)h) << 16);
}
#define MFMA16(a, b, c) __builtin_amdgcn_mfma_f32_16x16x32_bf16(a, b, c, 0, 0, 0)

#define GLD_LDS(gp, lp) __builtin_amdgcn_global_load_lds( \
    (const __attribute__((address_space(1))) void*)(gp),  \
    (__attribute__((address_space(3))) void*)(lp), 16, 0, 0)

// ============================================================
// K_prep: merged {im2col | weight casts | W2 combine} by blockIdx range.
// ============================================================
__global__ __launch_bounds__(256) void k_prep(const float* __restrict__ x,
    const float* __restrict__ w1, const float* __restrict__ w3,
    const float* __restrict__ conv1_w, const float* __restrict__ wout,
    ushort_t* __restrict__ PB, ushort_t* __restrict__ o1, ushort_t* __restrict__ o3,
    ushort_t* __restrict__ W2b) {
  const int bid = blockIdx.x;
  const int tid = threadIdx.x;
  if (bid < 512) {
    int idx = bid * 256 + tid;
    if (idx >= M_TOK * 8) return;
    int oct = idx & 7, row = idx >> 3;
    int t = row % L_SEQ, b = row / L_SEQ;
    int ic = oct >> 1, k0 = (oct & 1) * 8;
    const float* src = x + ((size_t)b * 4 + ic) * L_IN + t * 8 + k0;
    float4 a0 = *(const float4*)src;
    float4 a1 = *(const float4*)(src + 4);
    short8 o;
    o[0] = (short)f2bf(a0.x); o[1] = (short)f2bf(a0.y);
    o[2] = (short)f2bf(a0.z); o[3] = (short)f2bf(a0.w);
    o[4] = (short)f2bf(a1.x); o[5] = (short)f2bf(a1.y);
    o[6] = (short)f2bf(a1.z); o[7] = (short)f2bf(a1.w);
    *(short8*)(PB + (size_t)row * 64 + oct * 8) = o;
  } else if (bid < 1800) {
    int i = (bid - 512) * 256 + tid;
    if (i < D_IN_PROJ * 256) o1[i] = f2bf(w1[i]);
    if (i < 256 * 64)        o3[i] = f2bf(w3[i]);
  } else {
    const int r = bid - 1800;          // 0..127
    const int oc = r >> 4, k = r & 15;
    const int d0 = tid;
    float acc0 = 0.f, acc1 = 0.f;
    for (int o = 0; o < 256; o++) {
      float wv = conv1_w[((size_t)oc * 256 + o) * 16 + k];
      acc0 = fmaf(wv, wout[(size_t)o * 512 + d0], acc0);
      acc1 = fmaf(wv, wout[(size_t)o * 512 + d0 + 256], acc1);
    }
    W2b[(size_t)r * 512 + d0]       = f2bf(acc0);
    W2b[(size_t)r * 512 + d0 + 256] = f2bf(acc1);
  }
}

// ============================================================
// K2: bf16 MFMA GEMM NT.  128x128 tile, BK=64, 4 waves.
// Staging via global_load_lds width-16: linear LDS dest, PRE-SWIZZLED global
// source (slot s reads src slot s^(r&7)); MFMA reads use the same XOR -> net
// identity.  1D grid + bijective XCD chunk swizzle (grid%8==0 for all calls).
// EPI=0: fp32 store.  EPI=1: +bias, relu, bf16 packed store.
// EPI=2: in_proj region-split epilogue (z->zb, xBC->xbcb, dt fused).
// ============================================================
template<int EPI>
__global__ __launch_bounds__(256) void gemm_bf16(const ushort_t* __restrict__ A, int lda,
    const ushort_t* __restrict__ B, int ldb, float* __restrict__ C,
    const float* __restrict__ bias, int M, int N, int K, int nx,
    ushort_t* __restrict__ zb, ushort_t* __restrict__ xbcb,
    float* __restrict__ dtb, float* __restrict__ awb,
    const float* __restrict__ dt_bias, const float* __restrict__ A_log) {
  __shared__ __attribute__((aligned(16))) ushort_t sA[128 * 64];
  __shared__ __attribute__((aligned(16))) ushort_t sB[128 * 64];
  const int tid = threadIdx.x;
  // XCD chunk swizzle: consecutive swz (same A row-panel) -> same XCD L2
  const int cpx = gridDim.x >> 3;
  const int swz = (blockIdx.x & 7) * cpx + (blockIdx.x >> 3);
  const int m0 = (swz / nx) * 128, n0 = (swz % nx) * 128;
  const int w = tid >> 6, lane = tid & 63;
  const int l15 = lane & 15, lK = lane >> 4;
  const int wr = w >> 1, wc = w & 1;
  f32x4 acc[4][4] = {};
  for (int k0 = 0; k0 < K; k0 += 64) {
    __syncthreads();
#pragma unroll
    for (int j = 0; j < 4; j++) {
      int idx = j * 256 + tid;
      int r = idx >> 3;
      int ss = (idx & 7) ^ (r & 7);           // pre-swizzled source slot
      // wave-uniform LDS base: (j*256 + w*64) 16B-granules
      GLD_LDS(A + (size_t)(m0 + r) * lda + k0 + ss * 8, &sA[(j * 256 + w * 64) * 8]);
      GLD_LDS(B + (size_t)(n0 + r) * ldb + k0 + ss * 8, &sB[(j * 256 + w * 64) * 8]);
    }
    __syncthreads();
#pragma unroll
    for (int kk = 0; kk < 2; kk++) {
      short8 af[4], bf[4];
#pragma unroll
      for (int mt = 0; mt < 4; mt++) {
        int r = wr * 64 + mt * 16 + l15;
        af[mt] = *(const short8*)&sA[r * 64 + (((kk * 4 + lK) ^ (r & 7)) * 8)];
      }
#pragma unroll
      for (int nt = 0; nt < 4; nt++) {
        int r = wc * 64 + nt * 16 + l15;
        bf[nt] = *(const short8*)&sB[r * 64 + (((kk * 4 + lK) ^ (r & 7)) * 8)];
      }
#pragma unroll
      for (int mt = 0; mt < 4; mt++)
#pragma unroll
        for (int nt = 0; nt < 4; nt++)
          acc[mt][nt] = MFMA16(af[mt], bf[nt], acc[mt][nt]);
    }
  }
  if constexpr (EPI == 0) {
#pragma unroll
    for (int mt = 0; mt < 4; mt++)
#pragma unroll
      for (int i = 0; i < 4; i++) {
        int gm = m0 + wr * 64 + mt * 16 + lK * 4 + i;
        if (gm < M) {
          float* crow = C + (size_t)gm * N;
#pragma unroll
          for (int nt = 0; nt < 4; nt++) {
            int gn = n0 + wc * 64 + nt * 16 + l15;
            if (gn < N) crow[gn] = acc[mt][nt][i];
          }
        }
      }
  } else if constexpr (EPI == 1) {
    ushort_t* Cb = (ushort_t*)C;
#pragma unroll
    for (int mt = 0; mt < 4; mt++)
#pragma unroll
      for (int i = 0; i < 4; i++) {
        int gm = m0 + wr * 64 + mt * 16 + lK * 4 + i;
#pragma unroll
        for (int nt = 0; nt < 4; nt++) {
          int gn = n0 + wc * 64 + nt * 16 + l15;
          float v = fmaxf(acc[mt][nt][i] + bias[gn], 0.f);
          uint32_t mine = f2bf(v);
          uint32_t other = (uint32_t)__shfl_xor((int)mine, 1, 64);
          if (((lane & 1) == 0) && gm < M)
            *(uint32_t*)(Cb + (size_t)gm * N + gn) = mine | (other << 16);
        }
      }
  } else {
    if (n0 < 1280) {
      ushort_t* dst = (n0 < 512) ? zb : xbcb;
      const int ldd  = (n0 < 512) ? 512 : 768;
      const int coff = (n0 < 512) ? 0 : 512;
#pragma unroll
      for (int mt = 0; mt < 4; mt++)
#pragma unroll
        for (int i = 0; i < 4; i++) {
          int gm = m0 + wr * 64 + mt * 16 + lK * 4 + i;
#pragma unroll
          for (int nt = 0; nt < 4; nt++) {
            int gn = n0 + wc * 64 + nt * 16 + l15;
            uint32_t mine = f2bf(acc[mt][nt][i]);
            uint32_t other = (uint32_t)__shfl_xor((int)mine, 1, 64);
            if (((lane & 1) == 0) && gm < M)
              *(uint32_t*)(dst + (size_t)gm * ldd + (gn - coff)) = mine | (other << 16);
          }
        }
    } else {
      // dt tile: fused softplus + aw (k_dt eliminated)
#pragma unroll
      for (int mt = 0; mt < 4; mt++)
#pragma unroll
        for (int i = 0; i < 4; i++) {
          int gm = m0 + wr * 64 + mt * 16 + lK * 4 + i;
          if (gm >= M) continue;
#pragma unroll
          for (int nt = 0; nt < 4; nt++) {
            int gn = n0 + wc * 64 + nt * 16 + l15;
            if (gn < N) {
              int hd = gn - 1280;
              float v = acc[mt][nt][i] + dt_bias[hd];
              float sp = (v > 20.f) ? v : log1pf(expf(v));
              dtb[(size_t)gm * 8 + hd] = sp;
              awb[(size_t)gm * 8 + hd] = -expf(A_log[hd]) * sp;
            }
          }
        }
    }
  }
}

// ============================================================
// K4: depthwise causal conv + bias + silu, t-blocked sliding window.
// ============================================================
__global__ __launch_bounds__(192) void k_dw(const ushort_t* __restrict__ xbcb,
    const float* __restrict__ w, const float* __restrict__ bias,
    ushort_t* __restrict__ xcb) {
  const int bid = blockIdx.x;          // b*512 + tb
  const int tb = bid & 511, b = bid >> 9;
  const int t0 = tb * 4;
  const int c = threadIdx.x * 4;
  const size_t rowb = (size_t)b * L_SEQ;
  float wr[4][4];
#pragma unroll
  for (int j = 0; j < 4; j++)
#pragma unroll
    for (int k = 0; k < 4; k++) wr[j][k] = w[(c + j) * 4 + k];
  const float4 bs = {bias[c], bias[c + 1], bias[c + 2], bias[c + 3]};
  float v[7][4];
#pragma unroll
  for (int r = 0; r < 7; r++) {
    int tt = t0 - 3 + r;
    if (tt >= 0 && tt < L_SEQ) {
      uint2 pk = *(const uint2*)(xbcb + (rowb + tt) * CONV_DIM + c);
      v[r][0] = bf2f((ushort_t)(pk.x & 0xffff));
      v[r][1] = bf2f((ushort_t)(pk.x >> 16));
      v[r][2] = bf2f((ushort_t)(pk.y & 0xffff));
      v[r][3] = bf2f((ushort_t)(pk.y >> 16));
    } else {
      v[r][0] = v[r][1] = v[r][2] = v[r][3] = 0.f;
    }
  }
#pragma unroll
  for (int o = 0; o < 4; o++) {
    int t = t0 + o;
    if (t >= L_SEQ) break;
    float a0 = bs.x, a1 = bs.y, a2 = bs.z, a3 = bs.w;
#pragma unroll
    for (int k = 0; k < 4; k++) {
      a0 = fmaf(v[o + k][0], wr[0][k], a0);
      a1 = fmaf(v[o + k][1], wr[1][k], a1);
      a2 = fmaf(v[o + k][2], wr[2][k], a2);
      a3 = fmaf(v[o + k][3], wr[3][k], a3);
    }
    float s0 = a0 / (1.f + expf(-a0));
    float s1 = a1 / (1.f + expf(-a1));
    float s2 = a2 / (1.f + expf(-a2));
    float s3 = a3 / (1.f + expf(-a3));
    uint2 ov;
    ov.x = (uint32_t)f2bf(s0) | ((uint32_t)f2bf(s1) << 16);
    ov.y = (uint32_t)f2bf(s2) | ((uint32_t)f2bf(s3) << 16);
    *(uint2*)(xcb + (rowb + t) * CONV_DIM + c) = ov;
  }
}

// ============================================================
// K5a: SSD chunk state summaries -> HS (bf16, packed-pair stores)
// ============================================================
__global__ __launch_bounds__(256) void k_ssd_state(const ushort_t* __restrict__ xcb,
    const float* __restrict__ dtb, const float* __restrict__ aw,
    ushort_t* __restrict__ HSb, float* __restrict__ Pbuf) {
  const int ch = blockIdx.x, bh = blockIdx.y;
  const int b = bh >> 3, h = bh & 7;
  const int t0 = ch * QC;
  const int valid = (L_SEQ - t0 < QC) ? (L_SEQ - t0) : QC;
  const size_t rowbase = (size_t)b * L_SEQ;
  __shared__ __attribute__((aligned(16))) short sBT[128][72];
  __shared__ __attribute__((aligned(16))) short sXw[64][72];
  __shared__ float sW[64];
  __shared__ float sLtot;
  const int tid = threadIdx.x;
  if (tid < 64) {
    float aa = 0.f, dd = 0.f;
    if (tid < valid) { size_t r8 = (rowbase + t0 + tid) * 8 + h; aa = aw[r8]; dd = dtb[r8]; }
    float s = aa;
#pragma unroll
    for (int d = 1; d < 64; d <<= 1) { float o = __shfl_up(s, d, 64); if (tid >= d) s += o; }
    float Lt = __shfl(s, 63, 64);
    sW[tid] = expf(Lt - s) * dd;
    if (tid == 63) sLtot = s;
  }
  __syncthreads();
  for (int i = tid; i < 64 * 16; i += 256) {
    int r = i >> 4, q = (i & 15) * 8;
    short8 v = {0, 0, 0, 0, 0, 0, 0, 0};
    if (r < valid) v = *(const short8*)(xcb + (rowbase + t0 + r) * CONV_DIM + 512 + q);
#pragma unroll
    for (int j = 0; j < 8; j++) sBT[q + j][r] = v[j];
  }
  for (int i = tid; i < 64 * 8; i += 256) {
    int r = i >> 3, q = (i & 7) * 8;
    short8 v = {0, 0, 0, 0, 0, 0, 0, 0};
    if (r < valid) v = *(const short8*)(xcb + (rowbase + t0 + r) * CONV_DIM + h * 64 + q);
    float wv = sW[r];
#pragma unroll
    for (int j = 0; j < 8; j++) sXw[q + j][r] = (short)f2bf(bf2f((ushort_t)v[j]) * wv);
  }
  __syncthreads();
  const int w = tid >> 6, l15 = tid & 15, lK = (tid & 63) >> 4;
  f32x4 acc[2][4] = {};
  short8 afr[2][2];
#pragma unroll
  for (int j = 0; j < 2; j++)
#pragma unroll
    for (int kt = 0; kt < 2; kt++)
      afr[j][kt] = *(const short8*)&sBT[(w * 2 + j) * 16 + l15][kt * 32 + lK * 8];
#pragma unroll
  for (int pt = 0; pt < 4; pt++) {
#pragma unroll
    for (int kt = 0; kt < 2; kt++) {
      short8 bfr = *(const short8*)&sXw[pt * 16 + l15][kt * 32 + lK * 8];
      acc[0][pt] = MFMA16(afr[0][kt], bfr, acc[0][pt]);
      acc[1][pt] = MFMA16(afr[1][kt], bfr, acc[1][pt]);
    }
  }
  ushort_t* dst = HSb + ((size_t)bh * NCH + ch) * 8192;
#pragma unroll
  for (int j = 0; j < 2; j++)
#pragma unroll
    for (int pt = 0; pt < 4; pt++)
#pragma unroll
      for (int i = 0; i < 4; i++) {
        int n = (w * 2 + j) * 16 + lK * 4 + i, p = pt * 16 + l15;
        uint32_t mine = f2bf(acc[j][pt][i]);
        uint32_t other = (uint32_t)__shfl_xor((int)mine, 1, 64);
        if ((l15 & 1) == 0)
          *(uint32_t*)(dst + n * 64 + p) = mine | (other << 16);
      }
  if (tid == 0) Pbuf[bh * NCH + ch] = expf(sLtot);
}

// ============================================================
// K5b: inter-chunk combine — batch-load all 32 states to regs (one latency),
//      serial fp32 fma chain in-register, batch store.
// ============================================================
__global__ __launch_bounds__(256) void k_ssd_comb(ushort_t* __restrict__ HSb,
                                                  const float* __restrict__ Pbuf) {
  const int bh = blockIdx.y;
  const int e2 = blockIdx.x * 256 + threadIdx.x;   // grid.x=16 -> 4096 pairs
  const size_t base = (size_t)bh * NCH * 8192 + (size_t)e2 * 2;
  uint32_t pk[NCH];
  float P[NCH];
#pragma unroll
  for (int c = 0; c < NCH; c++) pk[c] = *(const uint32_t*)(HSb + base + (size_t)c * 8192);
#pragma unroll
  for (int c = 0; c < NCH; c++) P[c] = Pbuf[bh * NCH + c];
  float run0 = 0.f, run1 = 0.f;
#pragma unroll
  for (int c = 0; c < NCH; c++) {
    run0 = fmaf(P[c], run0, bf2f((ushort_t)(pk[c] & 0xffff)));
    run1 = fmaf(P[c], run1, bf2f((ushort_t)(pk[c] >> 16)));
    pk[c] = (uint32_t)f2bf(run0) | ((uint32_t)f2bf(run1) << 16);
  }
#pragma unroll
  for (int c = 0; c < NCH; c++) *(uint32_t*)(HSb + base + (size_t)c * 8192) = pk[c];
}

// ============================================================
// K5c: SSD output -> y bf16 (packed-pair stores)
// ============================================================
__global__ __launch_bounds__(256) void k_ssd_y(const ushort_t* __restrict__ xcb,
    const float* __restrict__ dtb, const float* __restrict__ aw,
    const float* __restrict__ Dskip, const ushort_t* __restrict__ HSb,
    ushort_t* __restrict__ y16) {
  const int ch = blockIdx.x, bh = blockIdx.y;
  const int b = bh >> 3, h = bh & 7;
  const int t0 = ch * QC;
  const int valid = (L_SEQ - t0 < QC) ? (L_SEQ - t0) : QC;
  const size_t rowbase = (size_t)b * L_SEQ;
  __shared__ __attribute__((aligned(16))) short sB[64][136];
  __shared__ __attribute__((aligned(16))) short sC[64][136];
  __shared__ __attribute__((aligned(16))) short sH[64][136];
  __shared__ __attribute__((aligned(16))) short sX[64][72];
  __shared__ float sLrel[64], sdt[64], sEL[64];
  short (*sM)[72] = (short(*)[72])&sB[0][0];
  const int tid = threadIdx.x;
  if (tid < 64) {
    float aa = 0.f, dd = 0.f;
    if (tid < valid) { size_t r8 = (rowbase + t0 + tid) * 8 + h; aa = aw[r8]; dd = dtb[r8]; }
    float s = aa;
#pragma unroll
    for (int d = 1; d < 64; d <<= 1) { float o = __shfl_up(s, d, 64); if (tid >= d) s += o; }
    sLrel[tid] = s; sdt[tid] = dd; sEL[tid] = expf(s);
  }
  for (int i = tid; i < 64 * 16; i += 256) {
    int r = i >> 4, q = (i & 15) * 8;
    short8 vb = {0, 0, 0, 0, 0, 0, 0, 0}, vc = {0, 0, 0, 0, 0, 0, 0, 0};
    if (r < valid) {
      const ushort_t* rp = xcb + (rowbase + t0 + r) * CONV_DIM;
      vb = *(const short8*)(rp + 512 + q);
      vc = *(const short8*)(rp + 640 + q);
    }
#pragma unroll
    for (int j = 0; j < 8; j++) { sB[r][q + j] = vb[j]; sC[r][q + j] = vc[j]; }
  }
  for (int i = tid; i < 64 * 8; i += 256) {
    int r = i >> 3, q = (i & 7) * 8;
    short8 v = {0, 0, 0, 0, 0, 0, 0, 0};
    if (r < valid) v = *(const short8*)(xcb + (rowbase + t0 + r) * CONV_DIM + h * 64 + q);
#pragma unroll
    for (int j = 0; j < 8; j++) sX[q + j][r] = v[j];
  }
  for (int i = tid; i < 128 * 8; i += 256) {
    int n = i >> 3, q = (i & 7) * 8;
    short8 v = {0, 0, 0, 0, 0, 0, 0, 0};
    if (ch > 0) v = *(const short8*)(HSb + ((size_t)bh * NCH + (ch - 1)) * 8192 + n * 64 + q);
#pragma unroll
    for (int j = 0; j < 8; j++) sH[q + j][n] = v[j];
  }
  __syncthreads();
  const int w = tid >> 6, l15 = tid & 15, lK = (tid & 63) >> 4;
  short8 aC[4];
#pragma unroll
  for (int kt = 0; kt < 4; kt++)
    aC[kt] = *(const short8*)&sC[w * 16 + l15][kt * 32 + lK * 8];
  f32x4 g[4] = {};
#pragma unroll
  for (int st = 0; st < 4; st++)
#pragma unroll
    for (int kt = 0; kt < 4; kt++)
      g[st] = MFMA16(aC[kt], *(const short8*)&sB[st * 16 + l15][kt * 32 + lK * 8], g[st]);
  __syncthreads();
#pragma unroll
  for (int st = 0; st < 4; st++)
#pragma unroll
    for (int i = 0; i < 4; i++) {
      int tt = w * 16 + lK * 4 + i, ss = st * 16 + l15;
      float f = (ss <= tt) ? expf(sLrel[tt] - sLrel[ss]) * sdt[ss] : 0.f;
      sM[tt][ss] = (short)f2bf(g[st][i] * f);
    }
  __syncthreads();
  f32x4 acc[4] = {};
#pragma unroll
  for (int pt = 0; pt < 4; pt++)
#pragma unroll
    for (int kt = 0; kt < 4; kt++)
      acc[pt] = MFMA16(aC[kt], *(const short8*)&sH[pt * 16 + l15][kt * 32 + lK * 8], acc[pt]);
#pragma unroll
  for (int pt = 0; pt < 4; pt++)
#pragma unroll
    for (int i = 0; i < 4; i++)
      acc[pt][i] *= sEL[w * 16 + lK * 4 + i];
  short8 aM[2];
#pragma unroll
  for (int kt = 0; kt < 2; kt++)
    aM[kt] = *(const short8*)&sM[w * 16 + l15][kt * 32 + lK * 8];
#pragma unroll
  for (int pt = 0; pt < 4; pt++)
#pragma unroll
    for (int kt = 0; kt < 2; kt++)
      acc[pt] = MFMA16(aM[kt], *(const short8*)&sX[pt * 16 + l15][kt * 32 + lK * 8], acc[pt]);
  const float Dsk = Dskip[h];
#pragma unroll
  for (int pt = 0; pt < 4; pt++)
#pragma unroll
    for (int i = 0; i < 4; i++) {
      int tt = w * 16 + lK * 4 + i;
      int pp = pt * 16 + l15;
      float v = acc[pt][i] + Dsk * bf2f((ushort_t)sX[pp][tt]);
      uint32_t mine = f2bf(v);
      uint32_t other = (uint32_t)__shfl_xor((int)mine, 1, 64);
      if (((l15 & 1) == 0) && tt < valid)
        *(uint32_t*)(y16 + (rowbase + t0 + tt) * D_INNER + h * 64 + pp) = mine | (other << 16);
    }
}

// ============================================================
// K6: gate + RMSNorm, wave-per-row (64 lanes x 8 ch), short8 16B I/O
// ============================================================
__global__ __launch_bounds__(256) void k_norm(ushort_t* __restrict__ y16,
    const ushort_t* __restrict__ zb, const float* __restrict__ norm_w) {
  const int row = blockIdx.x * 4 + (threadIdx.x >> 6);
  const int lane = threadIdx.x & 63;
  const int c0 = lane * 8;
  ushort_t* yrow = y16 + (size_t)row * D_INNER;
  short8 yv = *(const short8*)(yrow + c0);
  short8 zv = *(const short8*)(zb + (size_t)row * 512 + c0);
  float v[8];
  float ss = 0.f;
#pragma unroll
  for (int j = 0; j < 8; j++) {
    float z = bf2f((ushort_t)zv[j]);
    float g = z / (1.f + expf(-z));
    v[j] = bf2f((ushort_t)yv[j]) * g;
    ss += v[j] * v[j];
  }
#pragma unroll
  for (int m = 32; m >= 1; m >>= 1) ss += __shfl_xor(ss, m, 64);
  float scale = rsqrtf(ss * (1.f / 512.f) + 1e-5f);
  float4 nw0 = *(const float4*)(norm_w + c0);
  float4 nw1 = *(const float4*)(norm_w + c0 + 4);
  short8 o;
  o[0] = (short)f2bf(v[0] * scale * nw0.x); o[1] = (short)f2bf(v[1] * scale * nw0.y);
  o[2] = (short)f2bf(v[2] * scale * nw0.z); o[3] = (short)f2bf(v[3] * scale * nw0.w);
  o[4] = (short)f2bf(v[4] * scale * nw1.x); o[5] = (short)f2bf(v[5] * scale * nw1.y);
  o[6] = (short)f2bf(v[6] * scale * nw1.z); o[7] = (short)f2bf(v[7] * scale * nw1.w);
  *(short8*)(yrow + c0) = o;
}

// ============================================================
// K8: diagonal gather-reduce: yc1[b][j][t] = b1[j] + sum_k Y[b,t-7+k][j*16+k]
// ============================================================
__global__ void k_red(const float* __restrict__ Y, const float* __restrict__ b1,
                      float* __restrict__ yc1) {
  int idx = blockIdx.x * 256 + threadIdx.x;
  if (idx >= BATCH * 8 * L_SEQ) return;
  int t = idx % L_SEQ;
  int bj = idx / L_SEQ;
  int j = bj & 7, b = bj >> 3;
  float acc = b1[j];
  const float* Yb = Y + (size_t)b * L_SEQ * 128;
#pragma unroll
  for (int k = 0; k < 16; k++) {
    int tt = t - 7 + k;
    if (tt >= 0 && tt < L_SEQ) acc += Yb[(size_t)tt * 128 + j * 16 + k];
  }
  yc1[idx] = acc;
}

// ============================================================
// K9: transposed conv (8->4ch, K=16, lhs_dilation=8, pad 15/15)
// ============================================================
__global__ void k_convT(const float* __restrict__ yc1,
                        const float* __restrict__ wT,
                        const float* __restrict__ bT, float* __restrict__ out) {
  const int s = blockIdx.x * 256 + threadIdx.x;
  const int c = blockIdx.y, b = blockIdx.z;
  float acc = bT[c];
  const int k0 = (15 - (s & 7)) & 7;
#pragma unroll
  for (int dk = 0; dk < 2; dk++) {
    int k = k0 + 8 * dk;
    int num = s - 15 + k;
    int m = num >> 3;
    if (num >= 0 && m < L_SEQ) {
#pragma unroll
      for (int j = 0; j < 8; j++) {
        float v = yc1[((size_t)b * 8 + j) * L_SEQ + m];
        acc = fmaf(v, wT[((size_t)j * 4 + c) * 16 + (15 - k)], acc);
      }
    }
  }
  out[((size_t)b * 4 + c) * L_IN + s] = acc;
}

// ============================================================
extern "C" void kernel_launch(void* const* d_in, const int* in_sizes, int n_in,
                              void* d_out, int out_size, void* d_ws, size_t ws_size,
                              hipStream_t stream) {
  const float* x         = (const float*)d_in[0];
  const float* conv_w    = (const float*)d_in[1];
  const float* conv_b    = (const float*)d_in[2];
  const float* in_proj_w = (const float*)d_in[3];
  const float* conv1d_w  = (const float*)d_in[4];
  const float* conv1d_b  = (const float*)d_in[5];
  const float* dt_bias   = (const float*)d_in[6];
  const float* A_log     = (const float*)d_in[7];
  const float* D_skip    = (const float*)d_in[8];
  const float* norm_w    = (const float*)d_in[9];
  const float* out_proj_w= (const float*)d_in[10];
  const float* conv1_w   = (const float*)d_in[11];
  const float* conv1_b   = (const float*)d_in[12];
  const float* convT_w   = (const float*)d_in[13];
  const float* convT_b   = (const float*)d_in[14];
  float* out = (float*)d_out;
  float* ws  = (float*)d_ws;

  ushort_t* ub   = (ushort_t*)(ws + OFF_U);
  ushort_t* PB   = (ushort_t*)(ws + OFF_PB);
  ushort_t* zb   = (ushort_t*)(ws + OFF_ZB);
  ushort_t* xbcb = (ushort_t*)(ws + OFF_XBC);
  float* dtb  = ws + OFF_DT;
  float* awb  = ws + OFF_AW;
  ushort_t* xcb = (ushort_t*)(ws + OFF_XC);
  ushort_t* y16 = (ushort_t*)(ws + OFF_Y);
  float* yc1  = ws + OFF_YC1;
  float* Pbuf = ws + OFF_PBUF;
  ushort_t* HSb = (ushort_t*)(ws + OFF_HS);
  ushort_t* wbin  = (ushort_t*)(ws + OFF_WBIN);
  ushort_t* wbf   = (ushort_t*)(ws + OFF_WBF);
  ushort_t* W2b   = (ushort_t*)(ws + OFF_W2);
  float* Yg   = ws + OFF_U;   // U region dead after in_proj GEMM

  // 0. merged prep: im2col + weight casts + W2 combine
  k_prep<<<dim3(1928), 256, 0, stream>>>(x, in_proj_w, conv_w, conv1_w, out_proj_w,
                                         PB, wbin, wbf, W2b);
  // 1. front conv GEMM (bias+relu+bf16 epilogue), 1D grid 256 = 2x128
  gemm_bf16<1><<<dim3(256), 256, 0, stream>>>(PB, 64, wbf, 64, (float*)ub,
      conv_b, M_TOK, 256, 64, 2, nullptr, nullptr, nullptr, nullptr, nullptr, nullptr);
  // 2. in_proj GEMM, 1D grid 1408 = 11x128, region-split epilogue
  gemm_bf16<2><<<dim3(1408), 256, 0, stream>>>(ub, 256, wbin, 256, nullptr,
      nullptr, M_TOK, D_IN_PROJ, 256, 11, zb, xbcb, dtb, awb, dt_bias, A_log);
  // 4. depthwise conv + silu, t-blocked sliding window
  k_dw<<<dim3(BATCH * 512), 192, 0, stream>>>(xbcb, conv1d_w, conv1d_b, xcb);
  // 5. SSD scan (MFMA, bf16 states)
  k_ssd_state<<<dim3(NCH, 64), 256, 0, stream>>>(xcb, dtb, awb, HSb, Pbuf);
  k_ssd_comb<<<dim3(16, 64), 256, 0, stream>>>(HSb, Pbuf);
  k_ssd_y<<<dim3(NCH, 64), 256, 0, stream>>>(xcb, dtb, awb, D_skip, HSb, y16);
  // 6. gate + RMSNorm (wave-per-row, bf16 in place)
  k_norm<<<dim3(M_TOK / 4), 256, 0, stream>>>(y16, zb, norm_w);
  // 7. combined out_proj+conv1 GEMM: Y = ynorm @ W2^T, 1D grid 128 = 1x128
  gemm_bf16<0><<<dim3(128), 256, 0, stream>>>(y16, 512, W2b, 512, Yg,
      nullptr, M_TOK, 128, D_INNER, 1, nullptr, nullptr, nullptr, nullptr, nullptr, nullptr);
  // 8. diagonal gather-reduce -> yc1 (b1 folded)
  k_red<<<dim3((BATCH * 8 * L_SEQ + 255) / 256), 256, 0, stream>>>(Yg, conv1_b, yc1);
  // 9. transposed conv -> out
  k_convT<<<dim3(64, 4, 8), 256, 0, stream>>>(yc1, convT_w, convT_b, out);
}